// Round 2
// baseline (1478.211 us; speedup 1.0000x reference)
//
#include <hip/hip_runtime.h>
#include <stdint.h>

#define N_NODES 32768
#define NPER    8192
#define NB      4
#define KK      20
#define DH      128

typedef unsigned long long u64;

__device__ __forceinline__ u64 shflx64(u64 x, int m) {
  unsigned lo = __shfl_xor((unsigned)(x & 0xffffffffu), m, 64);
  unsigned hi = __shfl_xor((unsigned)(x >> 32), m, 64);
  return (((u64)hi) << 32) | lo;
}

// One wave per row: exact top-20 by (dist, idx) lexicographic (matches stable top_k).
__global__ __launch_bounds__(256) void knn_kernel(const float* __restrict__ pos,
                                                  int* __restrict__ knn)
{
  const int lane = threadIdx.x & 63;
  const int wave = threadIdx.x >> 6;
  const int row  = blockIdx.x * 4 + wave;
  const int b    = row >> 13;          // / 8192
  const int base = b << 13;
  const int rloc = row & (NPER - 1);

  const float px = pos[row*3+0], py = pos[row*3+1], pz = pos[row*3+2];

  u64 v[KK];
#pragma unroll
  for (int t = 0; t < KK; t++) v[t] = ~0ull;

  for (int it = 0; it < NPER/64; it++) {
    int jl = lane + it*64;
    if (jl == rloc) continue;          // diagonal = inf
    int j = base + jl;
    float dx = px - pos[j*3+0];
    float dy = py - pos[j*3+1];
    float dz = pz - pos[j*3+2];
    float d2 = dx*dx + dy*dy + dz*dz;
    u64 pk = (((u64)__float_as_uint(d2)) << 32) | (unsigned)j;
    if (pk < v[0]) {                   // v[0] = current worst of kept 20
      v[0] = pk;
#pragma unroll
      for (int t = 0; t < KK-1; t++) { // bubble down, keep descending
        u64 a = v[t], bb = v[t+1];
        bool sw = a < bb;
        u64 hi = sw ? bb : a;
        u64 lo = sw ? a  : bb;
        v[t] = hi; v[t+1] = lo;
      }
    }
  }

  // merge 64 sorted lists: 20 rounds of wave-wide min
  u64 cur  = v[KK-1];
  u64 keep = 0;
#pragma unroll
  for (int r = 0; r < KK; r++) {
    u64 m = cur;
#pragma unroll
    for (int o = 1; o < 64; o <<= 1) {
      u64 other = shflx64(m, o);
      m = (other < m) ? other : m;
    }
    if (cur == m) {                    // unique winner pops its head
#pragma unroll
      for (int t = KK-1; t > 0; t--) v[t] = v[t-1];
      v[0] = ~0ull;
      cur = v[KK-1];
    }
    if (lane == r) keep = m;
  }
  if (lane < KK) knn[row*KK + lane] = (int)(keep & 0xffffffffu);
}

// forward edge e=(i -> d=knn[i][j]); mutual iff i in knn(d). Non-mutual edges need a CSR slot.
__global__ void count_kernel(const int* __restrict__ knn, int* __restrict__ flags,
                             int* __restrict__ cnt)
{
  int e = blockIdx.x * 256 + threadIdx.x;
  if (e >= N_NODES*KK) return;
  int i = e / KK;
  int d = knn[e];
  int mut = 0;
#pragma unroll
  for (int t = 0; t < KK; t++) mut |= (knn[d*KK + t] == i);
  flags[e] = mut;
  if (!mut) atomicAdd(&cnt[d], 1);
}

__global__ __launch_bounds__(1024) void scan_kernel(const int* __restrict__ cnt,
                                                    int* __restrict__ off)
{
  __shared__ int ssum[1024];
  int tid = threadIdx.x;
  int i0 = tid * 32;
  int loc[32];
  int s = 0;
#pragma unroll
  for (int j = 0; j < 32; j++) { loc[j] = s; s += cnt[i0 + j]; }
  ssum[tid] = s;
  __syncthreads();
  for (int d = 1; d < 1024; d <<= 1) {
    int t = (tid >= d) ? ssum[tid - d] : 0;
    __syncthreads();
    ssum[tid] += t;
    __syncthreads();
  }
  int bse = ssum[tid] - s;             // exclusive base
#pragma unroll
  for (int j = 0; j < 32; j++) off[i0 + j] = bse + loc[j];
  if (tid == 1023) off[N_NODES] = bse + s;
}

__global__ void fill_kernel(const int* __restrict__ knn, const int* __restrict__ flags,
                            const int* __restrict__ off, int* __restrict__ cursor,
                            int* __restrict__ extra)
{
  int e = blockIdx.x * 256 + threadIdx.x;
  if (e >= N_NODES*KK) return;
  if (flags[e]) return;
  int i = e / KK;
  int d = knn[e];
  int p = atomicAdd(&cursor[d], 1);
  extra[off[d] + p] = i;
}

// Y = X @ W (+ bias [*deg]) [+relu]; X:[n,128] W:[128,128] row-major.
template<int RELU, int DEG>
__global__ __launch_bounds__(256) void gemm128(const float* __restrict__ X,
    const float* __restrict__ W, const float* __restrict__ bias,
    const int* __restrict__ offs, float* __restrict__ Y)
{
  __shared__ float xs[64*129];
  __shared__ float ws[8*128];
  const int tid = threadIdx.x;
  const int r0  = blockIdx.x * 64;
  for (int li = tid; li < 64*128; li += 256) {
    int r = li >> 7, c = li & 127;
    xs[r*129 + c] = X[(size_t)(r0 + r)*128 + c];
  }
  const int tr = tid >> 4, tc = tid & 15;
  const int rr0 = tr*4, cc0 = tc*8;
  float acc[4][8];
#pragma unroll
  for (int a = 0; a < 4; a++)
#pragma unroll
    for (int c = 0; c < 8; c++) acc[a][c] = 0.f;

  for (int kb = 0; kb < 16; kb++) {
    __syncthreads();                   // xs ready (kb=0) / prev ws reads done
    for (int li = tid; li < 1024; li += 256) ws[li] = W[kb*1024 + li];
    __syncthreads();
#pragma unroll
    for (int k8 = 0; k8 < 8; k8++) {
      float xa[4];
#pragma unroll
      for (int rr = 0; rr < 4; rr++) xa[rr] = xs[(rr0+rr)*129 + kb*8 + k8];
      float4 wA = *(const float4*)&ws[k8*128 + cc0];
      float4 wB = *(const float4*)&ws[k8*128 + cc0 + 4];
      float wv[8] = {wA.x, wA.y, wA.z, wA.w, wB.x, wB.y, wB.z, wB.w};
#pragma unroll
      for (int rr = 0; rr < 4; rr++)
#pragma unroll
        for (int cc = 0; cc < 8; cc++) acc[rr][cc] += xa[rr] * wv[cc];
    }
  }
#pragma unroll
  for (int rr = 0; rr < 4; rr++) {
    int r = r0 + rr0 + rr;
    float dg = 1.f;
    if (DEG) dg = (float)(KK + offs[r+1] - offs[r]);
    float o[8];
#pragma unroll
    for (int cc = 0; cc < 8; cc++) {
      float vv = acc[rr][cc] + bias[cc0+cc] * dg;
      if (RELU) vv = fmaxf(vv, 0.f);
      o[cc] = vv;
    }
    *(float4*)&Y[(size_t)r*128 + cc0]     = make_float4(o[0], o[1], o[2], o[3]);
    *(float4*)&Y[(size_t)r*128 + cc0 + 4] = make_float4(o[4], o[5], o[6], o[7]);
  }
}

// agg[d] = sum over in-neighbors s of relu(H[s] + (pos[d]-pos[s]) @ Wr); one wave per node.
__global__ __launch_bounds__(256) void agg_kernel(const float* __restrict__ H,
    const float* __restrict__ pos, const int* __restrict__ knn,
    const int* __restrict__ off, const int* __restrict__ extra,
    const float* __restrict__ Wr, float* __restrict__ agg)
{
  const int lane = threadIdx.x & 63;
  const int d    = blockIdx.x * 4 + (threadIdx.x >> 6);
  const int c0   = lane * 2;
  const float w0x = Wr[0*DH + c0], w0y = Wr[0*DH + c0 + 1];
  const float w1x = Wr[1*DH + c0], w1y = Wr[1*DH + c0 + 1];
  const float w2x = Wr[2*DH + c0], w2y = Wr[2*DH + c0 + 1];
  const float px = pos[d*3+0], py = pos[d*3+1], pz = pos[d*3+2];
  float a0 = 0.f, a1 = 0.f;
#pragma unroll 4
  for (int t = 0; t < KK; t++) {
    int s = knn[d*KK + t];
    float rx = px - pos[s*3+0];
    float ry = py - pos[s*3+1];
    float rz = pz - pos[s*3+2];
    float2 h = *(const float2*)&H[(size_t)s*DH + c0];
    float m0 = h.x + rx*w0x + ry*w1x + rz*w2x;
    float m1 = h.y + rx*w0y + ry*w1y + rz*w2y;
    a0 += fmaxf(m0, 0.f);
    a1 += fmaxf(m1, 0.f);
  }
  const int e0 = off[d], e1 = off[d+1];
  for (int t = e0; t < e1; t++) {
    int s = extra[t];
    float rx = px - pos[s*3+0];
    float ry = py - pos[s*3+1];
    float rz = pz - pos[s*3+2];
    float2 h = *(const float2*)&H[(size_t)s*DH + c0];
    float m0 = h.x + rx*w0x + ry*w1x + rz*w2x;
    float m1 = h.y + rx*w0y + ry*w1y + rz*w2y;
    a0 += fmaxf(m0, 0.f);
    a1 += fmaxf(m1, 0.f);
  }
  *(float2*)&agg[(size_t)d*DH + c0] = make_float2(a0, a1);
}

// logits = X @ Wf + bf; per-graph softmax over 8192 nodes.
__global__ __launch_bounds__(1024) void final_kernel(const float* __restrict__ X,
    const float* __restrict__ Wf, const float* __restrict__ bf, float* __restrict__ out)
{
  __shared__ float red[16];
  __shared__ float bcast;
  const int g = blockIdx.x, tid = threadIdx.x;
  const int lane = tid & 63, wid = tid >> 6;
  float lg[8];
#pragma unroll
  for (int k = 0; k < 8; k++) {
    int n = g*NPER + k*1024 + tid;
    const float4* xr = (const float4*)&X[(size_t)n*128];
    float acc = 0.f;
#pragma unroll 8
    for (int q = 0; q < 32; q++) {
      float4 xv = xr[q];
      float4 wv = *(const float4*)&Wf[q*4];
      acc += xv.x*wv.x + xv.y*wv.y + xv.z*wv.z + xv.w*wv.w;
    }
    lg[k] = acc + bf[0];
  }
  float m = lg[0];
#pragma unroll
  for (int k = 1; k < 8; k++) m = fmaxf(m, lg[k]);
  for (int o = 1; o < 64; o <<= 1) m = fmaxf(m, __shfl_xor(m, o, 64));
  if (lane == 0) red[wid] = m;
  __syncthreads();
  if (tid == 0) {
    float mm = red[0];
    for (int i = 1; i < 16; i++) mm = fmaxf(mm, red[i]);
    bcast = mm;
  }
  __syncthreads();
  const float M = bcast;
  float e[8];
  float s = 0.f;
#pragma unroll
  for (int k = 0; k < 8; k++) { e[k] = expf(lg[k] - M); s += e[k]; }
  for (int o = 1; o < 64; o <<= 1) s += __shfl_xor(s, o, 64);
  __syncthreads();
  if (lane == 0) red[wid] = s;
  __syncthreads();
  if (tid == 0) {
    float ss = 0.f;
    for (int i = 0; i < 16; i++) ss += red[i];
    bcast = ss;
  }
  __syncthreads();
  const float S = bcast;
#pragma unroll
  for (int k = 0; k < 8; k++) {
    int n = g*NPER + k*1024 + tid;
    out[n] = e[k] / S;
  }
}

extern "C" void kernel_launch(void* const* d_in, const int* in_sizes, int n_in,
                              void* d_out, int out_size, void* d_ws, size_t ws_size,
                              hipStream_t stream)
{
  const float* x   = (const float*)d_in[0];
  const float* pos = (const float*)d_in[1];
  // d_in[2] = batch (unused: sorted, equal-size graphs)
  const float* W1s = (const float*)d_in[3];
  const float* b1s = (const float*)d_in[4];
  const float* W2s = (const float*)d_in[5];
  const float* b2s = (const float*)d_in[6];
  const float* Wf  = (const float*)d_in[7];
  const float* bf  = (const float*)d_in[8];
  float* out = (float*)d_out;

  char* wsb = (char*)d_ws;
  size_t o = 0;
  auto alloc = [&](size_t bytes) { void* p = wsb + o; o += (bytes + 255) & ~255ull; return p; };
  int*   knn    = (int*)  alloc((size_t)N_NODES*KK*4);
  int*   flags  = (int*)  alloc((size_t)N_NODES*KK*4);
  int*   cnt    = (int*)  alloc((size_t)(N_NODES+1)*4);
  int*   off    = (int*)  alloc((size_t)(N_NODES+1)*4);
  int*   cursor = (int*)  alloc((size_t)N_NODES*4);
  int*   extra  = (int*)  alloc((size_t)N_NODES*KK*4);
  float* H      = (float*)alloc((size_t)N_NODES*DH*4);
  float* agg    = (float*)alloc((size_t)N_NODES*DH*4);
  float* xbuf   = (float*)alloc((size_t)N_NODES*DH*4);
  (void)ws_size; (void)in_sizes; (void)n_in; (void)out_size;

  hipMemsetAsync(cnt,    0, (size_t)(N_NODES+1)*4, stream);
  hipMemsetAsync(cursor, 0, (size_t)N_NODES*4,     stream);

  knn_kernel <<<N_NODES/4, 256, 0, stream>>>(pos, knn);
  count_kernel<<<(N_NODES*KK + 255)/256, 256, 0, stream>>>(knn, flags, cnt);
  scan_kernel<<<1, 1024, 0, stream>>>(cnt, off);
  fill_kernel<<<(N_NODES*KK + 255)/256, 256, 0, stream>>>(knn, flags, off, cursor, extra);

  const float* xin = x;
  for (int l = 0; l < 3; l++) {
    const float* W1 = W1s + (size_t)l*131*128;   // rows 0..127: x-part
    const float* Wr = W1 + 128*128;              // rows 128..130: rel-part
    const float* b1 = b1s + l*128;
    const float* W2 = W2s + (size_t)l*128*128;
    const float* b2 = b2s + l*128;
    gemm128<0,0><<<N_NODES/64, 256, 0, stream>>>(xin, W1, b1, nullptr, H);
    agg_kernel  <<<N_NODES/4,  256, 0, stream>>>(H, pos, knn, off, extra, Wr, agg);
    gemm128<1,1><<<N_NODES/64, 256, 0, stream>>>(agg, W2, b2, off, xbuf);
    xin = xbuf;
  }
  final_kernel<<<NB, 1024, 0, stream>>>(xbuf, Wf, bf, out);
}

// Round 4
// 827.095 us; speedup vs baseline: 1.7872x; 1.7872x over previous
//
#include <hip/hip_runtime.h>
#include <stdint.h>

#define N_NODES 32768
#define NPER    8192
#define NB      4
#define KK      20
#define DH      128

typedef unsigned long long u64;

__device__ __forceinline__ u64 shflx64(u64 x, int m) {
  unsigned lo = __shfl_xor((unsigned)(x & 0xffffffffu), m, 64);
  unsigned hi = __shfl_xor((unsigned)(x >> 32), m, 64);
  return (((u64)hi) << 32) | lo;
}

// One wave per row: exact top-20 by (dist, idx) via histogram-select + bitonic sort.
// Pass 1: 256-bin log histogram of d2 (exp + 4 mantissa bits). Scan -> bucket B where
// cumcount >= 20. Pass 2: compact all candidates with bits < upper_edge(B) (a >=20
// superset, expected ~21-25), then exact 64-lane bitonic sort of (d2_bits<<32)|idx.
#define HBASE 1888   // (2^-9 bits) >> 19; buckets cover d2 in [2^-9, 2^7)
__global__ __launch_bounds__(256) void knn_kernel(const float* __restrict__ pos,
                                                  int* __restrict__ knn)
{
  __shared__ int hist[4][256];
  __shared__ u64 buf[4][128];
  __shared__ int scnt[4];

  const int lane = threadIdx.x & 63;
  const int w    = threadIdx.x >> 6;
  const int row  = blockIdx.x * 4 + w;
  const int b    = row >> 13;          // / 8192
  const int base = b << 13;
  const int rloc = row & (NPER - 1);

  // per-wave init (wave-private structures; in-wave LDS ordering is enough)
#pragma unroll
  for (int t = 0; t < 4; t++) hist[w][lane + t*64] = 0;
  if (lane == 0) scnt[w] = 0;

  const float px = pos[row*3+0], py = pos[row*3+1], pz = pos[row*3+2];

  // pass 1: histogram
  for (int it = 0; it < NPER/64; it++) {
    int jl = lane + it*64;
    if (jl == rloc) continue;          // diagonal = inf
    int j = base + jl;
    float dx = px - pos[j*3+0];
    float dy = py - pos[j*3+1];
    float dz = pz - pos[j*3+2];
    float d2 = dx*dx + dy*dy + dz*dz;
    int bk = (int)(__float_as_uint(d2) >> 19) - HBASE;
    bk = max(0, min(255, bk));
    atomicAdd(&hist[w][bk], 1);
  }

  // scan: lane l owns bins [4l, 4l+4)
  int c4[4];
  int s = 0;
#pragma unroll
  for (int t = 0; t < 4; t++) { c4[t] = hist[w][lane*4 + t]; s += c4[t]; }
  int cum = s;
#pragma unroll
  for (int o = 1; o < 64; o <<= 1) {
    int t = __shfl_up(cum, o, 64);
    if (lane >= o) cum += t;
  }
  u64 bal = __ballot(cum >= KK);
  int f = __ffsll((long long)bal) - 1;       // first lane reaching 20 (exists: 8191 >= 20)
  int cc = cum - s;
  int Bmine = 255;
  bool fnd = false;
#pragma unroll
  for (int t = 0; t < 4; t++) {
    cc += c4[t];
    if (!fnd && cc >= KK) { Bmine = lane*4 + t; fnd = true; }
  }
  int Bsel = __shfl(Bmine, f, 64);
  const unsigned thr = (unsigned)(HBASE + Bsel + 1) << 19;   // survivor: bits < thr

  // pass 2: compact survivors
  for (int it = 0; it < NPER/64; it++) {
    int jl = lane + it*64;
    if (jl == rloc) continue;
    int j = base + jl;
    float dx = px - pos[j*3+0];
    float dy = py - pos[j*3+1];
    float dz = pz - pos[j*3+2];
    float d2 = dx*dx + dy*dy + dz*dz;
    unsigned bits = __float_as_uint(d2);
    if (bits < thr) {
      int slot = atomicAdd(&scnt[w], 1);
      if (slot < 128)
        buf[w][slot] = (((u64)bits) << 32) | (unsigned)j;
    }
  }

  // exact sort of survivors (S ~ 21-25, <= 64 for Gaussian data), ascending
  int S = scnt[w];
  u64 key = (lane < S) ? buf[w][lane] : ~0ull;
#pragma unroll
  for (int k = 2; k <= 64; k <<= 1) {
#pragma unroll
    for (int j = k >> 1; j >= 1; j >>= 1) {
      u64 other = shflx64(key, j);
      bool up = ((lane & k) == 0);                 // ascending block?
      bool keepmin = (((lane & j) == 0) == up);
      bool take = keepmin ? (other < key) : (other > key);
      key = take ? other : key;
    }
  }
  if (lane < KK) knn[row*KK + lane] = (int)(key & 0xffffffffu);
}

// forward edge e=(i -> d=knn[i][j]); mutual iff i in knn(d). Non-mutual edges need a CSR slot.
__global__ void count_kernel(const int* __restrict__ knn, int* __restrict__ flags,
                             int* __restrict__ cnt)
{
  int e = blockIdx.x * 256 + threadIdx.x;
  if (e >= N_NODES*KK) return;
  int i = e / KK;
  int d = knn[e];
  int mut = 0;
#pragma unroll
  for (int t = 0; t < KK; t++) mut |= (knn[d*KK + t] == i);
  flags[e] = mut;
  if (!mut) atomicAdd(&cnt[d], 1);
}

__global__ __launch_bounds__(1024) void scan_kernel(const int* __restrict__ cnt,
                                                    int* __restrict__ off)
{
  __shared__ int ssum[1024];
  int tid = threadIdx.x;
  int i0 = tid * 32;
  int loc[32];
  int s = 0;
#pragma unroll
  for (int j = 0; j < 32; j++) { loc[j] = s; s += cnt[i0 + j]; }
  ssum[tid] = s;
  __syncthreads();
  for (int d = 1; d < 1024; d <<= 1) {
    int t = (tid >= d) ? ssum[tid - d] : 0;
    __syncthreads();
    ssum[tid] += t;
    __syncthreads();
  }
  int bse = ssum[tid] - s;             // exclusive base
#pragma unroll
  for (int j = 0; j < 32; j++) off[i0 + j] = bse + loc[j];
  if (tid == 1023) off[N_NODES] = bse + s;
}

__global__ void fill_kernel(const int* __restrict__ knn, const int* __restrict__ flags,
                            const int* __restrict__ off, int* __restrict__ cursor,
                            int* __restrict__ extra)
{
  int e = blockIdx.x * 256 + threadIdx.x;
  if (e >= N_NODES*KK) return;
  if (flags[e]) return;
  int i = e / KK;
  int d = knn[e];
  int p = atomicAdd(&cursor[d], 1);
  extra[off[d] + p] = i;
}

// Y = X @ W (+ bias [*deg]) [+relu]; X:[n,128] W:[128,128] row-major.
template<int RELU, int DEG>
__global__ __launch_bounds__(256) void gemm128(const float* __restrict__ X,
    const float* __restrict__ W, const float* __restrict__ bias,
    const int* __restrict__ offs, float* __restrict__ Y)
{
  __shared__ float xs[64*129];
  __shared__ float ws[8*128];
  const int tid = threadIdx.x;
  const int r0  = blockIdx.x * 64;
  for (int li = tid; li < 64*128; li += 256) {
    int r = li >> 7, c = li & 127;
    xs[r*129 + c] = X[(size_t)(r0 + r)*128 + c];
  }
  const int tr = tid >> 4, tc = tid & 15;
  const int rr0 = tr*4, cc0 = tc*8;
  float acc[4][8];
#pragma unroll
  for (int a = 0; a < 4; a++)
#pragma unroll
    for (int c = 0; c < 8; c++) acc[a][c] = 0.f;

  for (int kb = 0; kb < 16; kb++) {
    __syncthreads();                   // xs ready (kb=0) / prev ws reads done
    for (int li = tid; li < 1024; li += 256) ws[li] = W[kb*1024 + li];
    __syncthreads();
#pragma unroll
    for (int k8 = 0; k8 < 8; k8++) {
      float xa[4];
#pragma unroll
      for (int rr = 0; rr < 4; rr++) xa[rr] = xs[(rr0+rr)*129 + kb*8 + k8];
      float4 wA = *(const float4*)&ws[k8*128 + cc0];
      float4 wB = *(const float4*)&ws[k8*128 + cc0 + 4];
      float wv[8] = {wA.x, wA.y, wA.z, wA.w, wB.x, wB.y, wB.z, wB.w};
#pragma unroll
      for (int rr = 0; rr < 4; rr++)
#pragma unroll
        for (int cc = 0; cc < 8; cc++) acc[rr][cc] += xa[rr] * wv[cc];
    }
  }
#pragma unroll
  for (int rr = 0; rr < 4; rr++) {
    int r = r0 + rr0 + rr;
    float dg = 1.f;
    if (DEG) dg = (float)(KK + offs[r+1] - offs[r]);
    float o[8];
#pragma unroll
    for (int cc = 0; cc < 8; cc++) {
      float vv = acc[rr][cc] + bias[cc0+cc] * dg;
      if (RELU) vv = fmaxf(vv, 0.f);
      o[cc] = vv;
    }
    *(float4*)&Y[(size_t)r*128 + cc0]     = make_float4(o[0], o[1], o[2], o[3]);
    *(float4*)&Y[(size_t)r*128 + cc0 + 4] = make_float4(o[4], o[5], o[6], o[7]);
  }
}

// agg[d] = sum over in-neighbors s of relu(H[s] + (pos[d]-pos[s]) @ Wr); one wave per node.
__global__ __launch_bounds__(256) void agg_kernel(const float* __restrict__ H,
    const float* __restrict__ pos, const int* __restrict__ knn,
    const int* __restrict__ off, const int* __restrict__ extra,
    const float* __restrict__ Wr, float* __restrict__ agg)
{
  const int lane = threadIdx.x & 63;
  const int d    = blockIdx.x * 4 + (threadIdx.x >> 6);
  const int c0   = lane * 2;
  const float w0x = Wr[0*DH + c0], w0y = Wr[0*DH + c0 + 1];
  const float w1x = Wr[1*DH + c0], w1y = Wr[1*DH + c0 + 1];
  const float w2x = Wr[2*DH + c0], w2y = Wr[2*DH + c0 + 1];
  const float px = pos[d*3+0], py = pos[d*3+1], pz = pos[d*3+2];
  float a0 = 0.f, a1 = 0.f;
#pragma unroll 4
  for (int t = 0; t < KK; t++) {
    int s = knn[d*KK + t];
    float rx = px - pos[s*3+0];
    float ry = py - pos[s*3+1];
    float rz = pz - pos[s*3+2];
    float2 h = *(const float2*)&H[(size_t)s*DH + c0];
    float m0 = h.x + rx*w0x + ry*w1x + rz*w2x;
    float m1 = h.y + rx*w0y + ry*w1y + rz*w2y;
    a0 += fmaxf(m0, 0.f);
    a1 += fmaxf(m1, 0.f);
  }
  const int e0 = off[d], e1 = off[d+1];
  for (int t = e0; t < e1; t++) {
    int s = extra[t];
    float rx = px - pos[s*3+0];
    float ry = py - pos[s*3+1];
    float rz = pz - pos[s*3+2];
    float2 h = *(const float2*)&H[(size_t)s*DH + c0];
    float m0 = h.x + rx*w0x + ry*w1x + rz*w2x;
    float m1 = h.y + rx*w0y + ry*w1y + rz*w2y;
    a0 += fmaxf(m0, 0.f);
    a1 += fmaxf(m1, 0.f);
  }
  *(float2*)&agg[(size_t)d*DH + c0] = make_float2(a0, a1);
}

// logits = X @ Wf + bf; per-graph softmax over 8192 nodes.
__global__ __launch_bounds__(1024) void final_kernel(const float* __restrict__ X,
    const float* __restrict__ Wf, const float* __restrict__ bf, float* __restrict__ out)
{
  __shared__ float red[16];
  __shared__ float bcast;
  const int g = blockIdx.x, tid = threadIdx.x;
  const int lane = tid & 63, wid = tid >> 6;
  float lg[8];
#pragma unroll
  for (int k = 0; k < 8; k++) {
    int n = g*NPER + k*1024 + tid;
    const float4* xr = (const float4*)&X[(size_t)n*128];
    float acc = 0.f;
#pragma unroll 8
    for (int q = 0; q < 32; q++) {
      float4 xv = xr[q];
      float4 wv = *(const float4*)&Wf[q*4];
      acc += xv.x*wv.x + xv.y*wv.y + xv.z*wv.z + xv.w*wv.w;
    }
    lg[k] = acc + bf[0];
  }
  float m = lg[0];
#pragma unroll
  for (int k = 1; k < 8; k++) m = fmaxf(m, lg[k]);
  for (int o = 1; o < 64; o <<= 1) m = fmaxf(m, __shfl_xor(m, o, 64));
  if (lane == 0) red[wid] = m;
  __syncthreads();
  if (tid == 0) {
    float mm = red[0];
    for (int i = 1; i < 16; i++) mm = fmaxf(mm, red[i]);
    bcast = mm;
  }
  __syncthreads();
  const float M = bcast;
  float e[8];
  float s = 0.f;
#pragma unroll
  for (int k = 0; k < 8; k++) { e[k] = expf(lg[k] - M); s += e[k]; }
  for (int o = 1; o < 64; o <<= 1) s += __shfl_xor(s, o, 64);
  __syncthreads();
  if (lane == 0) red[wid] = s;
  __syncthreads();
  if (tid == 0) {
    float ss = 0.f;
    for (int i = 0; i < 16; i++) ss += red[i];
    bcast = ss;
  }
  __syncthreads();
  const float S = bcast;
#pragma unroll
  for (int k = 0; k < 8; k++) {
    int n = g*NPER + k*1024 + tid;
    out[n] = e[k] / S;
  }
}

extern "C" void kernel_launch(void* const* d_in, const int* in_sizes, int n_in,
                              void* d_out, int out_size, void* d_ws, size_t ws_size,
                              hipStream_t stream)
{
  const float* x   = (const float*)d_in[0];
  const float* pos = (const float*)d_in[1];
  // d_in[2] = batch (unused: sorted, equal-size graphs)
  const float* W1s = (const float*)d_in[3];
  const float* b1s = (const float*)d_in[4];
  const float* W2s = (const float*)d_in[5];
  const float* b2s = (const float*)d_in[6];
  const float* Wf  = (const float*)d_in[7];
  const float* bf  = (const float*)d_in[8];
  float* out = (float*)d_out;

  char* wsb = (char*)d_ws;
  size_t o = 0;
  auto alloc = [&](size_t bytes) { void* p = wsb + o; o += (bytes + 255) & ~255ull; return p; };
  int*   knn    = (int*)  alloc((size_t)N_NODES*KK*4);
  int*   flags  = (int*)  alloc((size_t)N_NODES*KK*4);
  int*   cnt    = (int*)  alloc((size_t)(N_NODES+1)*4);
  int*   off    = (int*)  alloc((size_t)(N_NODES+1)*4);
  int*   cursor = (int*)  alloc((size_t)N_NODES*4);
  int*   extra  = (int*)  alloc((size_t)N_NODES*KK*4);
  float* H      = (float*)alloc((size_t)N_NODES*DH*4);
  float* agg    = (float*)alloc((size_t)N_NODES*DH*4);
  float* xbuf   = (float*)alloc((size_t)N_NODES*DH*4);
  (void)ws_size; (void)in_sizes; (void)n_in; (void)out_size;

  hipMemsetAsync(cnt,    0, (size_t)(N_NODES+1)*4, stream);
  hipMemsetAsync(cursor, 0, (size_t)N_NODES*4,     stream);

  knn_kernel <<<N_NODES/4, 256, 0, stream>>>(pos, knn);
  count_kernel<<<(N_NODES*KK + 255)/256, 256, 0, stream>>>(knn, flags, cnt);
  scan_kernel<<<1, 1024, 0, stream>>>(cnt, off);
  fill_kernel<<<(N_NODES*KK + 255)/256, 256, 0, stream>>>(knn, flags, off, cursor, extra);

  const float* xin = x;
  for (int l = 0; l < 3; l++) {
    const float* W1 = W1s + (size_t)l*131*128;   // rows 0..127: x-part
    const float* Wr = W1 + 128*128;              // rows 128..130: rel-part
    const float* b1 = b1s + l*128;
    const float* W2 = W2s + (size_t)l*128*128;
    const float* b2 = b2s + l*128;
    gemm128<0,0><<<N_NODES/64, 256, 0, stream>>>(xin, W1, b1, nullptr, H);
    agg_kernel  <<<N_NODES/4,  256, 0, stream>>>(H, pos, knn, off, extra, Wr, agg);
    gemm128<1,1><<<N_NODES/64, 256, 0, stream>>>(agg, W2, b2, off, xbuf);
    xin = xbuf;
  }
  final_kernel<<<NB, 1024, 0, stream>>>(xbuf, Wf, bf, out);
}

// Round 5
// 786.883 us; speedup vs baseline: 1.8786x; 1.0511x over previous
//
#include <hip/hip_runtime.h>
#include <stdint.h>

#define N_NODES 32768
#define NPER    8192
#define NB      4
#define KK      20
#define DH      128

typedef unsigned long long u64;

__device__ __forceinline__ u64 shflx64(u64 x, int m) {
  unsigned lo = __shfl_xor((unsigned)(x & 0xffffffffu), m, 64);
  unsigned hi = __shfl_xor((unsigned)(x >> 32), m, 64);
  return (((u64)hi) << 32) | lo;
}
__device__ __forceinline__ u64 shfl64(u64 x, int src) {
  unsigned lo = __shfl((unsigned)(x & 0xffffffffu), src, 64);
  unsigned hi = __shfl((unsigned)(x >> 32), src, 64);
  return (((u64)hi) << 32) | lo;
}
// 64-lane bitonic sort, ascending across lanes
__device__ __forceinline__ u64 bsort64(u64 key, int lane) {
#pragma unroll
  for (int k = 2; k <= 64; k <<= 1) {
#pragma unroll
    for (int j = k >> 1; j >= 1; j >>= 1) {
      u64 other = shflx64(key, j);
      bool up = ((lane & k) == 0);
      bool keepmin = (((lane & j) == 0) == up);
      bool take = keepmin ? (other < key) : (other > key);
      key = take ? other : key;
    }
  }
  return key;
}
// bitonic merge-clean (input bitonic, output ascending)
__device__ __forceinline__ u64 bclean64(u64 key, int lane) {
#pragma unroll
  for (int j = 32; j >= 1; j >>= 1) {
    u64 other = shflx64(key, j);
    bool keepmin = ((lane & j) == 0);
    bool take = keepmin ? (other < key) : (other > key);
    key = take ? other : key;
  }
  return key;
}

// One wave per row: exact top-20 by (dist, idx), single streaming pass.
// LDS buffer keeps all keys < thr (thr = exact 20th-smallest seen, +inf at start).
// Ballot-based slot assignment (no atomics). Compact via bitonic sort+merge when
// buffer count would overflow; compaction tightens thr. Exact: buffer is always
// a superset of the true top-20 (keys unique via idx low bits).
__global__ __launch_bounds__(256) void knn_kernel(const float* __restrict__ pos,
                                                  int* __restrict__ knn)
{
  __shared__ u64 buf[4][128];

  const int lane = threadIdx.x & 63;
  const int w    = threadIdx.x >> 6;
  const int row  = blockIdx.x * 4 + w;
  const int base = (row >> 13) << 13;   // graph start
  const int rloc = row & (NPER - 1);

  const float px = pos[row*3+0], py = pos[row*3+1], pz = pos[row*3+2];

  u64 thr = ~0ull;
  int cnt = 0;          // uniform across wave
  u64 lo  = ~0ull;      // sorted survivors after a compact

  auto compact = [&]() {
    asm volatile("s_waitcnt lgkmcnt(0)" ::: "memory");
    u64 k0 = (lane      < cnt) ? buf[w][lane]      : ~0ull;
    u64 k1 = (lane + 64 < cnt) ? buf[w][lane + 64] : ~0ull;
    k0 = bsort64(k0, lane);
    k1 = bsort64(k1, lane);
    u64 k1r = shfl64(k1, 63 - lane);          // descending copy of k1
    lo = (k1r < k0) ? k1r : k0;               // half-cleaner: 64 smallest, bitonic
    lo = bclean64(lo, lane);                  // sorted ascending
    thr = shfl64(lo, 19);                     // exact 20th smallest
    if (lane < KK) buf[w][lane] = lo;
    cnt = KK;
    asm volatile("s_waitcnt lgkmcnt(0)" ::: "memory");
  };

  for (int it = 0; it < NPER/64; it++) {
    int jl = lane + it*64;
    int j  = base + jl;
    float dx = px - pos[j*3+0];
    float dy = py - pos[j*3+1];
    float dz = pz - pos[j*3+2];
    float d2 = fmaf(dx, dx, fmaf(dy, dy, dz*dz));
    u64 pk = (((u64)__float_as_uint(d2)) << 32) | (unsigned)j;
    bool pred = (pk < thr) && (jl != rloc);   // exclude diagonal
    u64 mask = __ballot(pred);
    if (pred) {
      int below = __builtin_amdgcn_mbcnt_hi((unsigned)(mask >> 32),
                  __builtin_amdgcn_mbcnt_lo((unsigned)mask, 0u));
      buf[w][cnt + below] = pk;
    }
    cnt += __popcll(mask);
    if (cnt > 64) compact();                  // next iter appends <=64 -> fits 128
  }
  compact();                                  // final: lanes 0..19 hold sorted top-20
  if (lane < KK) knn[row*KK + lane] = (int)(lo & 0xffffffffu);
}

// forward edge e=(i -> d=knn[i][j]); mutual iff i in knn(d). Non-mutual edges need a CSR slot.
__global__ void count_kernel(const int* __restrict__ knn, int* __restrict__ flags,
                             int* __restrict__ cnt)
{
  int e = blockIdx.x * 256 + threadIdx.x;
  if (e >= N_NODES*KK) return;
  int i = e / KK;
  int d = knn[e];
  int mut = 0;
#pragma unroll
  for (int t = 0; t < KK; t++) mut |= (knn[d*KK + t] == i);
  flags[e] = mut;
  if (!mut) atomicAdd(&cnt[d], 1);
}

__global__ __launch_bounds__(1024) void scan_kernel(const int* __restrict__ cnt,
                                                    int* __restrict__ off)
{
  __shared__ int ssum[1024];
  int tid = threadIdx.x;
  int i0 = tid * 32;
  int loc[32];
  int s = 0;
#pragma unroll
  for (int j = 0; j < 32; j++) { loc[j] = s; s += cnt[i0 + j]; }
  ssum[tid] = s;
  __syncthreads();
  for (int d = 1; d < 1024; d <<= 1) {
    int t = (tid >= d) ? ssum[tid - d] : 0;
    __syncthreads();
    ssum[tid] += t;
    __syncthreads();
  }
  int bse = ssum[tid] - s;             // exclusive base
#pragma unroll
  for (int j = 0; j < 32; j++) off[i0 + j] = bse + loc[j];
  if (tid == 1023) off[N_NODES] = bse + s;
}

__global__ void fill_kernel(const int* __restrict__ knn, const int* __restrict__ flags,
                            const int* __restrict__ off, int* __restrict__ cursor,
                            int* __restrict__ extra)
{
  int e = blockIdx.x * 256 + threadIdx.x;
  if (e >= N_NODES*KK) return;
  if (flags[e]) return;
  int i = e / KK;
  int d = knn[e];
  int p = atomicAdd(&cursor[d], 1);
  extra[off[d] + p] = i;
}

// Y = X @ W (+ bias [*deg]) [+relu]; X:[n,128] W:[128,128] row-major.
template<int RELU, int DEG>
__global__ __launch_bounds__(256) void gemm128(const float* __restrict__ X,
    const float* __restrict__ W, const float* __restrict__ bias,
    const int* __restrict__ offs, float* __restrict__ Y)
{
  __shared__ float xs[64*129];
  __shared__ float ws[8*128];
  const int tid = threadIdx.x;
  const int r0  = blockIdx.x * 64;
  for (int li = tid; li < 64*128; li += 256) {
    int r = li >> 7, c = li & 127;
    xs[r*129 + c] = X[(size_t)(r0 + r)*128 + c];
  }
  const int tr = tid >> 4, tc = tid & 15;
  const int rr0 = tr*4, cc0 = tc*8;
  float acc[4][8];
#pragma unroll
  for (int a = 0; a < 4; a++)
#pragma unroll
    for (int c = 0; c < 8; c++) acc[a][c] = 0.f;

  for (int kb = 0; kb < 16; kb++) {
    __syncthreads();                   // xs ready (kb=0) / prev ws reads done
    for (int li = tid; li < 1024; li += 256) ws[li] = W[kb*1024 + li];
    __syncthreads();
#pragma unroll
    for (int k8 = 0; k8 < 8; k8++) {
      float xa[4];
#pragma unroll
      for (int rr = 0; rr < 4; rr++) xa[rr] = xs[(rr0+rr)*129 + kb*8 + k8];
      float4 wA = *(const float4*)&ws[k8*128 + cc0];
      float4 wB = *(const float4*)&ws[k8*128 + cc0 + 4];
      float wv[8] = {wA.x, wA.y, wA.z, wA.w, wB.x, wB.y, wB.z, wB.w};
#pragma unroll
      for (int rr = 0; rr < 4; rr++)
#pragma unroll
        for (int cc = 0; cc < 8; cc++) acc[rr][cc] += xa[rr] * wv[cc];
    }
  }
#pragma unroll
  for (int rr = 0; rr < 4; rr++) {
    int r = r0 + rr0 + rr;
    float dg = 1.f;
    if (DEG) dg = (float)(KK + offs[r+1] - offs[r]);
    float o[8];
#pragma unroll
    for (int cc = 0; cc < 8; cc++) {
      float vv = acc[rr][cc] + bias[cc0+cc] * dg;
      if (RELU) vv = fmaxf(vv, 0.f);
      o[cc] = vv;
    }
    *(float4*)&Y[(size_t)r*128 + cc0]     = make_float4(o[0], o[1], o[2], o[3]);
    *(float4*)&Y[(size_t)r*128 + cc0 + 4] = make_float4(o[4], o[5], o[6], o[7]);
  }
}

// agg[d] = sum over in-neighbors s of relu(H[s] + (pos[d]-pos[s]) @ Wr); one wave per node.
__global__ __launch_bounds__(256) void agg_kernel(const float* __restrict__ H,
    const float* __restrict__ pos, const int* __restrict__ knn,
    const int* __restrict__ off, const int* __restrict__ extra,
    const float* __restrict__ Wr, float* __restrict__ agg)
{
  const int lane = threadIdx.x & 63;
  const int d    = blockIdx.x * 4 + (threadIdx.x >> 6);
  const int c0   = lane * 2;
  const float w0x = Wr[0*DH + c0], w0y = Wr[0*DH + c0 + 1];
  const float w1x = Wr[1*DH + c0], w1y = Wr[1*DH + c0 + 1];
  const float w2x = Wr[2*DH + c0], w2y = Wr[2*DH + c0 + 1];
  const float px = pos[d*3+0], py = pos[d*3+1], pz = pos[d*3+2];
  float a0 = 0.f, a1 = 0.f;
#pragma unroll 4
  for (int t = 0; t < KK; t++) {
    int s = knn[d*KK + t];
    float rx = px - pos[s*3+0];
    float ry = py - pos[s*3+1];
    float rz = pz - pos[s*3+2];
    float2 h = *(const float2*)&H[(size_t)s*DH + c0];
    float m0 = h.x + rx*w0x + ry*w1x + rz*w2x;
    float m1 = h.y + rx*w0y + ry*w1y + rz*w2y;
    a0 += fmaxf(m0, 0.f);
    a1 += fmaxf(m1, 0.f);
  }
  const int e0 = off[d], e1 = off[d+1];
  for (int t = e0; t < e1; t++) {
    int s = extra[t];
    float rx = px - pos[s*3+0];
    float ry = py - pos[s*3+1];
    float rz = pz - pos[s*3+2];
    float2 h = *(const float2*)&H[(size_t)s*DH + c0];
    float m0 = h.x + rx*w0x + ry*w1x + rz*w2x;
    float m1 = h.y + rx*w0y + ry*w1y + rz*w2y;
    a0 += fmaxf(m0, 0.f);
    a1 += fmaxf(m1, 0.f);
  }
  *(float2*)&agg[(size_t)d*DH + c0] = make_float2(a0, a1);
}

// logits = X @ Wf + bf; per-graph softmax over 8192 nodes.
__global__ __launch_bounds__(1024) void final_kernel(const float* __restrict__ X,
    const float* __restrict__ Wf, const float* __restrict__ bf, float* __restrict__ out)
{
  __shared__ float red[16];
  __shared__ float bcast;
  const int g = blockIdx.x, tid = threadIdx.x;
  const int lane = tid & 63, wid = tid >> 6;
  float lg[8];
#pragma unroll
  for (int k = 0; k < 8; k++) {
    int n = g*NPER + k*1024 + tid;
    const float4* xr = (const float4*)&X[(size_t)n*128];
    float acc = 0.f;
#pragma unroll 8
    for (int q = 0; q < 32; q++) {
      float4 xv = xr[q];
      float4 wv = *(const float4*)&Wf[q*4];
      acc += xv.x*wv.x + xv.y*wv.y + xv.z*wv.z + xv.w*wv.w;
    }
    lg[k] = acc + bf[0];
  }
  float m = lg[0];
#pragma unroll
  for (int k = 1; k < 8; k++) m = fmaxf(m, lg[k]);
  for (int o = 1; o < 64; o <<= 1) m = fmaxf(m, __shfl_xor(m, o, 64));
  if (lane == 0) red[wid] = m;
  __syncthreads();
  if (tid == 0) {
    float mm = red[0];
    for (int i = 1; i < 16; i++) mm = fmaxf(mm, red[i]);
    bcast = mm;
  }
  __syncthreads();
  const float M = bcast;
  float e[8];
  float s = 0.f;
#pragma unroll
  for (int k = 0; k < 8; k++) { e[k] = expf(lg[k] - M); s += e[k]; }
  for (int o = 1; o < 64; o <<= 1) s += __shfl_xor(s, o, 64);
  __syncthreads();
  if (lane == 0) red[wid] = s;
  __syncthreads();
  if (tid == 0) {
    float ss = 0.f;
    for (int i = 0; i < 16; i++) ss += red[i];
    bcast = ss;
  }
  __syncthreads();
  const float S = bcast;
#pragma unroll
  for (int k = 0; k < 8; k++) {
    int n = g*NPER + k*1024 + tid;
    out[n] = e[k] / S;
  }
}

extern "C" void kernel_launch(void* const* d_in, const int* in_sizes, int n_in,
                              void* d_out, int out_size, void* d_ws, size_t ws_size,
                              hipStream_t stream)
{
  const float* x   = (const float*)d_in[0];
  const float* pos = (const float*)d_in[1];
  // d_in[2] = batch (unused: sorted, equal-size graphs)
  const float* W1s = (const float*)d_in[3];
  const float* b1s = (const float*)d_in[4];
  const float* W2s = (const float*)d_in[5];
  const float* b2s = (const float*)d_in[6];
  const float* Wf  = (const float*)d_in[7];
  const float* bf  = (const float*)d_in[8];
  float* out = (float*)d_out;

  char* wsb = (char*)d_ws;
  size_t o = 0;
  auto alloc = [&](size_t bytes) { void* p = wsb + o; o += (bytes + 255) & ~255ull; return p; };
  int*   knn    = (int*)  alloc((size_t)N_NODES*KK*4);
  int*   flags  = (int*)  alloc((size_t)N_NODES*KK*4);
  int*   cnt    = (int*)  alloc((size_t)(N_NODES+1)*4);
  int*   off    = (int*)  alloc((size_t)(N_NODES+1)*4);
  int*   cursor = (int*)  alloc((size_t)N_NODES*4);
  int*   extra  = (int*)  alloc((size_t)N_NODES*KK*4);
  float* H      = (float*)alloc((size_t)N_NODES*DH*4);
  float* agg    = (float*)alloc((size_t)N_NODES*DH*4);
  float* xbuf   = (float*)alloc((size_t)N_NODES*DH*4);
  (void)ws_size; (void)in_sizes; (void)n_in; (void)out_size;

  hipMemsetAsync(cnt,    0, (size_t)(N_NODES+1)*4, stream);
  hipMemsetAsync(cursor, 0, (size_t)N_NODES*4,     stream);

  knn_kernel <<<N_NODES/4, 256, 0, stream>>>(pos, knn);
  count_kernel<<<(N_NODES*KK + 255)/256, 256, 0, stream>>>(knn, flags, cnt);
  scan_kernel<<<1, 1024, 0, stream>>>(cnt, off);
  fill_kernel<<<(N_NODES*KK + 255)/256, 256, 0, stream>>>(knn, flags, off, cursor, extra);

  const float* xin = x;
  for (int l = 0; l < 3; l++) {
    const float* W1 = W1s + (size_t)l*131*128;   // rows 0..127: x-part
    const float* Wr = W1 + 128*128;              // rows 128..130: rel-part
    const float* b1 = b1s + l*128;
    const float* W2 = W2s + (size_t)l*128*128;
    const float* b2 = b2s + l*128;
    gemm128<0,0><<<N_NODES/64, 256, 0, stream>>>(xin, W1, b1, nullptr, H);
    agg_kernel  <<<N_NODES/4,  256, 0, stream>>>(H, pos, knn, off, extra, Wr, agg);
    gemm128<1,1><<<N_NODES/64, 256, 0, stream>>>(agg, W2, b2, off, xbuf);
    xin = xbuf;
  }
  final_kernel<<<NB, 1024, 0, stream>>>(xbuf, Wf, bf, out);
}

// Round 6
// 774.510 us; speedup vs baseline: 1.9086x; 1.0160x over previous
//
#include <hip/hip_runtime.h>
#include <stdint.h>

#define N_NODES 32768
#define NPER    8192
#define NB      4
#define KK      20
#define DH      128

typedef unsigned long long u64;

__device__ __forceinline__ u64 shflx64(u64 x, int m) {
  unsigned lo = __shfl_xor((unsigned)(x & 0xffffffffu), m, 64);
  unsigned hi = __shfl_xor((unsigned)(x >> 32), m, 64);
  return (((u64)hi) << 32) | lo;
}
__device__ __forceinline__ u64 shfl64(u64 x, int src) {
  unsigned lo = __shfl((unsigned)(x & 0xffffffffu), src, 64);
  unsigned hi = __shfl((unsigned)(x >> 32), src, 64);
  return (((u64)hi) << 32) | lo;
}
// 64-lane bitonic sort, ascending across lanes
__device__ __forceinline__ u64 bsort64(u64 key, int lane) {
#pragma unroll
  for (int k = 2; k <= 64; k <<= 1) {
#pragma unroll
    for (int j = k >> 1; j >= 1; j >>= 1) {
      u64 other = shflx64(key, j);
      bool up = ((lane & k) == 0);
      bool keepmin = (((lane & j) == 0) == up);
      bool take = keepmin ? (other < key) : (other > key);
      key = take ? other : key;
    }
  }
  return key;
}
// bitonic merge-clean (input bitonic, output ascending)
__device__ __forceinline__ u64 bclean64(u64 key, int lane) {
#pragma unroll
  for (int j = 32; j >= 1; j >>= 1) {
    u64 other = shflx64(key, j);
    bool keepmin = ((lane & j) == 0);
    bool take = keepmin ? (other < key) : (other > key);
    key = take ? other : key;
  }
  return key;
}

// One wave per row: exact top-20 by (dist, idx), single streaming pass.
// Hot loop filters on raw d2 bits vs uint threshold (1 cmp); self (d2=0) is
// allowed through and stripped at output by index match, so no diagonal check.
// Keep 21 survivors per compaction (self + real top-20); thr = 21st smallest.
// Ballot-based slot assignment (no atomics); compact = bitonic sort+merge.
__global__ __launch_bounds__(256) void knn_kernel(const float* __restrict__ pos,
                                                  int* __restrict__ knn)
{
  __shared__ u64 buf[4][128];

  const int lane = threadIdx.x & 63;
  const int w    = threadIdx.x >> 6;
  const int row  = blockIdx.x * 4 + w;
  const int base = (row >> 13) << 13;   // graph start

  const float px = pos[row*3+0], py = pos[row*3+1], pz = pos[row*3+2];

  unsigned thrb = 0xffffffffu;  // d2-bit threshold (<=); all valid floats pass initially
  int cnt = 0;                  // uniform across wave
  u64 lo  = ~0ull;              // sorted survivors after a compact

  auto compact = [&]() {
    asm volatile("s_waitcnt lgkmcnt(0)" ::: "memory");
    u64 k0 = (lane      < cnt) ? buf[w][lane]      : ~0ull;
    u64 k1 = (lane + 64 < cnt) ? buf[w][lane + 64] : ~0ull;
    k0 = bsort64(k0, lane);
    k1 = bsort64(k1, lane);
    u64 k1r = shfl64(k1, 63 - lane);          // descending copy of k1
    lo = (k1r < k0) ? k1r : k0;               // half-cleaner: 64 smallest, bitonic
    lo = bclean64(lo, lane);                  // sorted ascending
    thrb = (unsigned)(shfl64(lo, KK) >> 32);  // 21st smallest (self included)
    if (lane <= KK) buf[w][lane] = lo;        // keep 21
    cnt = KK + 1;
    asm volatile("s_waitcnt lgkmcnt(0)" ::: "memory");
  };

  const float* __restrict__ p = pos + (size_t)base*3;
#pragma unroll 2
  for (int it = 0; it < NPER/64; it++) {
    int jl = lane + it*64;
    float qx = p[jl*3+0], qy = p[jl*3+1], qz = p[jl*3+2];
    float dx = px - qx, dy = py - qy, dz = pz - qz;
    float d2 = fmaf(dx, dx, fmaf(dy, dy, dz*dz));
    unsigned bits = __float_as_uint(d2);
    bool pred = (bits <= thrb);
    u64 mask = __ballot(pred);
    if (pred) {
      int below = __builtin_amdgcn_mbcnt_hi((unsigned)(mask >> 32),
                  __builtin_amdgcn_mbcnt_lo((unsigned)mask, 0u));
      buf[w][cnt + below] = (((u64)bits) << 32) | (unsigned)(base + jl);
    }
    cnt += __popcll(mask);
    if (cnt > 64) compact();                  // next iter appends <=64 -> fits 128
  }
  compact();   // lanes 0..20 of lo = 21 smallest keys incl. self, sorted

  // strip self (identified by index; d2=0 makes it always among the 21)
  u64 ball = __ballot(((int)(lo & 0xffffffffu) == row) && (lane <= KK));
  int p0 = __ffsll((long long)ball) - 1;      // self position (uniform)
  if (p0 < 0) p0 = KK + 1;                    // paranoia: never taken
  int src = lane + ((lane >= p0) ? 1 : 0);
  u64 outk = shfl64(lo, src);
  if (lane < KK) knn[row*KK + lane] = (int)(outk & 0xffffffffu);
}

// forward edge e=(i -> d=knn[i][j]); mutual iff i in knn(d). Non-mutual edges need a CSR slot.
__global__ void count_kernel(const int* __restrict__ knn, int* __restrict__ flags,
                             int* __restrict__ cnt)
{
  int e = blockIdx.x * 256 + threadIdx.x;
  if (e >= N_NODES*KK) return;
  int i = e / KK;
  int d = knn[e];
  int mut = 0;
#pragma unroll
  for (int t = 0; t < KK; t++) mut |= (knn[d*KK + t] == i);
  flags[e] = mut;
  if (!mut) atomicAdd(&cnt[d], 1);
}

__global__ __launch_bounds__(1024) void scan_kernel(const int* __restrict__ cnt,
                                                    int* __restrict__ off)
{
  __shared__ int ssum[1024];
  int tid = threadIdx.x;
  int i0 = tid * 32;
  int loc[32];
  int s = 0;
#pragma unroll
  for (int j = 0; j < 32; j++) { loc[j] = s; s += cnt[i0 + j]; }
  ssum[tid] = s;
  __syncthreads();
  for (int d = 1; d < 1024; d <<= 1) {
    int t = (tid >= d) ? ssum[tid - d] : 0;
    __syncthreads();
    ssum[tid] += t;
    __syncthreads();
  }
  int bse = ssum[tid] - s;             // exclusive base
#pragma unroll
  for (int j = 0; j < 32; j++) off[i0 + j] = bse + loc[j];
  if (tid == 1023) off[N_NODES] = bse + s;
}

__global__ void fill_kernel(const int* __restrict__ knn, const int* __restrict__ flags,
                            const int* __restrict__ off, int* __restrict__ cursor,
                            int* __restrict__ extra)
{
  int e = blockIdx.x * 256 + threadIdx.x;
  if (e >= N_NODES*KK) return;
  if (flags[e]) return;
  int i = e / KK;
  int d = knn[e];
  int p = atomicAdd(&cursor[d], 1);
  extra[off[d] + p] = i;
}

// Y = X @ W (+ bias [*deg]) [+relu]; X:[n,128] W:[128,128] row-major.
template<int RELU, int DEG>
__global__ __launch_bounds__(256) void gemm128(const float* __restrict__ X,
    const float* __restrict__ W, const float* __restrict__ bias,
    const int* __restrict__ offs, float* __restrict__ Y)
{
  __shared__ float xs[64*129];
  __shared__ float ws[8*128];
  const int tid = threadIdx.x;
  const int r0  = blockIdx.x * 64;
  for (int li = tid; li < 64*128; li += 256) {
    int r = li >> 7, c = li & 127;
    xs[r*129 + c] = X[(size_t)(r0 + r)*128 + c];
  }
  const int tr = tid >> 4, tc = tid & 15;
  const int rr0 = tr*4, cc0 = tc*8;
  float acc[4][8];
#pragma unroll
  for (int a = 0; a < 4; a++)
#pragma unroll
    for (int c = 0; c < 8; c++) acc[a][c] = 0.f;

  for (int kb = 0; kb < 16; kb++) {
    __syncthreads();                   // xs ready (kb=0) / prev ws reads done
    for (int li = tid; li < 1024; li += 256) ws[li] = W[kb*1024 + li];
    __syncthreads();
#pragma unroll
    for (int k8 = 0; k8 < 8; k8++) {
      float xa[4];
#pragma unroll
      for (int rr = 0; rr < 4; rr++) xa[rr] = xs[(rr0+rr)*129 + kb*8 + k8];
      float4 wA = *(const float4*)&ws[k8*128 + cc0];
      float4 wB = *(const float4*)&ws[k8*128 + cc0 + 4];
      float wv[8] = {wA.x, wA.y, wA.z, wA.w, wB.x, wB.y, wB.z, wB.w};
#pragma unroll
      for (int rr = 0; rr < 4; rr++)
#pragma unroll
        for (int cc = 0; cc < 8; cc++) acc[rr][cc] += xa[rr] * wv[cc];
    }
  }
#pragma unroll
  for (int rr = 0; rr < 4; rr++) {
    int r = r0 + rr0 + rr;
    float dg = 1.f;
    if (DEG) dg = (float)(KK + offs[r+1] - offs[r]);
    float o[8];
#pragma unroll
    for (int cc = 0; cc < 8; cc++) {
      float vv = acc[rr][cc] + bias[cc0+cc] * dg;
      if (RELU) vv = fmaxf(vv, 0.f);
      o[cc] = vv;
    }
    *(float4*)&Y[(size_t)r*128 + cc0]     = make_float4(o[0], o[1], o[2], o[3]);
    *(float4*)&Y[(size_t)r*128 + cc0 + 4] = make_float4(o[4], o[5], o[6], o[7]);
  }
}

// agg[d] = sum over in-neighbors s of relu(H[s] + (pos[d]-pos[s]) @ Wr); one wave per node.
__global__ __launch_bounds__(256) void agg_kernel(const float* __restrict__ H,
    const float* __restrict__ pos, const int* __restrict__ knn,
    const int* __restrict__ off, const int* __restrict__ extra,
    const float* __restrict__ Wr, float* __restrict__ agg)
{
  const int lane = threadIdx.x & 63;
  const int d    = blockIdx.x * 4 + (threadIdx.x >> 6);
  const int c0   = lane * 2;
  const float w0x = Wr[0*DH + c0], w0y = Wr[0*DH + c0 + 1];
  const float w1x = Wr[1*DH + c0], w1y = Wr[1*DH + c0 + 1];
  const float w2x = Wr[2*DH + c0], w2y = Wr[2*DH + c0 + 1];
  const float px = pos[d*3+0], py = pos[d*3+1], pz = pos[d*3+2];
  float a0 = 0.f, a1 = 0.f;
#pragma unroll 4
  for (int t = 0; t < KK; t++) {
    int s = knn[d*KK + t];
    float rx = px - pos[s*3+0];
    float ry = py - pos[s*3+1];
    float rz = pz - pos[s*3+2];
    float2 h = *(const float2*)&H[(size_t)s*DH + c0];
    float m0 = h.x + rx*w0x + ry*w1x + rz*w2x;
    float m1 = h.y + rx*w0y + ry*w1y + rz*w2y;
    a0 += fmaxf(m0, 0.f);
    a1 += fmaxf(m1, 0.f);
  }
  const int e0 = off[d], e1 = off[d+1];
  for (int t = e0; t < e1; t++) {
    int s = extra[t];
    float rx = px - pos[s*3+0];
    float ry = py - pos[s*3+1];
    float rz = pz - pos[s*3+2];
    float2 h = *(const float2*)&H[(size_t)s*DH + c0];
    float m0 = h.x + rx*w0x + ry*w1x + rz*w2x;
    float m1 = h.y + rx*w0y + ry*w1y + rz*w2y;
    a0 += fmaxf(m0, 0.f);
    a1 += fmaxf(m1, 0.f);
  }
  *(float2*)&agg[(size_t)d*DH + c0] = make_float2(a0, a1);
}

// logits = X @ Wf + bf; per-graph softmax over 8192 nodes.
__global__ __launch_bounds__(1024) void final_kernel(const float* __restrict__ X,
    const float* __restrict__ Wf, const float* __restrict__ bf, float* __restrict__ out)
{
  __shared__ float red[16];
  __shared__ float bcast;
  const int g = blockIdx.x, tid = threadIdx.x;
  const int lane = tid & 63, wid = tid >> 6;
  float lg[8];
#pragma unroll
  for (int k = 0; k < 8; k++) {
    int n = g*NPER + k*1024 + tid;
    const float4* xr = (const float4*)&X[(size_t)n*128];
    float acc = 0.f;
#pragma unroll 8
    for (int q = 0; q < 32; q++) {
      float4 xv = xr[q];
      float4 wv = *(const float4*)&Wf[q*4];
      acc += xv.x*wv.x + xv.y*wv.y + xv.z*wv.z + xv.w*wv.w;
    }
    lg[k] = acc + bf[0];
  }
  float m = lg[0];
#pragma unroll
  for (int k = 1; k < 8; k++) m = fmaxf(m, lg[k]);
  for (int o = 1; o < 64; o <<= 1) m = fmaxf(m, __shfl_xor(m, o, 64));
  if (lane == 0) red[wid] = m;
  __syncthreads();
  if (tid == 0) {
    float mm = red[0];
    for (int i = 1; i < 16; i++) mm = fmaxf(mm, red[i]);
    bcast = mm;
  }
  __syncthreads();
  const float M = bcast;
  float e[8];
  float s = 0.f;
#pragma unroll
  for (int k = 0; k < 8; k++) { e[k] = expf(lg[k] - M); s += e[k]; }
  for (int o = 1; o < 64; o <<= 1) s += __shfl_xor(s, o, 64);
  __syncthreads();
  if (lane == 0) red[wid] = s;
  __syncthreads();
  if (tid == 0) {
    float ss = 0.f;
    for (int i = 0; i < 16; i++) ss += red[i];
    bcast = ss;
  }
  __syncthreads();
  const float S = bcast;
#pragma unroll
  for (int k = 0; k < 8; k++) {
    int n = g*NPER + k*1024 + tid;
    out[n] = e[k] / S;
  }
}

extern "C" void kernel_launch(void* const* d_in, const int* in_sizes, int n_in,
                              void* d_out, int out_size, void* d_ws, size_t ws_size,
                              hipStream_t stream)
{
  const float* x   = (const float*)d_in[0];
  const float* pos = (const float*)d_in[1];
  // d_in[2] = batch (unused: sorted, equal-size graphs)
  const float* W1s = (const float*)d_in[3];
  const float* b1s = (const float*)d_in[4];
  const float* W2s = (const float*)d_in[5];
  const float* b2s = (const float*)d_in[6];
  const float* Wf  = (const float*)d_in[7];
  const float* bf  = (const float*)d_in[8];
  float* out = (float*)d_out;

  char* wsb = (char*)d_ws;
  size_t o = 0;
  auto alloc = [&](size_t bytes) { void* p = wsb + o; o += (bytes + 255) & ~255ull; return p; };
  int*   knn    = (int*)  alloc((size_t)N_NODES*KK*4);
  int*   flags  = (int*)  alloc((size_t)N_NODES*KK*4);
  int*   cnt    = (int*)  alloc((size_t)(N_NODES+1)*4);
  int*   off    = (int*)  alloc((size_t)(N_NODES+1)*4);
  int*   cursor = (int*)  alloc((size_t)N_NODES*4);
  int*   extra  = (int*)  alloc((size_t)N_NODES*KK*4);
  float* H      = (float*)alloc((size_t)N_NODES*DH*4);
  float* agg    = (float*)alloc((size_t)N_NODES*DH*4);
  float* xbuf   = (float*)alloc((size_t)N_NODES*DH*4);
  (void)ws_size; (void)in_sizes; (void)n_in; (void)out_size;

  hipMemsetAsync(cnt,    0, (size_t)(N_NODES+1)*4, stream);
  hipMemsetAsync(cursor, 0, (size_t)N_NODES*4,     stream);

  knn_kernel <<<N_NODES/4, 256, 0, stream>>>(pos, knn);
  count_kernel<<<(N_NODES*KK + 255)/256, 256, 0, stream>>>(knn, flags, cnt);
  scan_kernel<<<1, 1024, 0, stream>>>(cnt, off);
  fill_kernel<<<(N_NODES*KK + 255)/256, 256, 0, stream>>>(knn, flags, off, cursor, extra);

  const float* xin = x;
  for (int l = 0; l < 3; l++) {
    const float* W1 = W1s + (size_t)l*131*128;   // rows 0..127: x-part
    const float* Wr = W1 + 128*128;              // rows 128..130: rel-part
    const float* b1 = b1s + l*128;
    const float* W2 = W2s + (size_t)l*128*128;
    const float* b2 = b2s + l*128;
    gemm128<0,0><<<N_NODES/64, 256, 0, stream>>>(xin, W1, b1, nullptr, H);
    agg_kernel  <<<N_NODES/4,  256, 0, stream>>>(H, pos, knn, off, extra, Wr, agg);
    gemm128<1,1><<<N_NODES/64, 256, 0, stream>>>(agg, W2, b2, off, xbuf);
    xin = xbuf;
  }
  final_kernel<<<NB, 1024, 0, stream>>>(xbuf, Wf, bf, out);
}

// Round 7
// 764.713 us; speedup vs baseline: 1.9330x; 1.0128x over previous
//
#include <hip/hip_runtime.h>
#include <stdint.h>

#define N_NODES 32768
#define NPER    8192
#define NB      4
#define KK      20
#define DH      128

typedef unsigned long long u64;

__device__ __forceinline__ u64 shflx64(u64 x, int m) {
  unsigned lo = __shfl_xor((unsigned)(x & 0xffffffffu), m, 64);
  unsigned hi = __shfl_xor((unsigned)(x >> 32), m, 64);
  return (((u64)hi) << 32) | lo;
}
__device__ __forceinline__ u64 shfl64(u64 x, int src) {
  unsigned lo = __shfl((unsigned)(x & 0xffffffffu), src, 64);
  unsigned hi = __shfl((unsigned)(x >> 32), src, 64);
  return (((u64)hi) << 32) | lo;
}
__device__ __forceinline__ int mbcnt64(u64 mask) {
  return __builtin_amdgcn_mbcnt_hi((unsigned)(mask >> 32),
         __builtin_amdgcn_mbcnt_lo((unsigned)mask, 0u));
}
// 64-lane bitonic sort, ascending across lanes
__device__ __forceinline__ u64 bsort64(u64 key, int lane) {
#pragma unroll
  for (int k = 2; k <= 64; k <<= 1) {
#pragma unroll
    for (int j = k >> 1; j >= 1; j >>= 1) {
      u64 other = shflx64(key, j);
      bool up = ((lane & k) == 0);
      bool keepmin = (((lane & j) == 0) == up);
      bool take = keepmin ? (other < key) : (other > key);
      key = take ? other : key;
    }
  }
  return key;
}
// bitonic merge-clean (input bitonic, output ascending)
__device__ __forceinline__ u64 bclean64(u64 key, int lane) {
#pragma unroll
  for (int j = 32; j >= 1; j >>= 1) {
    u64 other = shflx64(key, j);
    bool keepmin = ((lane & j) == 0);
    bool take = keepmin ? (other < key) : (other > key);
    key = take ? other : key;
  }
  return key;
}

// compact <=128 buffered keys -> sorted 21 smallest (lanes 0..20 of lo), tighten thr
__device__ __forceinline__ void compact128(u64* bufr, int& cnt, u64& lo,
                                           unsigned& thr, int lane) {
  asm volatile("s_waitcnt lgkmcnt(0)" ::: "memory");
  u64 k0 = (lane      < cnt) ? bufr[lane]      : ~0ull;
  u64 k1 = (lane + 64 < cnt) ? bufr[lane + 64] : ~0ull;
  k0 = bsort64(k0, lane);
  k1 = bsort64(k1, lane);
  u64 k1r = shfl64(k1, 63 - lane);          // descending copy of k1
  lo = (k1r < k0) ? k1r : k0;               // half-cleaner: 64 smallest, bitonic
  lo = bclean64(lo, lane);                  // sorted ascending
  thr = (unsigned)(shfl64(lo, KK) >> 32);   // d2-bits of 21st smallest (incl self)
  if (lane <= KK) bufr[lane] = lo;          // keep 21
  cnt = KK + 1;
  asm volatile("s_waitcnt lgkmcnt(0)" ::: "memory");
}

// One wave per TWO consecutive rows (same graph): shared candidate loads and loop
// overhead. Hot loop filters on raw d2 bits vs uint threshold; self (d2=0) flows
// through and is stripped at output by index match. Keep 21 per compaction.
// Ballot slot assignment (no atomics); compact = bitonic sort+merge (exact).
__global__ __launch_bounds__(256) void knn_kernel(const float* __restrict__ pos,
                                                  int* __restrict__ knn)
{
  __shared__ u64 buf[8][128];

  const int lane = threadIdx.x & 63;
  const int w    = threadIdx.x >> 6;
  const int rowA = blockIdx.x * 8 + w * 2;
  const int rowB = rowA + 1;
  const int base = (rowA >> 13) << 13;   // graph start (NPER even multiple)

  const float ax = pos[rowA*3+0], ay = pos[rowA*3+1], az = pos[rowA*3+2];
  const float bx = pos[rowB*3+0], by = pos[rowB*3+1], bz = pos[rowB*3+2];

  unsigned thra = 0xffffffffu, thrb = 0xffffffffu;
  int cnta = 0, cntb = 0;
  u64 loa = ~0ull, lob = ~0ull;
  u64* bufa = buf[w*2+0];
  u64* bufb = buf[w*2+1];

  const float* __restrict__ p = pos + (size_t)base*3;
  for (int it = 0; it < NPER/64; it++) {
    const int jl = lane + it*64;
    const float qx = p[jl*3+0], qy = p[jl*3+1], qz = p[jl*3+2];
    const unsigned idx = (unsigned)(base + jl);
    // row A
    {
      float dx = ax-qx, dy = ay-qy, dz = az-qz;
      float d2 = fmaf(dx, dx, fmaf(dy, dy, dz*dz));
      unsigned bits = __float_as_uint(d2);
      bool pred = (bits <= thra);
      u64 mask = __ballot(pred);
      if (pred) bufa[cnta + mbcnt64(mask)] = (((u64)bits) << 32) | idx;
      cnta += __popcll(mask);
      cnta = __builtin_amdgcn_readfirstlane(cnta);
      if (cnta > 64) compact128(bufa, cnta, loa, thra, lane);
    }
    // row B
    {
      float dx = bx-qx, dy = by-qy, dz = bz-qz;
      float d2 = fmaf(dx, dx, fmaf(dy, dy, dz*dz));
      unsigned bits = __float_as_uint(d2);
      bool pred = (bits <= thrb);
      u64 mask = __ballot(pred);
      if (pred) bufb[cntb + mbcnt64(mask)] = (((u64)bits) << 32) | idx;
      cntb += __popcll(mask);
      cntb = __builtin_amdgcn_readfirstlane(cntb);
      if (cntb > 64) compact128(bufb, cntb, lob, thrb, lane);
    }
  }
  compact128(bufa, cnta, loa, thra, lane);
  compact128(bufb, cntb, lob, thrb, lane);

  // strip self (d2=0 guarantees membership in the 21); output order irrelevant
  {
    u64 ball = __ballot(((int)(loa & 0xffffffffu) == rowA) && (lane <= KK));
    int p0 = __ffsll((long long)ball) - 1;
    if (p0 < 0) p0 = KK + 1;
    int src = lane + ((lane >= p0) ? 1 : 0);
    u64 outk = shfl64(loa, src);
    if (lane < KK) knn[rowA*KK + lane] = (int)(outk & 0xffffffffu);
  }
  {
    u64 ball = __ballot(((int)(lob & 0xffffffffu) == rowB) && (lane <= KK));
    int p0 = __ffsll((long long)ball) - 1;
    if (p0 < 0) p0 = KK + 1;
    int src = lane + ((lane >= p0) ? 1 : 0);
    u64 outk = shfl64(lob, src);
    if (lane < KK) knn[rowB*KK + lane] = (int)(outk & 0xffffffffu);
  }
}

// forward edge e=(i -> d=knn[i][j]); mutual iff i in knn(d). Non-mutual edges need a CSR slot.
__global__ void count_kernel(const int* __restrict__ knn, int* __restrict__ flags,
                             int* __restrict__ cnt)
{
  int e = blockIdx.x * 256 + threadIdx.x;
  if (e >= N_NODES*KK) return;
  int i = e / KK;
  int d = knn[e];
  int mut = 0;
#pragma unroll
  for (int t = 0; t < KK; t++) mut |= (knn[d*KK + t] == i);
  flags[e] = mut;
  if (!mut) atomicAdd(&cnt[d], 1);
}

__global__ __launch_bounds__(1024) void scan_kernel(const int* __restrict__ cnt,
                                                    int* __restrict__ off)
{
  __shared__ int ssum[1024];
  int tid = threadIdx.x;
  int i0 = tid * 32;
  int loc[32];
  int s = 0;
#pragma unroll
  for (int j = 0; j < 32; j++) { loc[j] = s; s += cnt[i0 + j]; }
  ssum[tid] = s;
  __syncthreads();
  for (int d = 1; d < 1024; d <<= 1) {
    int t = (tid >= d) ? ssum[tid - d] : 0;
    __syncthreads();
    ssum[tid] += t;
    __syncthreads();
  }
  int bse = ssum[tid] - s;             // exclusive base
#pragma unroll
  for (int j = 0; j < 32; j++) off[i0 + j] = bse + loc[j];
  if (tid == 1023) off[N_NODES] = bse + s;
}

__global__ void fill_kernel(const int* __restrict__ knn, const int* __restrict__ flags,
                            const int* __restrict__ off, int* __restrict__ cursor,
                            int* __restrict__ extra)
{
  int e = blockIdx.x * 256 + threadIdx.x;
  if (e >= N_NODES*KK) return;
  if (flags[e]) return;
  int i = e / KK;
  int d = knn[e];
  int p = atomicAdd(&cursor[d], 1);
  extra[off[d] + p] = i;
}

// Y = X @ W (+ bias [*deg]) [+relu]; X:[n,128] W:[128,128] row-major.
template<int RELU, int DEG>
__global__ __launch_bounds__(256) void gemm128(const float* __restrict__ X,
    const float* __restrict__ W, const float* __restrict__ bias,
    const int* __restrict__ offs, float* __restrict__ Y)
{
  __shared__ float xs[64*129];
  __shared__ float ws[8*128];
  const int tid = threadIdx.x;
  const int r0  = blockIdx.x * 64;
  for (int li = tid; li < 64*128; li += 256) {
    int r = li >> 7, c = li & 127;
    xs[r*129 + c] = X[(size_t)(r0 + r)*128 + c];
  }
  const int tr = tid >> 4, tc = tid & 15;
  const int rr0 = tr*4, cc0 = tc*8;
  float acc[4][8];
#pragma unroll
  for (int a = 0; a < 4; a++)
#pragma unroll
    for (int c = 0; c < 8; c++) acc[a][c] = 0.f;

  for (int kb = 0; kb < 16; kb++) {
    __syncthreads();                   // xs ready (kb=0) / prev ws reads done
    for (int li = tid; li < 1024; li += 256) ws[li] = W[kb*1024 + li];
    __syncthreads();
#pragma unroll
    for (int k8 = 0; k8 < 8; k8++) {
      float xa[4];
#pragma unroll
      for (int rr = 0; rr < 4; rr++) xa[rr] = xs[(rr0+rr)*129 + kb*8 + k8];
      float4 wA = *(const float4*)&ws[k8*128 + cc0];
      float4 wB = *(const float4*)&ws[k8*128 + cc0 + 4];
      float wv[8] = {wA.x, wA.y, wA.z, wA.w, wB.x, wB.y, wB.z, wB.w};
#pragma unroll
      for (int rr = 0; rr < 4; rr++)
#pragma unroll
        for (int cc = 0; cc < 8; cc++) acc[rr][cc] += xa[rr] * wv[cc];
    }
  }
#pragma unroll
  for (int rr = 0; rr < 4; rr++) {
    int r = r0 + rr0 + rr;
    float dg = 1.f;
    if (DEG) dg = (float)(KK + offs[r+1] - offs[r]);
    float o[8];
#pragma unroll
    for (int cc = 0; cc < 8; cc++) {
      float vv = acc[rr][cc] + bias[cc0+cc] * dg;
      if (RELU) vv = fmaxf(vv, 0.f);
      o[cc] = vv;
    }
    *(float4*)&Y[(size_t)r*128 + cc0]     = make_float4(o[0], o[1], o[2], o[3]);
    *(float4*)&Y[(size_t)r*128 + cc0 + 4] = make_float4(o[4], o[5], o[6], o[7]);
  }
}

// agg[d] = sum over in-neighbors s of relu(H[s] + (pos[d]-pos[s]) @ Wr); one wave/node.
// XCD swizzle: graph g's blocks land on XCD pair {2g,2g+1} (blockIdx%8 -> XCD heuristic),
// so each graph's 4MB H slab stays in 2 local L2s. Bijection: d=(g,nb) covers all.
__global__ __launch_bounds__(256) void agg_kernel(const float* __restrict__ H,
    const float* __restrict__ pos, const int* __restrict__ knn,
    const int* __restrict__ off, const int* __restrict__ extra,
    const float* __restrict__ Wr, float* __restrict__ agg)
{
  const int lane = threadIdx.x & 63;
  const int dblk = blockIdx.x;
  const int g    = (dblk >> 1) & 3;
  const int nb   = ((dblk >> 3) << 1) | (dblk & 1);
  const int d    = g*NPER + nb*4 + (threadIdx.x >> 6);
  const int c0   = lane * 2;
  const float w0x = Wr[0*DH + c0], w0y = Wr[0*DH + c0 + 1];
  const float w1x = Wr[1*DH + c0], w1y = Wr[1*DH + c0 + 1];
  const float w2x = Wr[2*DH + c0], w2y = Wr[2*DH + c0 + 1];
  const float px = pos[d*3+0], py = pos[d*3+1], pz = pos[d*3+2];
  float a0 = 0.f, a1 = 0.f;
#pragma unroll 4
  for (int t = 0; t < KK; t++) {
    int s = knn[d*KK + t];
    float rx = px - pos[s*3+0];
    float ry = py - pos[s*3+1];
    float rz = pz - pos[s*3+2];
    float2 h = *(const float2*)&H[(size_t)s*DH + c0];
    float m0 = h.x + rx*w0x + ry*w1x + rz*w2x;
    float m1 = h.y + rx*w0y + ry*w1y + rz*w2y;
    a0 += fmaxf(m0, 0.f);
    a1 += fmaxf(m1, 0.f);
  }
  const int e0 = off[d], e1 = off[d+1];
  for (int t = e0; t < e1; t++) {
    int s = extra[t];
    float rx = px - pos[s*3+0];
    float ry = py - pos[s*3+1];
    float rz = pz - pos[s*3+2];
    float2 h = *(const float2*)&H[(size_t)s*DH + c0];
    float m0 = h.x + rx*w0x + ry*w1x + rz*w2x;
    float m1 = h.y + rx*w0y + ry*w1y + rz*w2y;
    a0 += fmaxf(m0, 0.f);
    a1 += fmaxf(m1, 0.f);
  }
  *(float2*)&agg[(size_t)d*DH + c0] = make_float2(a0, a1);
}

// logits = X @ Wf + bf; per-graph softmax over 8192 nodes.
__global__ __launch_bounds__(1024) void final_kernel(const float* __restrict__ X,
    const float* __restrict__ Wf, const float* __restrict__ bf, float* __restrict__ out)
{
  __shared__ float red[16];
  __shared__ float bcast;
  const int g = blockIdx.x, tid = threadIdx.x;
  const int lane = tid & 63, wid = tid >> 6;
  float lg[8];
#pragma unroll
  for (int k = 0; k < 8; k++) {
    int n = g*NPER + k*1024 + tid;
    const float4* xr = (const float4*)&X[(size_t)n*128];
    float acc = 0.f;
#pragma unroll 8
    for (int q = 0; q < 32; q++) {
      float4 xv = xr[q];
      float4 wv = *(const float4*)&Wf[q*4];
      acc += xv.x*wv.x + xv.y*wv.y + xv.z*wv.z + xv.w*wv.w;
    }
    lg[k] = acc + bf[0];
  }
  float m = lg[0];
#pragma unroll
  for (int k = 1; k < 8; k++) m = fmaxf(m, lg[k]);
  for (int o = 1; o < 64; o <<= 1) m = fmaxf(m, __shfl_xor(m, o, 64));
  if (lane == 0) red[wid] = m;
  __syncthreads();
  if (tid == 0) {
    float mm = red[0];
    for (int i = 1; i < 16; i++) mm = fmaxf(mm, red[i]);
    bcast = mm;
  }
  __syncthreads();
  const float M = bcast;
  float e[8];
  float s = 0.f;
#pragma unroll
  for (int k = 0; k < 8; k++) { e[k] = expf(lg[k] - M); s += e[k]; }
  for (int o = 1; o < 64; o <<= 1) s += __shfl_xor(s, o, 64);
  __syncthreads();
  if (lane == 0) red[wid] = s;
  __syncthreads();
  if (tid == 0) {
    float ss = 0.f;
    for (int i = 0; i < 16; i++) ss += red[i];
    bcast = ss;
  }
  __syncthreads();
  const float S = bcast;
#pragma unroll
  for (int k = 0; k < 8; k++) {
    int n = g*NPER + k*1024 + tid;
    out[n] = e[k] / S;
  }
}

extern "C" void kernel_launch(void* const* d_in, const int* in_sizes, int n_in,
                              void* d_out, int out_size, void* d_ws, size_t ws_size,
                              hipStream_t stream)
{
  const float* x   = (const float*)d_in[0];
  const float* pos = (const float*)d_in[1];
  // d_in[2] = batch (unused: sorted, equal-size graphs)
  const float* W1s = (const float*)d_in[3];
  const float* b1s = (const float*)d_in[4];
  const float* W2s = (const float*)d_in[5];
  const float* b2s = (const float*)d_in[6];
  const float* Wf  = (const float*)d_in[7];
  const float* bf  = (const float*)d_in[8];
  float* out = (float*)d_out;

  char* wsb = (char*)d_ws;
  size_t o = 0;
  auto alloc = [&](size_t bytes) { void* p = wsb + o; o += (bytes + 255) & ~255ull; return p; };
  int*   knn    = (int*)  alloc((size_t)N_NODES*KK*4);
  int*   flags  = (int*)  alloc((size_t)N_NODES*KK*4);
  int*   cnt    = (int*)  alloc((size_t)(N_NODES+1)*4);
  int*   off    = (int*)  alloc((size_t)(N_NODES+1)*4);
  int*   cursor = (int*)  alloc((size_t)N_NODES*4);
  int*   extra  = (int*)  alloc((size_t)N_NODES*KK*4);
  float* H      = (float*)alloc((size_t)N_NODES*DH*4);
  float* agg    = (float*)alloc((size_t)N_NODES*DH*4);
  float* xbuf   = (float*)alloc((size_t)N_NODES*DH*4);
  (void)ws_size; (void)in_sizes; (void)n_in; (void)out_size;

  hipMemsetAsync(cnt,    0, (size_t)(N_NODES+1)*4, stream);
  hipMemsetAsync(cursor, 0, (size_t)N_NODES*4,     stream);

  knn_kernel <<<N_NODES/8, 256, 0, stream>>>(pos, knn);
  count_kernel<<<(N_NODES*KK + 255)/256, 256, 0, stream>>>(knn, flags, cnt);
  scan_kernel<<<1, 1024, 0, stream>>>(cnt, off);
  fill_kernel<<<(N_NODES*KK + 255)/256, 256, 0, stream>>>(knn, flags, off, cursor, extra);

  const float* xin = x;
  for (int l = 0; l < 3; l++) {
    const float* W1 = W1s + (size_t)l*131*128;   // rows 0..127: x-part
    const float* Wr = W1 + 128*128;              // rows 128..130: rel-part
    const float* b1 = b1s + l*128;
    const float* W2 = W2s + (size_t)l*128*128;
    const float* b2 = b2s + l*128;
    gemm128<0,0><<<N_NODES/64, 256, 0, stream>>>(xin, W1, b1, nullptr, H);
    agg_kernel  <<<N_NODES/4,  256, 0, stream>>>(H, pos, knn, off, extra, Wr, agg);
    gemm128<1,1><<<N_NODES/64, 256, 0, stream>>>(agg, W2, b2, off, xbuf);
    xin = xbuf;
  }
  final_kernel<<<NB, 1024, 0, stream>>>(xbuf, Wf, bf, out);
}

// Round 11
// 755.892 us; speedup vs baseline: 1.9556x; 1.0117x over previous
//
#include <hip/hip_runtime.h>
#include <stdint.h>

#define N_NODES 32768
#define NPER    8192
#define NB      4
#define KK      20
#define DH      128

typedef unsigned long long u64;

__device__ __forceinline__ u64 shflx64(u64 x, int m) {
  unsigned lo = __shfl_xor((unsigned)(x & 0xffffffffu), m, 64);
  unsigned hi = __shfl_xor((unsigned)(x >> 32), m, 64);
  return (((u64)hi) << 32) | lo;
}
__device__ __forceinline__ u64 shfl64(u64 x, int src) {
  unsigned lo = __shfl((unsigned)(x & 0xffffffffu), src, 64);
  unsigned hi = __shfl((unsigned)(x >> 32), src, 64);
  return (((u64)hi) << 32) | lo;
}
__device__ __forceinline__ int mbcnt64(u64 mask) {
  return __builtin_amdgcn_mbcnt_hi((unsigned)(mask >> 32),
         __builtin_amdgcn_mbcnt_lo((unsigned)mask, 0u));
}
// 64-lane bitonic sort, ascending across lanes
__device__ __forceinline__ u64 bsort64(u64 key, int lane) {
#pragma unroll
  for (int k = 2; k <= 64; k <<= 1) {
#pragma unroll
    for (int j = k >> 1; j >= 1; j >>= 1) {
      u64 other = shflx64(key, j);
      bool up = ((lane & k) == 0);
      bool keepmin = (((lane & j) == 0) == up);
      bool take = keepmin ? (other < key) : (other > key);
      key = take ? other : key;
    }
  }
  return key;
}
// bitonic merge-clean (input bitonic, output ascending)
__device__ __forceinline__ u64 bclean64(u64 key, int lane) {
#pragma unroll
  for (int j = 32; j >= 1; j >>= 1) {
    u64 other = shflx64(key, j);
    bool keepmin = ((lane & j) == 0);
    bool take = keepmin ? (other < key) : (other > key);
    key = take ? other : key;
  }
  return key;
}

// compact <=128 buffered keys -> sorted 21 smallest (lanes 0..20 of lo), tighten thr
__device__ __forceinline__ void compact128(u64* bufr, int& cnt, u64& lo,
                                           unsigned& thr, int lane) {
  asm volatile("s_waitcnt lgkmcnt(0)" ::: "memory");
  u64 k0 = (lane      < cnt) ? bufr[lane]      : ~0ull;
  u64 k1 = (lane + 64 < cnt) ? bufr[lane + 64] : ~0ull;
  k0 = bsort64(k0, lane);
  k1 = bsort64(k1, lane);
  u64 k1r = shfl64(k1, 63 - lane);          // descending copy of k1
  lo = (k1r < k0) ? k1r : k0;               // half-cleaner: 64 smallest, bitonic
  lo = bclean64(lo, lane);                  // sorted ascending
  thr = (unsigned)(shfl64(lo, KK) >> 32);   // d2-bits of 21st smallest (incl self)
  if (lane <= KK) bufr[lane] = lo;          // keep 21
  cnt = KK + 1;
  asm volatile("s_waitcnt lgkmcnt(0)" ::: "memory");
}

// One wave per TWO consecutive rows; each lane handles FOUR consecutive candidates
// per iteration (48B contiguous per lane = 3x float4, coalesced). Fast path: 4 d2 ->
// v_min tree -> ONE compare + __any vote per row. Slow path (rare once thr tight):
// per-candidate ballot append, compact trigger checked per sub-step. Self (d2=0)
// flows through, stripped at output. Exact top-20 by (d2, idx).
__global__ __launch_bounds__(256) void knn_kernel(const float* __restrict__ pos,
                                                  int* __restrict__ knn)
{
  __shared__ u64 buf[8][128];

  const int lane = threadIdx.x & 63;
  const int w    = threadIdx.x >> 6;
  const int rowA = blockIdx.x * 8 + w * 2;
  const int rowB = rowA + 1;
  const int base = (rowA >> 13) << 13;   // graph start

  const float ax = pos[rowA*3+0], ay = pos[rowA*3+1], az = pos[rowA*3+2];
  const float bx = pos[rowB*3+0], by = pos[rowB*3+1], bz = pos[rowB*3+2];

  unsigned thra = 0xffffffffu, thrb = 0xffffffffu;
  int cnta = 0, cntb = 0;
  u64 loa = ~0ull, lob = ~0ull;
  u64* bufa = buf[w*2+0];
  u64* bufb = buf[w*2+1];

  const float4* __restrict__ p4 = (const float4*)(pos + (size_t)base*3);
  for (int it = 0; it < 32; it++) {
    const int c0 = it*256 + lane*4;            // 4 consecutive candidates
    const int f4 = it*192 + lane*3;            // float4 index of candidate block
    float4 q0 = p4[f4+0];
    float4 q1 = p4[f4+1];
    float4 q2 = p4[f4+2];
    const float X[4] = {q0.x, q0.w, q1.z, q2.y};
    const float Y[4] = {q0.y, q1.x, q1.w, q2.z};
    const float Z[4] = {q0.z, q1.y, q2.x, q2.w};

    float dA[4], dB[4];
#pragma unroll
    for (int r = 0; r < 4; r++) {
      float dx = ax - X[r], dy = ay - Y[r], dz = az - Z[r];
      dA[r] = fmaf(dx, dx, fmaf(dy, dy, dz*dz));
      float ex = bx - X[r], ey = by - Y[r], ez = bz - Z[r];
      dB[r] = fmaf(ex, ex, fmaf(ey, ey, ez*ez));
    }
    float mnA = fminf(fminf(dA[0], dA[1]), fminf(dA[2], dA[3]));
    float mnB = fminf(fminf(dB[0], dB[1]), fminf(dB[2], dB[3]));

    if (__any(__float_as_uint(mnA) <= thra)) {
#pragma unroll
      for (int r = 0; r < 4; r++) {
        unsigned bits = __float_as_uint(dA[r]);
        bool pred = (bits <= thra);
        u64 mask = __ballot(pred);
        if (pred) bufa[cnta + mbcnt64(mask)] =
            (((u64)bits) << 32) | (unsigned)(base + c0 + r);
        cnta += __popcll(mask);
        cnta = __builtin_amdgcn_readfirstlane(cnta);
        if (cnta > 64) compact128(bufa, cnta, loa, thra, lane);
      }
    }
    if (__any(__float_as_uint(mnB) <= thrb)) {
#pragma unroll
      for (int r = 0; r < 4; r++) {
        unsigned bits = __float_as_uint(dB[r]);
        bool pred = (bits <= thrb);
        u64 mask = __ballot(pred);
        if (pred) bufb[cntb + mbcnt64(mask)] =
            (((u64)bits) << 32) | (unsigned)(base + c0 + r);
        cntb += __popcll(mask);
        cntb = __builtin_amdgcn_readfirstlane(cntb);
        if (cntb > 64) compact128(bufb, cntb, lob, thrb, lane);
      }
    }
  }
  compact128(bufa, cnta, loa, thra, lane);
  compact128(bufb, cntb, lob, thrb, lane);

  // strip self (d2=0 guarantees membership in the 21); output order irrelevant
  {
    u64 ball = __ballot(((int)(loa & 0xffffffffu) == rowA) && (lane <= KK));
    int p0 = __ffsll((long long)ball) - 1;
    if (p0 < 0) p0 = KK + 1;
    int src = lane + ((lane >= p0) ? 1 : 0);
    u64 outk = shfl64(loa, src);
    if (lane < KK) knn[rowA*KK + lane] = (int)(outk & 0xffffffffu);
  }
  {
    u64 ball = __ballot(((int)(lob & 0xffffffffu) == rowB) && (lane <= KK));
    int p0 = __ffsll((long long)ball) - 1;
    if (p0 < 0) p0 = KK + 1;
    int src = lane + ((lane >= p0) ? 1 : 0);
    u64 outk = shfl64(lob, src);
    if (lane < KK) knn[rowB*KK + lane] = (int)(outk & 0xffffffffu);
  }
}

// forward edge e=(i -> d=knn[i][j]); mutual iff i in knn(d). Non-mutual edges need a CSR slot.
__global__ void count_kernel(const int* __restrict__ knn, int* __restrict__ flags,
                             int* __restrict__ cnt)
{
  int e = blockIdx.x * 256 + threadIdx.x;
  if (e >= N_NODES*KK) return;
  int i = e / KK;
  int d = knn[e];
  int mut = 0;
#pragma unroll
  for (int t = 0; t < KK; t++) mut |= (knn[d*KK + t] == i);
  flags[e] = mut;
  if (!mut) atomicAdd(&cnt[d], 1);
}

__global__ __launch_bounds__(1024) void scan_kernel(const int* __restrict__ cnt,
                                                    int* __restrict__ off)
{
  __shared__ int ssum[1024];
  int tid = threadIdx.x;
  int i0 = tid * 32;
  int loc[32];
  int s = 0;
#pragma unroll
  for (int j = 0; j < 32; j++) { loc[j] = s; s += cnt[i0 + j]; }
  ssum[tid] = s;
  __syncthreads();
  for (int d = 1; d < 1024; d <<= 1) {
    int t = (tid >= d) ? ssum[tid - d] : 0;
    __syncthreads();
    ssum[tid] += t;
    __syncthreads();
  }
  int bse = ssum[tid] - s;             // exclusive base
#pragma unroll
  for (int j = 0; j < 32; j++) off[i0 + j] = bse + loc[j];
  if (tid == 1023) off[N_NODES] = bse + s;
}

__global__ void fill_kernel(const int* __restrict__ knn, const int* __restrict__ flags,
                            const int* __restrict__ off, int* __restrict__ cursor,
                            int* __restrict__ extra)
{
  int e = blockIdx.x * 256 + threadIdx.x;
  if (e >= N_NODES*KK) return;
  if (flags[e]) return;
  int i = e / KK;
  int d = knn[e];
  int p = atomicAdd(&cursor[d], 1);
  extra[off[d] + p] = i;
}

// Y = X @ W (+ bias [*deg]) [+relu]; X:[n,128] W:[128,128] row-major.
template<int RELU, int DEG>
__global__ __launch_bounds__(256) void gemm128(const float* __restrict__ X,
    const float* __restrict__ W, const float* __restrict__ bias,
    const int* __restrict__ offs, float* __restrict__ Y)
{
  __shared__ float xs[64*129];
  __shared__ float ws[8*128];
  const int tid = threadIdx.x;
  const int r0  = blockIdx.x * 64;
  for (int li = tid; li < 64*128; li += 256) {
    int r = li >> 7, c = li & 127;
    xs[r*129 + c] = X[(size_t)(r0 + r)*128 + c];
  }
  const int tr = tid >> 4, tc = tid & 15;
  const int rr0 = tr*4, cc0 = tc*8;
  float acc[4][8];
#pragma unroll
  for (int a = 0; a < 4; a++)
#pragma unroll
    for (int c = 0; c < 8; c++) acc[a][c] = 0.f;

  for (int kb = 0; kb < 16; kb++) {
    __syncthreads();                   // xs ready (kb=0) / prev ws reads done
    for (int li = tid; li < 1024; li += 256) ws[li] = W[kb*1024 + li];
    __syncthreads();
#pragma unroll
    for (int k8 = 0; k8 < 8; k8++) {
      float xa[4];
#pragma unroll
      for (int rr = 0; rr < 4; rr++) xa[rr] = xs[(rr0+rr)*129 + kb*8 + k8];
      float4 wA = *(const float4*)&ws[k8*128 + cc0];
      float4 wB = *(const float4*)&ws[k8*128 + cc0 + 4];
      float wv[8] = {wA.x, wA.y, wA.z, wA.w, wB.x, wB.y, wB.z, wB.w};
#pragma unroll
      for (int rr = 0; rr < 4; rr++)
#pragma unroll
        for (int cc = 0; cc < 8; cc++) acc[rr][cc] += xa[rr] * wv[cc];
    }
  }
#pragma unroll
  for (int rr = 0; rr < 4; rr++) {
    int r = r0 + rr0 + rr;
    float dg = 1.f;
    if (DEG) dg = (float)(KK + offs[r+1] - offs[r]);
    float o[8];
#pragma unroll
    for (int cc = 0; cc < 8; cc++) {
      float vv = acc[rr][cc] + bias[cc0+cc] * dg;
      if (RELU) vv = fmaxf(vv, 0.f);
      o[cc] = vv;
    }
    *(float4*)&Y[(size_t)r*128 + cc0]     = make_float4(o[0], o[1], o[2], o[3]);
    *(float4*)&Y[(size_t)r*128 + cc0 + 4] = make_float4(o[4], o[5], o[6], o[7]);
  }
}

// agg[d] = sum over in-neighbors s of relu(H[s] + (pos[d]-pos[s]) @ Wr); one wave/node.
// XCD swizzle: graph g's blocks land on XCD pair {2g,2g+1} (blockIdx%8 -> XCD heuristic),
// so each graph's 4MB H slab stays in 2 local L2s. Bijection: d=(g,nb) covers all.
__global__ __launch_bounds__(256) void agg_kernel(const float* __restrict__ H,
    const float* __restrict__ pos, const int* __restrict__ knn,
    const int* __restrict__ off, const int* __restrict__ extra,
    const float* __restrict__ Wr, float* __restrict__ agg)
{
  const int lane = threadIdx.x & 63;
  const int dblk = blockIdx.x;
  const int g    = (dblk >> 1) & 3;
  const int nb   = ((dblk >> 3) << 1) | (dblk & 1);
  const int d    = g*NPER + nb*4 + (threadIdx.x >> 6);
  const int c0   = lane * 2;
  const float w0x = Wr[0*DH + c0], w0y = Wr[0*DH + c0 + 1];
  const float w1x = Wr[1*DH + c0], w1y = Wr[1*DH + c0 + 1];
  const float w2x = Wr[2*DH + c0], w2y = Wr[2*DH + c0 + 1];
  const float px = pos[d*3+0], py = pos[d*3+1], pz = pos[d*3+2];
  float a0 = 0.f, a1 = 0.f;
#pragma unroll 4
  for (int t = 0; t < KK; t++) {
    int s = knn[d*KK + t];
    float rx = px - pos[s*3+0];
    float ry = py - pos[s*3+1];
    float rz = pz - pos[s*3+2];
    float2 h = *(const float2*)&H[(size_t)s*DH + c0];
    float m0 = h.x + rx*w0x + ry*w1x + rz*w2x;
    float m1 = h.y + rx*w0y + ry*w1y + rz*w2y;
    a0 += fmaxf(m0, 0.f);
    a1 += fmaxf(m1, 0.f);
  }
  const int e0 = off[d], e1 = off[d+1];
  for (int t = e0; t < e1; t++) {
    int s = extra[t];
    float rx = px - pos[s*3+0];
    float ry = py - pos[s*3+1];
    float rz = pz - pos[s*3+2];
    float2 h = *(const float2*)&H[(size_t)s*DH + c0];
    float m0 = h.x + rx*w0x + ry*w1x + rz*w2x;
    float m1 = h.y + rx*w0y + ry*w1y + rz*w2y;
    a0 += fmaxf(m0, 0.f);
    a1 += fmaxf(m1, 0.f);
  }
  *(float2*)&agg[(size_t)d*DH + c0] = make_float2(a0, a1);
}

// logits = X @ Wf + bf; per-graph softmax over 8192 nodes.
__global__ __launch_bounds__(1024) void final_kernel(const float* __restrict__ X,
    const float* __restrict__ Wf, const float* __restrict__ bf, float* __restrict__ out)
{
  __shared__ float red[16];
  __shared__ float bcast;
  const int g = blockIdx.x, tid = threadIdx.x;
  const int lane = tid & 63, wid = tid >> 6;
  float lg[8];
#pragma unroll
  for (int k = 0; k < 8; k++) {
    int n = g*NPER + k*1024 + tid;
    const float4* xr = (const float4*)&X[(size_t)n*128];
    float acc = 0.f;
#pragma unroll 8
    for (int q = 0; q < 32; q++) {
      float4 xv = xr[q];
      float4 wv = *(const float4*)&Wf[q*4];
      acc += xv.x*wv.x + xv.y*wv.y + xv.z*wv.z + xv.w*wv.w;
    }
    lg[k] = acc + bf[0];
  }
  float m = lg[0];
#pragma unroll
  for (int k = 1; k < 8; k++) m = fmaxf(m, lg[k]);
  for (int o = 1; o < 64; o <<= 1) m = fmaxf(m, __shfl_xor(m, o, 64));
  if (lane == 0) red[wid] = m;
  __syncthreads();
  if (tid == 0) {
    float mm = red[0];
    for (int i = 1; i < 16; i++) mm = fmaxf(mm, red[i]);
    bcast = mm;
  }
  __syncthreads();
  const float M = bcast;
  float e[8];
  float s = 0.f;
#pragma unroll
  for (int k = 0; k < 8; k++) { e[k] = expf(lg[k] - M); s += e[k]; }
  for (int o = 1; o < 64; o <<= 1) s += __shfl_xor(s, o, 64);
  __syncthreads();
  if (lane == 0) red[wid] = s;
  __syncthreads();
  if (tid == 0) {
    float ss = 0.f;
    for (int i = 0; i < 16; i++) ss += red[i];
    bcast = ss;
  }
  __syncthreads();
  const float S = bcast;
#pragma unroll
  for (int k = 0; k < 8; k++) {
    int n = g*NPER + k*1024 + tid;
    out[n] = e[k] / S;
  }
}

extern "C" void kernel_launch(void* const* d_in, const int* in_sizes, int n_in,
                              void* d_out, int out_size, void* d_ws, size_t ws_size,
                              hipStream_t stream)
{
  const float* x   = (const float*)d_in[0];
  const float* pos = (const float*)d_in[1];
  // d_in[2] = batch (unused: sorted, equal-size graphs)
  const float* W1s = (const float*)d_in[3];
  const float* b1s = (const float*)d_in[4];
  const float* W2s = (const float*)d_in[5];
  const float* b2s = (const float*)d_in[6];
  const float* Wf  = (const float*)d_in[7];
  const float* bf  = (const float*)d_in[8];
  float* out = (float*)d_out;

  char* wsb = (char*)d_ws;
  size_t o = 0;
  auto alloc = [&](size_t bytes) { void* p = wsb + o; o += (bytes + 255) & ~255ull; return p; };
  int*   knn    = (int*)  alloc((size_t)N_NODES*KK*4);
  int*   flags  = (int*)  alloc((size_t)N_NODES*KK*4);
  int*   cnt    = (int*)  alloc((size_t)(N_NODES+1)*4);
  int*   off    = (int*)  alloc((size_t)(N_NODES+1)*4);
  int*   cursor = (int*)  alloc((size_t)N_NODES*4);
  int*   extra  = (int*)  alloc((size_t)N_NODES*KK*4);
  float* H      = (float*)alloc((size_t)N_NODES*DH*4);
  float* agg    = (float*)alloc((size_t)N_NODES*DH*4);
  float* xbuf   = (float*)alloc((size_t)N_NODES*DH*4);
  (void)ws_size; (void)in_sizes; (void)n_in; (void)out_size;

  hipMemsetAsync(cnt,    0, (size_t)(N_NODES+1)*4, stream);
  hipMemsetAsync(cursor, 0, (size_t)N_NODES*4,     stream);

  knn_kernel <<<N_NODES/8, 256, 0, stream>>>(pos, knn);
  count_kernel<<<(N_NODES*KK + 255)/256, 256, 0, stream>>>(knn, flags, cnt);
  scan_kernel<<<1, 1024, 0, stream>>>(cnt, off);
  fill_kernel<<<(N_NODES*KK + 255)/256, 256, 0, stream>>>(knn, flags, off, cursor, extra);

  const float* xin = x;
  for (int l = 0; l < 3; l++) {
    const float* W1 = W1s + (size_t)l*131*128;   // rows 0..127: x-part
    const float* Wr = W1 + 128*128;              // rows 128..130: rel-part
    const float* b1 = b1s + l*128;
    const float* W2 = W2s + (size_t)l*128*128;
    const float* b2 = b2s + l*128;
    gemm128<0,0><<<N_NODES/64, 256, 0, stream>>>(xin, W1, b1, nullptr, H);
    agg_kernel  <<<N_NODES/4,  256, 0, stream>>>(H, pos, knn, off, extra, Wr, agg);
    gemm128<1,1><<<N_NODES/64, 256, 0, stream>>>(agg, W2, b2, off, xbuf);
    xin = xbuf;
  }
  final_kernel<<<NB, 1024, 0, stream>>>(xbuf, Wf, bf, out);
}

// Round 12
// 678.219 us; speedup vs baseline: 2.1795x; 1.1145x over previous
//
#include <hip/hip_runtime.h>
#include <stdint.h>

#define N_NODES 32768
#define NPER    8192
#define NB      4
#define KK      20
#define DH      128

typedef unsigned long long u64;

__device__ __forceinline__ u64 shflx64(u64 x, int m) {
  unsigned lo = __shfl_xor((unsigned)(x & 0xffffffffu), m, 64);
  unsigned hi = __shfl_xor((unsigned)(x >> 32), m, 64);
  return (((u64)hi) << 32) | lo;
}
__device__ __forceinline__ u64 shfl64(u64 x, int src) {
  unsigned lo = __shfl((unsigned)(x & 0xffffffffu), src, 64);
  unsigned hi = __shfl((unsigned)(x >> 32), src, 64);
  return (((u64)hi) << 32) | lo;
}
__device__ __forceinline__ int mbcnt64(u64 mask) {
  return __builtin_amdgcn_mbcnt_hi((unsigned)(mask >> 32),
         __builtin_amdgcn_mbcnt_lo((unsigned)mask, 0u));
}
// 64-lane bitonic sort, ascending across lanes (u64 keys)
__device__ __forceinline__ u64 bsort64(u64 key, int lane) {
#pragma unroll
  for (int k = 2; k <= 64; k <<= 1) {
#pragma unroll
    for (int j = k >> 1; j >= 1; j >>= 1) {
      u64 other = shflx64(key, j);
      bool up = ((lane & k) == 0);
      bool keepmin = (((lane & j) == 0) == up);
      bool take = keepmin ? (other < key) : (other > key);
      key = take ? other : key;
    }
  }
  return key;
}
// 64-lane bitonic sort, ascending, u32 keys (half the shuffle cost)
__device__ __forceinline__ unsigned bsortu32(unsigned key, int lane) {
#pragma unroll
  for (int k = 2; k <= 64; k <<= 1) {
#pragma unroll
    for (int j = k >> 1; j >= 1; j >>= 1) {
      unsigned other = (unsigned)__shfl_xor((int)key, j, 64);
      bool up = ((lane & k) == 0);
      bool keepmin = (((lane & j) == 0) == up);
      bool take = keepmin ? (other < key) : (other > key);
      key = take ? other : key;
    }
  }
  return key;
}
// bitonic merge-clean (input bitonic, output ascending)
__device__ __forceinline__ u64 bclean64(u64 key, int lane) {
#pragma unroll
  for (int j = 32; j >= 1; j >>= 1) {
    u64 other = shflx64(key, j);
    bool keepmin = ((lane & j) == 0);
    bool take = keepmin ? (other < key) : (other > key);
    key = take ? other : key;
  }
  return key;
}

// Fold <=64 NEW buffered keys into register-kept sorted list lo (21 valid + pad):
// one bsort64 of the new keys, half-cleaner merge vs lo, bclean. Tighten thr.
__device__ __forceinline__ void compact64(u64* bufr, int& cnt, u64& lo,
                                          unsigned& thr, int lane) {
  asm volatile("s_waitcnt lgkmcnt(0)" ::: "memory");
  u64 k = (lane < cnt) ? bufr[lane] : ~0ull;
  k = bsort64(k, lane);                     // new keys ascending
  u64 kr = shfl64(k, 63 - lane);            // descending copy
  u64 m = (kr < lo) ? kr : lo;              // half-cleaner: 64 smallest of 128, bitonic
  lo = bclean64(m, lane);                   // sorted ascending
  thr = (unsigned)(shfl64(lo, KK) >> 32);   // d2-bits of 21st smallest (incl self)
  cnt = 0;
  asm volatile("s_waitcnt lgkmcnt(0)" ::: "memory");
}

// One wave per TWO consecutive rows; each lane handles FOUR consecutive candidates
// per iteration (48B contiguous = 3x float4, coalesced). Threshold PRIMED from
// iteration-0 lane-mins (21st smallest lane-min >= 21st smallest of 256 => valid
// superset bound). Sorted top-21 lives in registers (lo); LDS buffer holds only
// new appends (<=64); compact triggered BEFORE append when cnt+popc would overflow.
// Self (d2=0) flows through, stripped at output. Exact top-20 by (d2, idx).
__global__ __launch_bounds__(256) void knn_kernel(const float* __restrict__ pos,
                                                  int* __restrict__ knn)
{
  __shared__ u64 buf[8][64];

  const int lane = threadIdx.x & 63;
  const int w    = threadIdx.x >> 6;
  const int rowA = blockIdx.x * 8 + w * 2;
  const int rowB = rowA + 1;
  const int base = (rowA >> 13) << 13;   // graph start

  const float ax = pos[rowA*3+0], ay = pos[rowA*3+1], az = pos[rowA*3+2];
  const float bx = pos[rowB*3+0], by = pos[rowB*3+1], bz = pos[rowB*3+2];

  unsigned thra, thrb;
  int cnta = 0, cntb = 0;
  u64 loa = ~0ull, lob = ~0ull;
  u64* bufa = buf[w*2+0];
  u64* bufb = buf[w*2+1];

  const float4* __restrict__ p4 = (const float4*)(pos + (size_t)base*3);

  // ---- prime thresholds from iteration-0 candidates (lane-min upper bound) ----
  {
    float4 q0 = p4[lane*3+0];
    float4 q1 = p4[lane*3+1];
    float4 q2 = p4[lane*3+2];
    const float X[4] = {q0.x, q0.w, q1.z, q2.y};
    const float Y[4] = {q0.y, q1.x, q1.w, q2.z};
    const float Z[4] = {q0.z, q1.y, q2.x, q2.w};
    float mA = 3.4e38f, mB = 3.4e38f;
#pragma unroll
    for (int r = 0; r < 4; r++) {
      float dx = ax - X[r], dy = ay - Y[r], dz = az - Z[r];
      mA = fminf(mA, fmaf(dx, dx, fmaf(dy, dy, dz*dz)));
      float ex = bx - X[r], ey = by - Y[r], ez = bz - Z[r];
      mB = fminf(mB, fmaf(ex, ex, fmaf(ey, ey, ez*ez)));
    }
    unsigned sA = bsortu32(__float_as_uint(mA), lane);
    unsigned sB = bsortu32(__float_as_uint(mB), lane);
    thra = (unsigned)__shfl((int)sA, KK, 64);   // 21st smallest lane-min
    thrb = (unsigned)__shfl((int)sB, KK, 64);
  }

  for (int it = 0; it < 32; it++) {
    const int c0 = it*256 + lane*4;            // 4 consecutive candidates
    const int f4 = it*192 + lane*3;            // float4 index of candidate block
    float4 q0 = p4[f4+0];
    float4 q1 = p4[f4+1];
    float4 q2 = p4[f4+2];
    const float X[4] = {q0.x, q0.w, q1.z, q2.y};
    const float Y[4] = {q0.y, q1.x, q1.w, q2.z};
    const float Z[4] = {q0.z, q1.y, q2.x, q2.w};

    float dA[4], dB[4];
#pragma unroll
    for (int r = 0; r < 4; r++) {
      float dx = ax - X[r], dy = ay - Y[r], dz = az - Z[r];
      dA[r] = fmaf(dx, dx, fmaf(dy, dy, dz*dz));
      float ex = bx - X[r], ey = by - Y[r], ez = bz - Z[r];
      dB[r] = fmaf(ex, ex, fmaf(ey, ey, ez*ez));
    }
    float mnA = fminf(fminf(dA[0], dA[1]), fminf(dA[2], dA[3]));
    float mnB = fminf(fminf(dB[0], dB[1]), fminf(dB[2], dB[3]));

    if (__any(__float_as_uint(mnA) <= thra)) {
#pragma unroll
      for (int r = 0; r < 4; r++) {
        unsigned bits = __float_as_uint(dA[r]);
        bool pred = (bits <= thra);
        u64 mask = __ballot(pred);
        int pc = __popcll(mask);
        if (cnta + pc > 64) compact64(bufa, cnta, loa, thra, lane);
        if (pred) bufa[cnta + mbcnt64(mask)] =
            (((u64)bits) << 32) | (unsigned)(base + c0 + r);
        cnta = __builtin_amdgcn_readfirstlane(cnta + pc);
      }
    }
    if (__any(__float_as_uint(mnB) <= thrb)) {
#pragma unroll
      for (int r = 0; r < 4; r++) {
        unsigned bits = __float_as_uint(dB[r]);
        bool pred = (bits <= thrb);
        u64 mask = __ballot(pred);
        int pc = __popcll(mask);
        if (cntb + pc > 64) compact64(bufb, cntb, lob, thrb, lane);
        if (pred) bufb[cntb + mbcnt64(mask)] =
            (((u64)bits) << 32) | (unsigned)(base + c0 + r);
        cntb = __builtin_amdgcn_readfirstlane(cntb + pc);
      }
    }
  }
  compact64(bufa, cnta, loa, thra, lane);
  compact64(bufb, cntb, lob, thrb, lane);

  // strip self (d2=0 guarantees membership in the 21); output order irrelevant
  {
    u64 ball = __ballot(((int)(loa & 0xffffffffu) == rowA) && (lane <= KK));
    int p0 = __ffsll((long long)ball) - 1;
    if (p0 < 0) p0 = KK + 1;
    int src = lane + ((lane >= p0) ? 1 : 0);
    u64 outk = shfl64(loa, src);
    if (lane < KK) knn[rowA*KK + lane] = (int)(outk & 0xffffffffu);
  }
  {
    u64 ball = __ballot(((int)(lob & 0xffffffffu) == rowB) && (lane <= KK));
    int p0 = __ffsll((long long)ball) - 1;
    if (p0 < 0) p0 = KK + 1;
    int src = lane + ((lane >= p0) ? 1 : 0);
    u64 outk = shfl64(lob, src);
    if (lane < KK) knn[rowB*KK + lane] = (int)(outk & 0xffffffffu);
  }
}

// forward edge e=(i -> d=knn[i][j]); mutual iff i in knn(d). Non-mutual edges need a CSR slot.
__global__ void count_kernel(const int* __restrict__ knn, int* __restrict__ flags,
                             int* __restrict__ cnt)
{
  int e = blockIdx.x * 256 + threadIdx.x;
  if (e >= N_NODES*KK) return;
  int i = e / KK;
  int d = knn[e];
  int mut = 0;
#pragma unroll
  for (int t = 0; t < KK; t++) mut |= (knn[d*KK + t] == i);
  flags[e] = mut;
  if (!mut) atomicAdd(&cnt[d], 1);
}

__global__ __launch_bounds__(1024) void scan_kernel(const int* __restrict__ cnt,
                                                    int* __restrict__ off)
{
  __shared__ int ssum[1024];
  int tid = threadIdx.x;
  int i0 = tid * 32;
  int loc[32];
  int s = 0;
#pragma unroll
  for (int j = 0; j < 32; j++) { loc[j] = s; s += cnt[i0 + j]; }
  ssum[tid] = s;
  __syncthreads();
  for (int d = 1; d < 1024; d <<= 1) {
    int t = (tid >= d) ? ssum[tid - d] : 0;
    __syncthreads();
    ssum[tid] += t;
    __syncthreads();
  }
  int bse = ssum[tid] - s;             // exclusive base
#pragma unroll
  for (int j = 0; j < 32; j++) off[i0 + j] = bse + loc[j];
  if (tid == 1023) off[N_NODES] = bse + s;
}

__global__ void fill_kernel(const int* __restrict__ knn, const int* __restrict__ flags,
                            const int* __restrict__ off, int* __restrict__ cursor,
                            int* __restrict__ extra)
{
  int e = blockIdx.x * 256 + threadIdx.x;
  if (e >= N_NODES*KK) return;
  if (flags[e]) return;
  int i = e / KK;
  int d = knn[e];
  int p = atomicAdd(&cursor[d], 1);
  extra[off[d] + p] = i;
}

// Y = X @ W (+ bias [*deg]) [+relu]; X:[n,128] W:[128,128] row-major.
template<int RELU, int DEG>
__global__ __launch_bounds__(256) void gemm128(const float* __restrict__ X,
    const float* __restrict__ W, const float* __restrict__ bias,
    const int* __restrict__ offs, float* __restrict__ Y)
{
  __shared__ float xs[64*129];
  __shared__ float ws[8*128];
  const int tid = threadIdx.x;
  const int r0  = blockIdx.x * 64;
  for (int li = tid; li < 64*128; li += 256) {
    int r = li >> 7, c = li & 127;
    xs[r*129 + c] = X[(size_t)(r0 + r)*128 + c];
  }
  const int tr = tid >> 4, tc = tid & 15;
  const int rr0 = tr*4, cc0 = tc*8;
  float acc[4][8];
#pragma unroll
  for (int a = 0; a < 4; a++)
#pragma unroll
    for (int c = 0; c < 8; c++) acc[a][c] = 0.f;

  for (int kb = 0; kb < 16; kb++) {
    __syncthreads();                   // xs ready (kb=0) / prev ws reads done
    for (int li = tid; li < 1024; li += 256) ws[li] = W[kb*1024 + li];
    __syncthreads();
#pragma unroll
    for (int k8 = 0; k8 < 8; k8++) {
      float xa[4];
#pragma unroll
      for (int rr = 0; rr < 4; rr++) xa[rr] = xs[(rr0+rr)*129 + kb*8 + k8];
      float4 wA = *(const float4*)&ws[k8*128 + cc0];
      float4 wB = *(const float4*)&ws[k8*128 + cc0 + 4];
      float wv[8] = {wA.x, wA.y, wA.z, wA.w, wB.x, wB.y, wB.z, wB.w};
#pragma unroll
      for (int rr = 0; rr < 4; rr++)
#pragma unroll
        for (int cc = 0; cc < 8; cc++) acc[rr][cc] += xa[rr] * wv[cc];
    }
  }
#pragma unroll
  for (int rr = 0; rr < 4; rr++) {
    int r = r0 + rr0 + rr;
    float dg = 1.f;
    if (DEG) dg = (float)(KK + offs[r+1] - offs[r]);
    float o[8];
#pragma unroll
    for (int cc = 0; cc < 8; cc++) {
      float vv = acc[rr][cc] + bias[cc0+cc] * dg;
      if (RELU) vv = fmaxf(vv, 0.f);
      o[cc] = vv;
    }
    *(float4*)&Y[(size_t)r*128 + cc0]     = make_float4(o[0], o[1], o[2], o[3]);
    *(float4*)&Y[(size_t)r*128 + cc0 + 4] = make_float4(o[4], o[5], o[6], o[7]);
  }
}

// agg[d] = sum over in-neighbors s of relu(H[s] + (pos[d]-pos[s]) @ Wr); one wave/node.
// XCD swizzle: graph g's blocks land on XCD pair {2g,2g+1} (blockIdx%8 -> XCD heuristic),
// so each graph's 4MB H slab stays in 2 local L2s. Bijection: d=(g,nb) covers all.
__global__ __launch_bounds__(256) void agg_kernel(const float* __restrict__ H,
    const float* __restrict__ pos, const int* __restrict__ knn,
    const int* __restrict__ off, const int* __restrict__ extra,
    const float* __restrict__ Wr, float* __restrict__ agg)
{
  const int lane = threadIdx.x & 63;
  const int dblk = blockIdx.x;
  const int g    = (dblk >> 1) & 3;
  const int nb   = ((dblk >> 3) << 1) | (dblk & 1);
  const int d    = g*NPER + nb*4 + (threadIdx.x >> 6);
  const int c0   = lane * 2;
  const float w0x = Wr[0*DH + c0], w0y = Wr[0*DH + c0 + 1];
  const float w1x = Wr[1*DH + c0], w1y = Wr[1*DH + c0 + 1];
  const float w2x = Wr[2*DH + c0], w2y = Wr[2*DH + c0 + 1];
  const float px = pos[d*3+0], py = pos[d*3+1], pz = pos[d*3+2];
  float a0 = 0.f, a1 = 0.f;
#pragma unroll 4
  for (int t = 0; t < KK; t++) {
    int s = knn[d*KK + t];
    float rx = px - pos[s*3+0];
    float ry = py - pos[s*3+1];
    float rz = pz - pos[s*3+2];
    float2 h = *(const float2*)&H[(size_t)s*DH + c0];
    float m0 = h.x + rx*w0x + ry*w1x + rz*w2x;
    float m1 = h.y + rx*w0y + ry*w1y + rz*w2y;
    a0 += fmaxf(m0, 0.f);
    a1 += fmaxf(m1, 0.f);
  }
  const int e0 = off[d], e1 = off[d+1];
  for (int t = e0; t < e1; t++) {
    int s = extra[t];
    float rx = px - pos[s*3+0];
    float ry = py - pos[s*3+1];
    float rz = pz - pos[s*3+2];
    float2 h = *(const float2*)&H[(size_t)s*DH + c0];
    float m0 = h.x + rx*w0x + ry*w1x + rz*w2x;
    float m1 = h.y + rx*w0y + ry*w1y + rz*w2y;
    a0 += fmaxf(m0, 0.f);
    a1 += fmaxf(m1, 0.f);
  }
  *(float2*)&agg[(size_t)d*DH + c0] = make_float2(a0, a1);
}

// logits = X @ Wf + bf; per-graph softmax over 8192 nodes.
__global__ __launch_bounds__(1024) void final_kernel(const float* __restrict__ X,
    const float* __restrict__ Wf, const float* __restrict__ bf, float* __restrict__ out)
{
  __shared__ float red[16];
  __shared__ float bcast;
  const int g = blockIdx.x, tid = threadIdx.x;
  const int lane = tid & 63, wid = tid >> 6;
  float lg[8];
#pragma unroll
  for (int k = 0; k < 8; k++) {
    int n = g*NPER + k*1024 + tid;
    const float4* xr = (const float4*)&X[(size_t)n*128];
    float acc = 0.f;
#pragma unroll 8
    for (int q = 0; q < 32; q++) {
      float4 xv = xr[q];
      float4 wv = *(const float4*)&Wf[q*4];
      acc += xv.x*wv.x + xv.y*wv.y + xv.z*wv.z + xv.w*wv.w;
    }
    lg[k] = acc + bf[0];
  }
  float m = lg[0];
#pragma unroll
  for (int k = 1; k < 8; k++) m = fmaxf(m, lg[k]);
  for (int o = 1; o < 64; o <<= 1) m = fmaxf(m, __shfl_xor(m, o, 64));
  if (lane == 0) red[wid] = m;
  __syncthreads();
  if (tid == 0) {
    float mm = red[0];
    for (int i = 1; i < 16; i++) mm = fmaxf(mm, red[i]);
    bcast = mm;
  }
  __syncthreads();
  const float M = bcast;
  float e[8];
  float s = 0.f;
#pragma unroll
  for (int k = 0; k < 8; k++) { e[k] = expf(lg[k] - M); s += e[k]; }
  for (int o = 1; o < 64; o <<= 1) s += __shfl_xor(s, o, 64);
  __syncthreads();
  if (lane == 0) red[wid] = s;
  __syncthreads();
  if (tid == 0) {
    float ss = 0.f;
    for (int i = 0; i < 16; i++) ss += red[i];
    bcast = ss;
  }
  __syncthreads();
  const float S = bcast;
#pragma unroll
  for (int k = 0; k < 8; k++) {
    int n = g*NPER + k*1024 + tid;
    out[n] = e[k] / S;
  }
}

extern "C" void kernel_launch(void* const* d_in, const int* in_sizes, int n_in,
                              void* d_out, int out_size, void* d_ws, size_t ws_size,
                              hipStream_t stream)
{
  const float* x   = (const float*)d_in[0];
  const float* pos = (const float*)d_in[1];
  // d_in[2] = batch (unused: sorted, equal-size graphs)
  const float* W1s = (const float*)d_in[3];
  const float* b1s = (const float*)d_in[4];
  const float* W2s = (const float*)d_in[5];
  const float* b2s = (const float*)d_in[6];
  const float* Wf  = (const float*)d_in[7];
  const float* bf  = (const float*)d_in[8];
  float* out = (float*)d_out;

  char* wsb = (char*)d_ws;
  size_t o = 0;
  auto alloc = [&](size_t bytes) { void* p = wsb + o; o += (bytes + 255) & ~255ull; return p; };
  int*   knn    = (int*)  alloc((size_t)N_NODES*KK*4);
  int*   flags  = (int*)  alloc((size_t)N_NODES*KK*4);
  int*   cnt    = (int*)  alloc((size_t)(N_NODES+1)*4);
  int*   off    = (int*)  alloc((size_t)(N_NODES+1)*4);
  int*   cursor = (int*)  alloc((size_t)N_NODES*4);
  int*   extra  = (int*)  alloc((size_t)N_NODES*KK*4);
  float* H      = (float*)alloc((size_t)N_NODES*DH*4);
  float* agg    = (float*)alloc((size_t)N_NODES*DH*4);
  float* xbuf   = (float*)alloc((size_t)N_NODES*DH*4);
  (void)ws_size; (void)in_sizes; (void)n_in; (void)out_size;

  hipMemsetAsync(cnt,    0, (size_t)(N_NODES+1)*4, stream);
  hipMemsetAsync(cursor, 0, (size_t)N_NODES*4,     stream);

  knn_kernel <<<N_NODES/8, 256, 0, stream>>>(pos, knn);
  count_kernel<<<(N_NODES*KK + 255)/256, 256, 0, stream>>>(knn, flags, cnt);
  scan_kernel<<<1, 1024, 0, stream>>>(cnt, off);
  fill_kernel<<<(N_NODES*KK + 255)/256, 256, 0, stream>>>(knn, flags, off, cursor, extra);

  const float* xin = x;
  for (int l = 0; l < 3; l++) {
    const float* W1 = W1s + (size_t)l*131*128;   // rows 0..127: x-part
    const float* Wr = W1 + 128*128;              // rows 128..130: rel-part
    const float* b1 = b1s + l*128;
    const float* W2 = W2s + (size_t)l*128*128;
    const float* b2 = b2s + l*128;
    gemm128<0,0><<<N_NODES/64, 256, 0, stream>>>(xin, W1, b1, nullptr, H);
    agg_kernel  <<<N_NODES/4,  256, 0, stream>>>(H, pos, knn, off, extra, Wr, agg);
    gemm128<1,1><<<N_NODES/64, 256, 0, stream>>>(agg, W2, b2, off, xbuf);
    xin = xbuf;
  }
  final_kernel<<<NB, 1024, 0, stream>>>(xbuf, Wf, bf, out);
}

// Round 13
// 584.223 us; speedup vs baseline: 2.5302x; 1.1609x over previous
//
#include <hip/hip_runtime.h>
#include <stdint.h>

#define N_NODES 32768
#define NPER    8192
#define NB      4
#define KK      20
#define DH      128

typedef unsigned long long u64;

__device__ __forceinline__ u64 shflx64(u64 x, int m) {
  unsigned lo = __shfl_xor((unsigned)(x & 0xffffffffu), m, 64);
  unsigned hi = __shfl_xor((unsigned)(x >> 32), m, 64);
  return (((u64)hi) << 32) | lo;
}
__device__ __forceinline__ u64 shfl64(u64 x, int src) {
  unsigned lo = __shfl((unsigned)(x & 0xffffffffu), src, 64);
  unsigned hi = __shfl((unsigned)(x >> 32), src, 64);
  return (((u64)hi) << 32) | lo;
}
__device__ __forceinline__ int mbcnt64(u64 mask) {
  return __builtin_amdgcn_mbcnt_hi((unsigned)(mask >> 32),
         __builtin_amdgcn_mbcnt_lo((unsigned)mask, 0u));
}
// 64-lane bitonic sort, ascending across lanes (u64 keys)
__device__ __forceinline__ u64 bsort64(u64 key, int lane) {
#pragma unroll
  for (int k = 2; k <= 64; k <<= 1) {
#pragma unroll
    for (int j = k >> 1; j >= 1; j >>= 1) {
      u64 other = shflx64(key, j);
      bool up = ((lane & k) == 0);
      bool keepmin = (((lane & j) == 0) == up);
      bool take = keepmin ? (other < key) : (other > key);
      key = take ? other : key;
    }
  }
  return key;
}
// 64-lane bitonic sort, ascending, u32 keys (half the shuffle cost)
__device__ __forceinline__ unsigned bsortu32(unsigned key, int lane) {
#pragma unroll
  for (int k = 2; k <= 64; k <<= 1) {
#pragma unroll
    for (int j = k >> 1; j >= 1; j >>= 1) {
      unsigned other = (unsigned)__shfl_xor((int)key, j, 64);
      bool up = ((lane & k) == 0);
      bool keepmin = (((lane & j) == 0) == up);
      bool take = keepmin ? (other < key) : (other > key);
      key = take ? other : key;
    }
  }
  return key;
}
// bitonic merge-clean (input bitonic, output ascending)
__device__ __forceinline__ u64 bclean64(u64 key, int lane) {
#pragma unroll
  for (int j = 32; j >= 1; j >>= 1) {
    u64 other = shflx64(key, j);
    bool keepmin = ((lane & j) == 0);
    bool take = keepmin ? (other < key) : (other > key);
    key = take ? other : key;
  }
  return key;
}

// Fold <=64 NEW buffered keys into register-kept sorted list lo (21 valid + pad):
// one bsort64 of the new keys, half-cleaner merge vs lo, bclean. Tighten thr.
__device__ __forceinline__ void compact64(u64* bufr, int& cnt, u64& lo,
                                          unsigned& thr, int lane) {
  asm volatile("s_waitcnt lgkmcnt(0)" ::: "memory");
  u64 k = (lane < cnt) ? bufr[lane] : ~0ull;
  k = bsort64(k, lane);                     // new keys ascending
  u64 kr = shfl64(k, 63 - lane);            // descending copy
  u64 m = (kr < lo) ? kr : lo;              // half-cleaner: 64 smallest of 128, bitonic
  lo = bclean64(m, lane);                   // sorted ascending
  thr = (unsigned)(shfl64(lo, KK) >> 32);   // d2-bits of 21st smallest (incl self)
  cnt = 0;
  asm volatile("s_waitcnt lgkmcnt(0)" ::: "memory");
}

// One wave per TWO consecutive rows; each lane handles FOUR consecutive candidates
// per iteration (48B contiguous = 3x float4, coalesced). Threshold PRIMED from
// iteration-0 lane-mins (21st smallest lane-min >= 21st smallest of 256 => valid
// superset bound). Sorted top-21 lives in registers (lo); LDS buffer holds only
// new appends (<=64); compact triggered BEFORE append when cnt+popc would overflow.
// Self (d2=0) flows through, stripped at output. Exact top-20 by (d2, idx).
__global__ __launch_bounds__(256) void knn_kernel(const float* __restrict__ pos,
                                                  int* __restrict__ knn)
{
  __shared__ u64 buf[8][64];

  const int lane = threadIdx.x & 63;
  const int w    = threadIdx.x >> 6;
  const int rowA = blockIdx.x * 8 + w * 2;
  const int rowB = rowA + 1;
  const int base = (rowA >> 13) << 13;   // graph start

  const float ax = pos[rowA*3+0], ay = pos[rowA*3+1], az = pos[rowA*3+2];
  const float bx = pos[rowB*3+0], by = pos[rowB*3+1], bz = pos[rowB*3+2];

  unsigned thra, thrb;
  int cnta = 0, cntb = 0;
  u64 loa = ~0ull, lob = ~0ull;
  u64* bufa = buf[w*2+0];
  u64* bufb = buf[w*2+1];

  const float4* __restrict__ p4 = (const float4*)(pos + (size_t)base*3);

  // ---- prime thresholds from iteration-0 candidates (lane-min upper bound) ----
  {
    float4 q0 = p4[lane*3+0];
    float4 q1 = p4[lane*3+1];
    float4 q2 = p4[lane*3+2];
    const float X[4] = {q0.x, q0.w, q1.z, q2.y};
    const float Y[4] = {q0.y, q1.x, q1.w, q2.z};
    const float Z[4] = {q0.z, q1.y, q2.x, q2.w};
    float mA = 3.4e38f, mB = 3.4e38f;
#pragma unroll
    for (int r = 0; r < 4; r++) {
      float dx = ax - X[r], dy = ay - Y[r], dz = az - Z[r];
      mA = fminf(mA, fmaf(dx, dx, fmaf(dy, dy, dz*dz)));
      float ex = bx - X[r], ey = by - Y[r], ez = bz - Z[r];
      mB = fminf(mB, fmaf(ex, ex, fmaf(ey, ey, ez*ez)));
    }
    unsigned sA = bsortu32(__float_as_uint(mA), lane);
    unsigned sB = bsortu32(__float_as_uint(mB), lane);
    thra = (unsigned)__shfl((int)sA, KK, 64);   // 21st smallest lane-min
    thrb = (unsigned)__shfl((int)sB, KK, 64);
  }

  for (int it = 0; it < 32; it++) {
    const int c0 = it*256 + lane*4;            // 4 consecutive candidates
    const int f4 = it*192 + lane*3;            // float4 index of candidate block
    float4 q0 = p4[f4+0];
    float4 q1 = p4[f4+1];
    float4 q2 = p4[f4+2];
    const float X[4] = {q0.x, q0.w, q1.z, q2.y};
    const float Y[4] = {q0.y, q1.x, q1.w, q2.z};
    const float Z[4] = {q0.z, q1.y, q2.x, q2.w};

    float dA[4], dB[4];
#pragma unroll
    for (int r = 0; r < 4; r++) {
      float dx = ax - X[r], dy = ay - Y[r], dz = az - Z[r];
      dA[r] = fmaf(dx, dx, fmaf(dy, dy, dz*dz));
      float ex = bx - X[r], ey = by - Y[r], ez = bz - Z[r];
      dB[r] = fmaf(ex, ex, fmaf(ey, ey, ez*ez));
    }
    float mnA = fminf(fminf(dA[0], dA[1]), fminf(dA[2], dA[3]));
    float mnB = fminf(fminf(dB[0], dB[1]), fminf(dB[2], dB[3]));

    if (__any(__float_as_uint(mnA) <= thra)) {
#pragma unroll
      for (int r = 0; r < 4; r++) {
        unsigned bits = __float_as_uint(dA[r]);
        bool pred = (bits <= thra);
        u64 mask = __ballot(pred);
        int pc = __popcll(mask);
        if (cnta + pc > 64) compact64(bufa, cnta, loa, thra, lane);
        if (pred) bufa[cnta + mbcnt64(mask)] =
            (((u64)bits) << 32) | (unsigned)(base + c0 + r);
        cnta = __builtin_amdgcn_readfirstlane(cnta + pc);
      }
    }
    if (__any(__float_as_uint(mnB) <= thrb)) {
#pragma unroll
      for (int r = 0; r < 4; r++) {
        unsigned bits = __float_as_uint(dB[r]);
        bool pred = (bits <= thrb);
        u64 mask = __ballot(pred);
        int pc = __popcll(mask);
        if (cntb + pc > 64) compact64(bufb, cntb, lob, thrb, lane);
        if (pred) bufb[cntb + mbcnt64(mask)] =
            (((u64)bits) << 32) | (unsigned)(base + c0 + r);
        cntb = __builtin_amdgcn_readfirstlane(cntb + pc);
      }
    }
  }
  compact64(bufa, cnta, loa, thra, lane);
  compact64(bufb, cntb, lob, thrb, lane);

  // strip self (d2=0 guarantees membership in the 21); output order irrelevant
  {
    u64 ball = __ballot(((int)(loa & 0xffffffffu) == rowA) && (lane <= KK));
    int p0 = __ffsll((long long)ball) - 1;
    if (p0 < 0) p0 = KK + 1;
    int src = lane + ((lane >= p0) ? 1 : 0);
    u64 outk = shfl64(loa, src);
    if (lane < KK) knn[rowA*KK + lane] = (int)(outk & 0xffffffffu);
  }
  {
    u64 ball = __ballot(((int)(lob & 0xffffffffu) == rowB) && (lane <= KK));
    int p0 = __ffsll((long long)ball) - 1;
    if (p0 < 0) p0 = KK + 1;
    int src = lane + ((lane >= p0) ? 1 : 0);
    u64 outk = shfl64(lob, src);
    if (lane < KK) knn[rowB*KK + lane] = (int)(outk & 0xffffffffu);
  }
}

// forward edge e=(i -> d=knn[i][j]); mutual iff i in knn(d). Non-mutual edges need a CSR slot.
__global__ void count_kernel(const int* __restrict__ knn, int* __restrict__ flags,
                             int* __restrict__ cnt)
{
  int e = blockIdx.x * 256 + threadIdx.x;
  if (e >= N_NODES*KK) return;
  int i = e / KK;
  int d = knn[e];
  int mut = 0;
#pragma unroll
  for (int t = 0; t < KK; t++) mut |= (knn[d*KK + t] == i);
  flags[e] = mut;
  if (!mut) atomicAdd(&cnt[d], 1);
}

__global__ __launch_bounds__(1024) void scan_kernel(const int* __restrict__ cnt,
                                                    int* __restrict__ off)
{
  __shared__ int ssum[1024];
  int tid = threadIdx.x;
  int i0 = tid * 32;
  int loc[32];
  int s = 0;
#pragma unroll
  for (int j = 0; j < 32; j++) { loc[j] = s; s += cnt[i0 + j]; }
  ssum[tid] = s;
  __syncthreads();
  for (int d = 1; d < 1024; d <<= 1) {
    int t = (tid >= d) ? ssum[tid - d] : 0;
    __syncthreads();
    ssum[tid] += t;
    __syncthreads();
  }
  int bse = ssum[tid] - s;             // exclusive base
#pragma unroll
  for (int j = 0; j < 32; j++) off[i0 + j] = bse + loc[j];
  if (tid == 1023) off[N_NODES] = bse + s;
}

__global__ void fill_kernel(const int* __restrict__ knn, const int* __restrict__ flags,
                            const int* __restrict__ off, int* __restrict__ cursor,
                            int* __restrict__ extra)
{
  int e = blockIdx.x * 256 + threadIdx.x;
  if (e >= N_NODES*KK) return;
  if (flags[e]) return;
  int i = e / KK;
  int d = knn[e];
  int p = atomicAdd(&cursor[d], 1);
  extra[off[d] + p] = i;
}

// Y = X @ W (+ bias [*deg]) [+relu]; X:[n,128] W:[128,128] row-major.
// Full W staged in LDS (64 KB, 2 blocks/CU); X streamed via float4 (16 same-addr
// lanes merge); ONE barrier total; inner chunk = 4 global float4 + 8 LDS b128
// (bank-conflict-free) per 128 FMA.
template<int RELU, int DEG>
__global__ __launch_bounds__(256) void gemm128(const float* __restrict__ X,
    const float* __restrict__ W, const float* __restrict__ bias,
    const int* __restrict__ offs, float* __restrict__ Y)
{
  __shared__ float ws[128*128];
  const int tid = threadIdx.x;
  const int r0  = blockIdx.x * 64;

  {
    const float4* W4 = (const float4*)W;
    float4* ws4 = (float4*)ws;
#pragma unroll
    for (int li = 0; li < 16; li++) ws4[tid + li*256] = W4[tid + li*256];
  }
  __syncthreads();

  const int tr = tid >> 4, tc = tid & 15;
  const int rr0 = tr*4, cc0 = tc*8;
  float acc[4][8];
#pragma unroll
  for (int a = 0; a < 4; a++)
#pragma unroll
    for (int c = 0; c < 8; c++) acc[a][c] = 0.f;

  for (int kc = 0; kc < 32; kc++) {
    float4 xr[4];
#pragma unroll
    for (int rr = 0; rr < 4; rr++)
      xr[rr] = *(const float4*)&X[(size_t)(r0 + rr0 + rr)*128 + kc*4];
#pragma unroll
    for (int kk = 0; kk < 4; kk++) {
      float4 wA = *(const float4*)&ws[(kc*4 + kk)*128 + cc0];
      float4 wB = *(const float4*)&ws[(kc*4 + kk)*128 + cc0 + 4];
      float wv[8] = {wA.x, wA.y, wA.z, wA.w, wB.x, wB.y, wB.z, wB.w};
      float xa[4] = {kk==0?xr[0].x:kk==1?xr[0].y:kk==2?xr[0].z:xr[0].w,
                     kk==0?xr[1].x:kk==1?xr[1].y:kk==2?xr[1].z:xr[1].w,
                     kk==0?xr[2].x:kk==1?xr[2].y:kk==2?xr[2].z:xr[2].w,
                     kk==0?xr[3].x:kk==1?xr[3].y:kk==2?xr[3].z:xr[3].w};
#pragma unroll
      for (int rr = 0; rr < 4; rr++)
#pragma unroll
        for (int cc = 0; cc < 8; cc++) acc[rr][cc] += xa[rr] * wv[cc];
    }
  }
#pragma unroll
  for (int rr = 0; rr < 4; rr++) {
    int r = r0 + rr0 + rr;
    float dg = 1.f;
    if (DEG) dg = (float)(KK + offs[r+1] - offs[r]);
    float o[8];
#pragma unroll
    for (int cc = 0; cc < 8; cc++) {
      float vv = acc[rr][cc] + bias[cc0+cc] * dg;
      if (RELU) vv = fmaxf(vv, 0.f);
      o[cc] = vv;
    }
    *(float4*)&Y[(size_t)r*128 + cc0]     = make_float4(o[0], o[1], o[2], o[3]);
    *(float4*)&Y[(size_t)r*128 + cc0 + 4] = make_float4(o[4], o[5], o[6], o[7]);
  }
}

// agg[d] = sum over in-neighbors s of relu(H[s] + (pos[d]-pos[s]) @ Wr); one wave/node.
// XCD swizzle: graph g's blocks land on XCD pair {2g,2g+1} (blockIdx%8 -> XCD heuristic),
// so each graph's 4MB H slab stays in 2 local L2s. Bijection: d=(g,nb) covers all.
__global__ __launch_bounds__(256) void agg_kernel(const float* __restrict__ H,
    const float* __restrict__ pos, const int* __restrict__ knn,
    const int* __restrict__ off, const int* __restrict__ extra,
    const float* __restrict__ Wr, float* __restrict__ agg)
{
  const int lane = threadIdx.x & 63;
  const int dblk = blockIdx.x;
  const int g    = (dblk >> 1) & 3;
  const int nb   = ((dblk >> 3) << 1) | (dblk & 1);
  const int d    = g*NPER + nb*4 + (threadIdx.x >> 6);
  const int c0   = lane * 2;
  const float w0x = Wr[0*DH + c0], w0y = Wr[0*DH + c0 + 1];
  const float w1x = Wr[1*DH + c0], w1y = Wr[1*DH + c0 + 1];
  const float w2x = Wr[2*DH + c0], w2y = Wr[2*DH + c0 + 1];
  const float px = pos[d*3+0], py = pos[d*3+1], pz = pos[d*3+2];
  float a0 = 0.f, a1 = 0.f;
#pragma unroll 4
  for (int t = 0; t < KK; t++) {
    int s = knn[d*KK + t];
    float rx = px - pos[s*3+0];
    float ry = py - pos[s*3+1];
    float rz = pz - pos[s*3+2];
    float2 h = *(const float2*)&H[(size_t)s*DH + c0];
    float m0 = h.x + rx*w0x + ry*w1x + rz*w2x;
    float m1 = h.y + rx*w0y + ry*w1y + rz*w2y;
    a0 += fmaxf(m0, 0.f);
    a1 += fmaxf(m1, 0.f);
  }
  const int e0 = off[d], e1 = off[d+1];
  for (int t = e0; t < e1; t++) {
    int s = extra[t];
    float rx = px - pos[s*3+0];
    float ry = py - pos[s*3+1];
    float rz = pz - pos[s*3+2];
    float2 h = *(const float2*)&H[(size_t)s*DH + c0];
    float m0 = h.x + rx*w0x + ry*w1x + rz*w2x;
    float m1 = h.y + rx*w0y + ry*w1y + rz*w2y;
    a0 += fmaxf(m0, 0.f);
    a1 += fmaxf(m1, 0.f);
  }
  *(float2*)&agg[(size_t)d*DH + c0] = make_float2(a0, a1);
}

// logits = X @ Wf + bf; per-graph softmax over 8192 nodes.
__global__ __launch_bounds__(1024) void final_kernel(const float* __restrict__ X,
    const float* __restrict__ Wf, const float* __restrict__ bf, float* __restrict__ out)
{
  __shared__ float red[16];
  __shared__ float bcast;
  const int g = blockIdx.x, tid = threadIdx.x;
  const int lane = tid & 63, wid = tid >> 6;
  float lg[8];
#pragma unroll
  for (int k = 0; k < 8; k++) {
    int n = g*NPER + k*1024 + tid;
    const float4* xr = (const float4*)&X[(size_t)n*128];
    float acc = 0.f;
#pragma unroll 8
    for (int q = 0; q < 32; q++) {
      float4 xv = xr[q];
      float4 wv = *(const float4*)&Wf[q*4];
      acc += xv.x*wv.x + xv.y*wv.y + xv.z*wv.z + xv.w*wv.w;
    }
    lg[k] = acc + bf[0];
  }
  float m = lg[0];
#pragma unroll
  for (int k = 1; k < 8; k++) m = fmaxf(m, lg[k]);
  for (int o = 1; o < 64; o <<= 1) m = fmaxf(m, __shfl_xor(m, o, 64));
  if (lane == 0) red[wid] = m;
  __syncthreads();
  if (tid == 0) {
    float mm = red[0];
    for (int i = 1; i < 16; i++) mm = fmaxf(mm, red[i]);
    bcast = mm;
  }
  __syncthreads();
  const float M = bcast;
  float e[8];
  float s = 0.f;
#pragma unroll
  for (int k = 0; k < 8; k++) { e[k] = expf(lg[k] - M); s += e[k]; }
  for (int o = 1; o < 64; o <<= 1) s += __shfl_xor(s, o, 64);
  __syncthreads();
  if (lane == 0) red[wid] = s;
  __syncthreads();
  if (tid == 0) {
    float ss = 0.f;
    for (int i = 0; i < 16; i++) ss += red[i];
    bcast = ss;
  }
  __syncthreads();
  const float S = bcast;
#pragma unroll
  for (int k = 0; k < 8; k++) {
    int n = g*NPER + k*1024 + tid;
    out[n] = e[k] / S;
  }
}

extern "C" void kernel_launch(void* const* d_in, const int* in_sizes, int n_in,
                              void* d_out, int out_size, void* d_ws, size_t ws_size,
                              hipStream_t stream)
{
  const float* x   = (const float*)d_in[0];
  const float* pos = (const float*)d_in[1];
  // d_in[2] = batch (unused: sorted, equal-size graphs)
  const float* W1s = (const float*)d_in[3];
  const float* b1s = (const float*)d_in[4];
  const float* W2s = (const float*)d_in[5];
  const float* b2s = (const float*)d_in[6];
  const float* Wf  = (const float*)d_in[7];
  const float* bf  = (const float*)d_in[8];
  float* out = (float*)d_out;

  char* wsb = (char*)d_ws;
  size_t o = 0;
  auto alloc = [&](size_t bytes) { void* p = wsb + o; o += (bytes + 255) & ~255ull; return p; };
  int*   knn    = (int*)  alloc((size_t)N_NODES*KK*4);
  int*   flags  = (int*)  alloc((size_t)N_NODES*KK*4);
  int*   cnt    = (int*)  alloc((size_t)(N_NODES+1)*4);
  int*   off    = (int*)  alloc((size_t)(N_NODES+1)*4);
  int*   cursor = (int*)  alloc((size_t)N_NODES*4);
  int*   extra  = (int*)  alloc((size_t)N_NODES*KK*4);
  float* H      = (float*)alloc((size_t)N_NODES*DH*4);
  float* agg    = (float*)alloc((size_t)N_NODES*DH*4);
  float* xbuf   = (float*)alloc((size_t)N_NODES*DH*4);
  (void)ws_size; (void)in_sizes; (void)n_in; (void)out_size;

  hipMemsetAsync(cnt,    0, (size_t)(N_NODES+1)*4, stream);
  hipMemsetAsync(cursor, 0, (size_t)N_NODES*4,     stream);

  knn_kernel <<<N_NODES/8, 256, 0, stream>>>(pos, knn);
  count_kernel<<<(N_NODES*KK + 255)/256, 256, 0, stream>>>(knn, flags, cnt);
  scan_kernel<<<1, 1024, 0, stream>>>(cnt, off);
  fill_kernel<<<(N_NODES*KK + 255)/256, 256, 0, stream>>>(knn, flags, off, cursor, extra);

  const float* xin = x;
  for (int l = 0; l < 3; l++) {
    const float* W1 = W1s + (size_t)l*131*128;   // rows 0..127: x-part
    const float* Wr = W1 + 128*128;              // rows 128..130: rel-part
    const float* b1 = b1s + l*128;
    const float* W2 = W2s + (size_t)l*128*128;
    const float* b2 = b2s + l*128;
    gemm128<0,0><<<N_NODES/64, 256, 0, stream>>>(xin, W1, b1, nullptr, H);
    agg_kernel  <<<N_NODES/4,  256, 0, stream>>>(H, pos, knn, off, extra, Wr, agg);
    gemm128<1,1><<<N_NODES/64, 256, 0, stream>>>(agg, W2, b2, off, xbuf);
    xin = xbuf;
  }
  final_kernel<<<NB, 1024, 0, stream>>>(xbuf, Wf, bf, out);
}

// Round 14
// 520.109 us; speedup vs baseline: 2.8421x; 1.1233x over previous
//
#include <hip/hip_runtime.h>
#include <stdint.h>

#define N_NODES 32768
#define NPER    8192
#define NB      4
#define KK      20
#define DH      128

typedef unsigned long long u64;

__device__ __forceinline__ u64 shflx64(u64 x, int m) {
  unsigned lo = __shfl_xor((unsigned)(x & 0xffffffffu), m, 64);
  unsigned hi = __shfl_xor((unsigned)(x >> 32), m, 64);
  return (((u64)hi) << 32) | lo;
}
__device__ __forceinline__ u64 shfl64(u64 x, int src) {
  unsigned lo = __shfl((unsigned)(x & 0xffffffffu), src, 64);
  unsigned hi = __shfl((unsigned)(x >> 32), src, 64);
  return (((u64)hi) << 32) | lo;
}
__device__ __forceinline__ int mbcnt64(u64 mask) {
  return __builtin_amdgcn_mbcnt_hi((unsigned)(mask >> 32),
         __builtin_amdgcn_mbcnt_lo((unsigned)mask, 0u));
}
// 64-lane bitonic sort, ascending across lanes (u64 keys)
__device__ __forceinline__ u64 bsort64(u64 key, int lane) {
#pragma unroll
  for (int k = 2; k <= 64; k <<= 1) {
#pragma unroll
    for (int j = k >> 1; j >= 1; j >>= 1) {
      u64 other = shflx64(key, j);
      bool up = ((lane & k) == 0);
      bool keepmin = (((lane & j) == 0) == up);
      bool take = keepmin ? (other < key) : (other > key);
      key = take ? other : key;
    }
  }
  return key;
}
// 64-lane bitonic sort, ascending, u32 keys (half the shuffle cost)
__device__ __forceinline__ unsigned bsortu32(unsigned key, int lane) {
#pragma unroll
  for (int k = 2; k <= 64; k <<= 1) {
#pragma unroll
    for (int j = k >> 1; j >= 1; j >>= 1) {
      unsigned other = (unsigned)__shfl_xor((int)key, j, 64);
      bool up = ((lane & k) == 0);
      bool keepmin = (((lane & j) == 0) == up);
      bool take = keepmin ? (other < key) : (other > key);
      key = take ? other : key;
    }
  }
  return key;
}
// bitonic merge-clean (input bitonic, output ascending)
__device__ __forceinline__ u64 bclean64(u64 key, int lane) {
#pragma unroll
  for (int j = 32; j >= 1; j >>= 1) {
    u64 other = shflx64(key, j);
    bool keepmin = ((lane & j) == 0);
    bool take = keepmin ? (other < key) : (other > key);
    key = take ? other : key;
  }
  return key;
}

// Fold <=64 NEW buffered keys into register-kept sorted list lo (21 valid + pad):
// one bsort64 of the new keys, half-cleaner merge vs lo, bclean. Tighten thr.
__device__ __forceinline__ void compact64(u64* bufr, int& cnt, u64& lo,
                                          unsigned& thr, int lane) {
  asm volatile("s_waitcnt lgkmcnt(0)" ::: "memory");
  u64 k = (lane < cnt) ? bufr[lane] : ~0ull;
  k = bsort64(k, lane);                     // new keys ascending
  u64 kr = shfl64(k, 63 - lane);            // descending copy
  u64 m = (kr < lo) ? kr : lo;              // half-cleaner: 64 smallest of 128, bitonic
  lo = bclean64(m, lane);                   // sorted ascending
  thr = (unsigned)(shfl64(lo, KK) >> 32);   // d2-bits of 21st smallest (incl self)
  cnt = 0;
  asm volatile("s_waitcnt lgkmcnt(0)" ::: "memory");
}

// One wave per TWO consecutive rows; each lane handles FOUR consecutive candidates
// per iteration (48B contiguous = 3x float4, coalesced). Threshold PRIMED from
// iteration-0 lane-mins (21st smallest lane-min >= 21st smallest of 256 => valid
// superset bound). Sorted top-21 lives in registers (lo); LDS buffer holds only
// new appends (<=64); compact triggered BEFORE append when cnt+popc would overflow.
// Self (d2=0) flows through, stripped at output. Exact top-20 by (d2, idx).
__global__ __launch_bounds__(256) void knn_kernel(const float* __restrict__ pos,
                                                  int* __restrict__ knn)
{
  __shared__ u64 buf[8][64];

  const int lane = threadIdx.x & 63;
  const int w    = threadIdx.x >> 6;
  const int rowA = blockIdx.x * 8 + w * 2;
  const int rowB = rowA + 1;
  const int base = (rowA >> 13) << 13;   // graph start

  const float ax = pos[rowA*3+0], ay = pos[rowA*3+1], az = pos[rowA*3+2];
  const float bx = pos[rowB*3+0], by = pos[rowB*3+1], bz = pos[rowB*3+2];

  unsigned thra, thrb;
  int cnta = 0, cntb = 0;
  u64 loa = ~0ull, lob = ~0ull;
  u64* bufa = buf[w*2+0];
  u64* bufb = buf[w*2+1];

  const float4* __restrict__ p4 = (const float4*)(pos + (size_t)base*3);

  // ---- prime thresholds from iteration-0 candidates (lane-min upper bound) ----
  {
    float4 q0 = p4[lane*3+0];
    float4 q1 = p4[lane*3+1];
    float4 q2 = p4[lane*3+2];
    const float X[4] = {q0.x, q0.w, q1.z, q2.y};
    const float Y[4] = {q0.y, q1.x, q1.w, q2.z};
    const float Z[4] = {q0.z, q1.y, q2.x, q2.w};
    float mA = 3.4e38f, mB = 3.4e38f;
#pragma unroll
    for (int r = 0; r < 4; r++) {
      float dx = ax - X[r], dy = ay - Y[r], dz = az - Z[r];
      mA = fminf(mA, fmaf(dx, dx, fmaf(dy, dy, dz*dz)));
      float ex = bx - X[r], ey = by - Y[r], ez = bz - Z[r];
      mB = fminf(mB, fmaf(ex, ex, fmaf(ey, ey, ez*ez)));
    }
    unsigned sA = bsortu32(__float_as_uint(mA), lane);
    unsigned sB = bsortu32(__float_as_uint(mB), lane);
    thra = (unsigned)__shfl((int)sA, KK, 64);   // 21st smallest lane-min
    thrb = (unsigned)__shfl((int)sB, KK, 64);
  }

  for (int it = 0; it < 32; it++) {
    const int c0 = it*256 + lane*4;            // 4 consecutive candidates
    const int f4 = it*192 + lane*3;            // float4 index of candidate block
    float4 q0 = p4[f4+0];
    float4 q1 = p4[f4+1];
    float4 q2 = p4[f4+2];
    const float X[4] = {q0.x, q0.w, q1.z, q2.y};
    const float Y[4] = {q0.y, q1.x, q1.w, q2.z};
    const float Z[4] = {q0.z, q1.y, q2.x, q2.w};

    float dA[4], dB[4];
#pragma unroll
    for (int r = 0; r < 4; r++) {
      float dx = ax - X[r], dy = ay - Y[r], dz = az - Z[r];
      dA[r] = fmaf(dx, dx, fmaf(dy, dy, dz*dz));
      float ex = bx - X[r], ey = by - Y[r], ez = bz - Z[r];
      dB[r] = fmaf(ex, ex, fmaf(ey, ey, ez*ez));
    }
    float mnA = fminf(fminf(dA[0], dA[1]), fminf(dA[2], dA[3]));
    float mnB = fminf(fminf(dB[0], dB[1]), fminf(dB[2], dB[3]));

    if (__any(__float_as_uint(mnA) <= thra)) {
#pragma unroll
      for (int r = 0; r < 4; r++) {
        unsigned bits = __float_as_uint(dA[r]);
        bool pred = (bits <= thra);
        u64 mask = __ballot(pred);
        int pc = __popcll(mask);
        if (cnta + pc > 64) compact64(bufa, cnta, loa, thra, lane);
        if (pred) bufa[cnta + mbcnt64(mask)] =
            (((u64)bits) << 32) | (unsigned)(base + c0 + r);
        cnta = __builtin_amdgcn_readfirstlane(cnta + pc);
      }
    }
    if (__any(__float_as_uint(mnB) <= thrb)) {
#pragma unroll
      for (int r = 0; r < 4; r++) {
        unsigned bits = __float_as_uint(dB[r]);
        bool pred = (bits <= thrb);
        u64 mask = __ballot(pred);
        int pc = __popcll(mask);
        if (cntb + pc > 64) compact64(bufb, cntb, lob, thrb, lane);
        if (pred) bufb[cntb + mbcnt64(mask)] =
            (((u64)bits) << 32) | (unsigned)(base + c0 + r);
        cntb = __builtin_amdgcn_readfirstlane(cntb + pc);
      }
    }
  }
  compact64(bufa, cnta, loa, thra, lane);
  compact64(bufb, cntb, lob, thrb, lane);

  // strip self (d2=0 guarantees membership in the 21); output order irrelevant
  {
    u64 ball = __ballot(((int)(loa & 0xffffffffu) == rowA) && (lane <= KK));
    int p0 = __ffsll((long long)ball) - 1;
    if (p0 < 0) p0 = KK + 1;
    int src = lane + ((lane >= p0) ? 1 : 0);
    u64 outk = shfl64(loa, src);
    if (lane < KK) knn[rowA*KK + lane] = (int)(outk & 0xffffffffu);
  }
  {
    u64 ball = __ballot(((int)(lob & 0xffffffffu) == rowB) && (lane <= KK));
    int p0 = __ffsll((long long)ball) - 1;
    if (p0 < 0) p0 = KK + 1;
    int src = lane + ((lane >= p0) ? 1 : 0);
    u64 outk = shfl64(lob, src);
    if (lane < KK) knn[rowB*KK + lane] = (int)(outk & 0xffffffffu);
  }
}

// forward edge e=(i -> d=knn[i][j]); mutual iff i in knn(d). Non-mutual edges need a CSR slot.
__global__ void count_kernel(const int* __restrict__ knn, int* __restrict__ flags,
                             int* __restrict__ cnt)
{
  int e = blockIdx.x * 256 + threadIdx.x;
  if (e >= N_NODES*KK) return;
  int i = e / KK;
  int d = knn[e];
  int mut = 0;
#pragma unroll
  for (int t = 0; t < KK; t++) mut |= (knn[d*KK + t] == i);
  flags[e] = mut;
  if (!mut) atomicAdd(&cnt[d], 1);
}

__global__ __launch_bounds__(1024) void scan_kernel(const int* __restrict__ cnt,
                                                    int* __restrict__ off)
{
  __shared__ int ssum[1024];
  int tid = threadIdx.x;
  int i0 = tid * 32;
  int loc[32];
  int s = 0;
#pragma unroll
  for (int j = 0; j < 32; j++) { loc[j] = s; s += cnt[i0 + j]; }
  ssum[tid] = s;
  __syncthreads();
  for (int d = 1; d < 1024; d <<= 1) {
    int t = (tid >= d) ? ssum[tid - d] : 0;
    __syncthreads();
    ssum[tid] += t;
    __syncthreads();
  }
  int bse = ssum[tid] - s;             // exclusive base
#pragma unroll
  for (int j = 0; j < 32; j++) off[i0 + j] = bse + loc[j];
  if (tid == 1023) off[N_NODES] = bse + s;
}

__global__ void fill_kernel(const int* __restrict__ knn, const int* __restrict__ flags,
                            const int* __restrict__ off, int* __restrict__ cursor,
                            int* __restrict__ extra)
{
  int e = blockIdx.x * 256 + threadIdx.x;
  if (e >= N_NODES*KK) return;
  if (flags[e]) return;
  int i = e / KK;
  int d = knn[e];
  int p = atomicAdd(&cursor[d], 1);
  extra[off[d] + p] = i;
}

// Y = X @ W (+ bias [*deg]) [+relu]; X:[n,128] W:[128,128] row-major.
// Full W staged in LDS (64 KB, 2 blocks/CU); X streamed via float4 (16 same-addr
// lanes merge); ONE barrier total; inner chunk = 4 global float4 + 8 LDS b128
// (bank-conflict-free) per 128 FMA.
template<int RELU, int DEG>
__global__ __launch_bounds__(256) void gemm128(const float* __restrict__ X,
    const float* __restrict__ W, const float* __restrict__ bias,
    const int* __restrict__ offs, float* __restrict__ Y)
{
  __shared__ float ws[128*128];
  const int tid = threadIdx.x;
  const int r0  = blockIdx.x * 64;

  {
    const float4* W4 = (const float4*)W;
    float4* ws4 = (float4*)ws;
#pragma unroll
    for (int li = 0; li < 16; li++) ws4[tid + li*256] = W4[tid + li*256];
  }
  __syncthreads();

  const int tr = tid >> 4, tc = tid & 15;
  const int rr0 = tr*4, cc0 = tc*8;
  float acc[4][8];
#pragma unroll
  for (int a = 0; a < 4; a++)
#pragma unroll
    for (int c = 0; c < 8; c++) acc[a][c] = 0.f;

  for (int kc = 0; kc < 32; kc++) {
    float4 xr[4];
#pragma unroll
    for (int rr = 0; rr < 4; rr++)
      xr[rr] = *(const float4*)&X[(size_t)(r0 + rr0 + rr)*128 + kc*4];
#pragma unroll
    for (int kk = 0; kk < 4; kk++) {
      float4 wA = *(const float4*)&ws[(kc*4 + kk)*128 + cc0];
      float4 wB = *(const float4*)&ws[(kc*4 + kk)*128 + cc0 + 4];
      float wv[8] = {wA.x, wA.y, wA.z, wA.w, wB.x, wB.y, wB.z, wB.w};
      float xa[4] = {kk==0?xr[0].x:kk==1?xr[0].y:kk==2?xr[0].z:xr[0].w,
                     kk==0?xr[1].x:kk==1?xr[1].y:kk==2?xr[1].z:xr[1].w,
                     kk==0?xr[2].x:kk==1?xr[2].y:kk==2?xr[2].z:xr[2].w,
                     kk==0?xr[3].x:kk==1?xr[3].y:kk==2?xr[3].z:xr[3].w};
#pragma unroll
      for (int rr = 0; rr < 4; rr++)
#pragma unroll
        for (int cc = 0; cc < 8; cc++) acc[rr][cc] += xa[rr] * wv[cc];
    }
  }
#pragma unroll
  for (int rr = 0; rr < 4; rr++) {
    int r = r0 + rr0 + rr;
    float dg = 1.f;
    if (DEG) dg = (float)(KK + offs[r+1] - offs[r]);
    float o[8];
#pragma unroll
    for (int cc = 0; cc < 8; cc++) {
      float vv = acc[rr][cc] + bias[cc0+cc] * dg;
      if (RELU) vv = fmaxf(vv, 0.f);
      o[cc] = vv;
    }
    *(float4*)&Y[(size_t)r*128 + cc0]     = make_float4(o[0], o[1], o[2], o[3]);
    *(float4*)&Y[(size_t)r*128 + cc0 + 4] = make_float4(o[4], o[5], o[6], o[7]);
  }
}

// agg[d] = sum over in-neighbors s of relu(H[s] + (pos[d]-pos[s]) @ Wr).
// TWO nodes per wave: lanes 0-31 own node A, lanes 32-63 node B; each lane holds
// 4 columns (float4). One dwordx4 instr fetches TWO 512B H rows (1KB/instr);
// per-node loop bookkeeping halves vs one-node-per-wave float2 version.
// XCD swizzle: graph g -> XCD pair {2g,2g+1}; bijection (g,nb) <-> dblk bits.
__global__ __launch_bounds__(256) void agg_kernel(const float* __restrict__ H,
    const float* __restrict__ pos, const int* __restrict__ knn,
    const int* __restrict__ off, const int* __restrict__ extra,
    const float* __restrict__ Wr, float* __restrict__ agg)
{
  const int lane = threadIdx.x & 63;
  const int w    = threadIdx.x >> 6;
  const int half = lane >> 5;
  const int hl   = lane & 31;
  const int dblk = blockIdx.x;            // 4096 blocks
  const int g    = (dblk >> 1) & 3;
  const int nb   = ((dblk >> 3) << 1) | (dblk & 1);   // 0..1023
  const int d    = g*NPER + nb*8 + w*2 + half;
  const int c0   = hl * 4;

  const float4 w0 = *(const float4*)&Wr[0*DH + c0];
  const float4 w1 = *(const float4*)&Wr[1*DH + c0];
  const float4 w2 = *(const float4*)&Wr[2*DH + c0];
  const float px = pos[d*3+0], py = pos[d*3+1], pz = pos[d*3+2];

  float a0 = 0.f, a1 = 0.f, a2 = 0.f, a3 = 0.f;
#pragma unroll 4
  for (int t = 0; t < KK; t++) {
    int s = knn[d*KK + t];
    float rx = px - pos[s*3+0];
    float ry = py - pos[s*3+1];
    float rz = pz - pos[s*3+2];
    float4 h = *(const float4*)&H[(size_t)s*DH + c0];
    a0 += fmaxf(h.x + rx*w0.x + ry*w1.x + rz*w2.x, 0.f);
    a1 += fmaxf(h.y + rx*w0.y + ry*w1.y + rz*w2.y, 0.f);
    a2 += fmaxf(h.z + rx*w0.z + ry*w1.z + rz*w2.z, 0.f);
    a3 += fmaxf(h.w + rx*w0.w + ry*w1.w + rz*w2.w, 0.f);
  }
  const int e0 = off[d], e1 = off[d+1];
  for (int t = e0; t < e1; t++) {
    int s = extra[t];
    float rx = px - pos[s*3+0];
    float ry = py - pos[s*3+1];
    float rz = pz - pos[s*3+2];
    float4 h = *(const float4*)&H[(size_t)s*DH + c0];
    a0 += fmaxf(h.x + rx*w0.x + ry*w1.x + rz*w2.x, 0.f);
    a1 += fmaxf(h.y + rx*w0.y + ry*w1.y + rz*w2.y, 0.f);
    a2 += fmaxf(h.z + rx*w0.z + ry*w1.z + rz*w2.z, 0.f);
    a3 += fmaxf(h.w + rx*w0.w + ry*w1.w + rz*w2.w, 0.f);
  }
  *(float4*)&agg[(size_t)d*DH + c0] = make_float4(a0, a1, a2, a3);
}

// logits = X @ Wf + bf; per-graph softmax over 8192 nodes.
__global__ __launch_bounds__(1024) void final_kernel(const float* __restrict__ X,
    const float* __restrict__ Wf, const float* __restrict__ bf, float* __restrict__ out)
{
  __shared__ float red[16];
  __shared__ float bcast;
  const int g = blockIdx.x, tid = threadIdx.x;
  const int lane = tid & 63, wid = tid >> 6;
  float lg[8];
#pragma unroll
  for (int k = 0; k < 8; k++) {
    int n = g*NPER + k*1024 + tid;
    const float4* xr = (const float4*)&X[(size_t)n*128];
    float acc = 0.f;
#pragma unroll 8
    for (int q = 0; q < 32; q++) {
      float4 xv = xr[q];
      float4 wv = *(const float4*)&Wf[q*4];
      acc += xv.x*wv.x + xv.y*wv.y + xv.z*wv.z + xv.w*wv.w;
    }
    lg[k] = acc + bf[0];
  }
  float m = lg[0];
#pragma unroll
  for (int k = 1; k < 8; k++) m = fmaxf(m, lg[k]);
  for (int o = 1; o < 64; o <<= 1) m = fmaxf(m, __shfl_xor(m, o, 64));
  if (lane == 0) red[wid] = m;
  __syncthreads();
  if (tid == 0) {
    float mm = red[0];
    for (int i = 1; i < 16; i++) mm = fmaxf(mm, red[i]);
    bcast = mm;
  }
  __syncthreads();
  const float M = bcast;
  float e[8];
  float s = 0.f;
#pragma unroll
  for (int k = 0; k < 8; k++) { e[k] = expf(lg[k] - M); s += e[k]; }
  for (int o = 1; o < 64; o <<= 1) s += __shfl_xor(s, o, 64);
  __syncthreads();
  if (lane == 0) red[wid] = s;
  __syncthreads();
  if (tid == 0) {
    float ss = 0.f;
    for (int i = 0; i < 16; i++) ss += red[i];
    bcast = ss;
  }
  __syncthreads();
  const float S = bcast;
#pragma unroll
  for (int k = 0; k < 8; k++) {
    int n = g*NPER + k*1024 + tid;
    out[n] = e[k] / S;
  }
}

extern "C" void kernel_launch(void* const* d_in, const int* in_sizes, int n_in,
                              void* d_out, int out_size, void* d_ws, size_t ws_size,
                              hipStream_t stream)
{
  const float* x   = (const float*)d_in[0];
  const float* pos = (const float*)d_in[1];
  // d_in[2] = batch (unused: sorted, equal-size graphs)
  const float* W1s = (const float*)d_in[3];
  const float* b1s = (const float*)d_in[4];
  const float* W2s = (const float*)d_in[5];
  const float* b2s = (const float*)d_in[6];
  const float* Wf  = (const float*)d_in[7];
  const float* bf  = (const float*)d_in[8];
  float* out = (float*)d_out;

  char* wsb = (char*)d_ws;
  size_t o = 0;
  auto alloc = [&](size_t bytes) { void* p = wsb + o; o += (bytes + 255) & ~255ull; return p; };
  int*   knn    = (int*)  alloc((size_t)N_NODES*KK*4);
  int*   flags  = (int*)  alloc((size_t)N_NODES*KK*4);
  int*   cnt    = (int*)  alloc((size_t)(N_NODES+1)*4);
  int*   off    = (int*)  alloc((size_t)(N_NODES+1)*4);
  int*   cursor = (int*)  alloc((size_t)N_NODES*4);
  int*   extra  = (int*)  alloc((size_t)N_NODES*KK*4);
  float* H      = (float*)alloc((size_t)N_NODES*DH*4);
  float* agg    = (float*)alloc((size_t)N_NODES*DH*4);
  float* xbuf   = (float*)alloc((size_t)N_NODES*DH*4);
  (void)ws_size; (void)in_sizes; (void)n_in; (void)out_size;

  hipMemsetAsync(cnt,    0, (size_t)(N_NODES+1)*4, stream);
  hipMemsetAsync(cursor, 0, (size_t)N_NODES*4,     stream);

  knn_kernel <<<N_NODES/8, 256, 0, stream>>>(pos, knn);
  count_kernel<<<(N_NODES*KK + 255)/256, 256, 0, stream>>>(knn, flags, cnt);
  scan_kernel<<<1, 1024, 0, stream>>>(cnt, off);
  fill_kernel<<<(N_NODES*KK + 255)/256, 256, 0, stream>>>(knn, flags, off, cursor, extra);

  const float* xin = x;
  for (int l = 0; l < 3; l++) {
    const float* W1 = W1s + (size_t)l*131*128;   // rows 0..127: x-part
    const float* Wr = W1 + 128*128;              // rows 128..130: rel-part
    const float* b1 = b1s + l*128;
    const float* W2 = W2s + (size_t)l*128*128;
    const float* b2 = b2s + l*128;
    gemm128<0,0><<<N_NODES/64, 256, 0, stream>>>(xin, W1, b1, nullptr, H);
    agg_kernel  <<<N_NODES/8,  256, 0, stream>>>(H, pos, knn, off, extra, Wr, agg);
    gemm128<1,1><<<N_NODES/64, 256, 0, stream>>>(agg, W2, b2, off, xbuf);
    xin = xbuf;
  }
  final_kernel<<<NB, 1024, 0, stream>>>(xbuf, Wf, bf, out);
}

// Round 15
// 517.434 us; speedup vs baseline: 2.8568x; 1.0052x over previous
//
#include <hip/hip_runtime.h>
#include <stdint.h>

#define N_NODES 32768
#define NPER    8192
#define NB      4
#define KK      20
#define DH      128

typedef unsigned long long u64;

__device__ __forceinline__ u64 shflx64(u64 x, int m) {
  unsigned lo = __shfl_xor((unsigned)(x & 0xffffffffu), m, 64);
  unsigned hi = __shfl_xor((unsigned)(x >> 32), m, 64);
  return (((u64)hi) << 32) | lo;
}
__device__ __forceinline__ u64 shfl64(u64 x, int src) {
  unsigned lo = __shfl((unsigned)(x & 0xffffffffu), src, 64);
  unsigned hi = __shfl((unsigned)(x >> 32), src, 64);
  return (((u64)hi) << 32) | lo;
}
__device__ __forceinline__ int mbcnt64(u64 mask) {
  return __builtin_amdgcn_mbcnt_hi((unsigned)(mask >> 32),
         __builtin_amdgcn_mbcnt_lo((unsigned)mask, 0u));
}
// 64-lane bitonic sort, ascending across lanes (u64 keys)
__device__ __forceinline__ u64 bsort64(u64 key, int lane) {
#pragma unroll
  for (int k = 2; k <= 64; k <<= 1) {
#pragma unroll
    for (int j = k >> 1; j >= 1; j >>= 1) {
      u64 other = shflx64(key, j);
      bool up = ((lane & k) == 0);
      bool keepmin = (((lane & j) == 0) == up);
      bool take = keepmin ? (other < key) : (other > key);
      key = take ? other : key;
    }
  }
  return key;
}
// 64-lane bitonic sort, ascending, u32 keys (half the shuffle cost)
__device__ __forceinline__ unsigned bsortu32(unsigned key, int lane) {
#pragma unroll
  for (int k = 2; k <= 64; k <<= 1) {
#pragma unroll
    for (int j = k >> 1; j >= 1; j >>= 1) {
      unsigned other = (unsigned)__shfl_xor((int)key, j, 64);
      bool up = ((lane & k) == 0);
      bool keepmin = (((lane & j) == 0) == up);
      bool take = keepmin ? (other < key) : (other > key);
      key = take ? other : key;
    }
  }
  return key;
}
// bitonic merge-clean (input bitonic, output ascending)
__device__ __forceinline__ u64 bclean64(u64 key, int lane) {
#pragma unroll
  for (int j = 32; j >= 1; j >>= 1) {
    u64 other = shflx64(key, j);
    bool keepmin = ((lane & j) == 0);
    bool take = keepmin ? (other < key) : (other > key);
    key = take ? other : key;
  }
  return key;
}

// Fold <=64 NEW buffered keys into register-kept sorted list lo (21 valid + pad):
// one bsort64 of the new keys, half-cleaner merge vs lo, bclean. Tighten thr.
__device__ __forceinline__ void compact64(u64* bufr, int& cnt, u64& lo,
                                          unsigned& thr, int lane) {
  asm volatile("s_waitcnt lgkmcnt(0)" ::: "memory");
  u64 k = (lane < cnt) ? bufr[lane] : ~0ull;
  k = bsort64(k, lane);                     // new keys ascending
  u64 kr = shfl64(k, 63 - lane);            // descending copy
  u64 m = (kr < lo) ? kr : lo;              // half-cleaner: 64 smallest of 128, bitonic
  lo = bclean64(m, lane);                   // sorted ascending
  thr = (unsigned)(shfl64(lo, KK) >> 32);   // d2-bits of 21st smallest (incl self)
  cnt = 0;
  asm volatile("s_waitcnt lgkmcnt(0)" ::: "memory");
}

// One wave per TWO consecutive rows; each lane handles FOUR consecutive candidates
// per iteration (48B contiguous = 3x float4, coalesced). Threshold PRIMED from
// iteration-0 lane-mins (21st smallest lane-min >= 21st smallest of 256 => valid
// superset bound). Sorted top-21 lives in registers (lo); LDS buffer holds only
// new appends (<=64); compact triggered BEFORE append when cnt+popc would overflow.
// Self (d2=0) flows through, stripped at output. Exact top-20 by (d2, idx).
__global__ __launch_bounds__(256) void knn_kernel(const float* __restrict__ pos,
                                                  int* __restrict__ knn)
{
  __shared__ u64 buf[8][64];

  const int lane = threadIdx.x & 63;
  const int w    = threadIdx.x >> 6;
  const int rowA = blockIdx.x * 8 + w * 2;
  const int rowB = rowA + 1;
  const int base = (rowA >> 13) << 13;   // graph start

  const float ax = pos[rowA*3+0], ay = pos[rowA*3+1], az = pos[rowA*3+2];
  const float bx = pos[rowB*3+0], by = pos[rowB*3+1], bz = pos[rowB*3+2];

  unsigned thra, thrb;
  int cnta = 0, cntb = 0;
  u64 loa = ~0ull, lob = ~0ull;
  u64* bufa = buf[w*2+0];
  u64* bufb = buf[w*2+1];

  const float4* __restrict__ p4 = (const float4*)(pos + (size_t)base*3);

  // ---- prime thresholds from iteration-0 candidates (lane-min upper bound) ----
  {
    float4 q0 = p4[lane*3+0];
    float4 q1 = p4[lane*3+1];
    float4 q2 = p4[lane*3+2];
    const float X[4] = {q0.x, q0.w, q1.z, q2.y};
    const float Y[4] = {q0.y, q1.x, q1.w, q2.z};
    const float Z[4] = {q0.z, q1.y, q2.x, q2.w};
    float mA = 3.4e38f, mB = 3.4e38f;
#pragma unroll
    for (int r = 0; r < 4; r++) {
      float dx = ax - X[r], dy = ay - Y[r], dz = az - Z[r];
      mA = fminf(mA, fmaf(dx, dx, fmaf(dy, dy, dz*dz)));
      float ex = bx - X[r], ey = by - Y[r], ez = bz - Z[r];
      mB = fminf(mB, fmaf(ex, ex, fmaf(ey, ey, ez*ez)));
    }
    unsigned sA = bsortu32(__float_as_uint(mA), lane);
    unsigned sB = bsortu32(__float_as_uint(mB), lane);
    thra = (unsigned)__shfl((int)sA, KK, 64);   // 21st smallest lane-min
    thrb = (unsigned)__shfl((int)sB, KK, 64);
  }

  for (int it = 0; it < 32; it++) {
    const int c0 = it*256 + lane*4;            // 4 consecutive candidates
    const int f4 = it*192 + lane*3;            // float4 index of candidate block
    float4 q0 = p4[f4+0];
    float4 q1 = p4[f4+1];
    float4 q2 = p4[f4+2];
    const float X[4] = {q0.x, q0.w, q1.z, q2.y};
    const float Y[4] = {q0.y, q1.x, q1.w, q2.z};
    const float Z[4] = {q0.z, q1.y, q2.x, q2.w};

    float dA[4], dB[4];
#pragma unroll
    for (int r = 0; r < 4; r++) {
      float dx = ax - X[r], dy = ay - Y[r], dz = az - Z[r];
      dA[r] = fmaf(dx, dx, fmaf(dy, dy, dz*dz));
      float ex = bx - X[r], ey = by - Y[r], ez = bz - Z[r];
      dB[r] = fmaf(ex, ex, fmaf(ey, ey, ez*ez));
    }
    float mnA = fminf(fminf(dA[0], dA[1]), fminf(dA[2], dA[3]));
    float mnB = fminf(fminf(dB[0], dB[1]), fminf(dB[2], dB[3]));

    if (__any(__float_as_uint(mnA) <= thra)) {
#pragma unroll
      for (int r = 0; r < 4; r++) {
        unsigned bits = __float_as_uint(dA[r]);
        bool pred = (bits <= thra);
        u64 mask = __ballot(pred);
        int pc = __popcll(mask);
        if (cnta + pc > 64) compact64(bufa, cnta, loa, thra, lane);
        if (pred) bufa[cnta + mbcnt64(mask)] =
            (((u64)bits) << 32) | (unsigned)(base + c0 + r);
        cnta = __builtin_amdgcn_readfirstlane(cnta + pc);
      }
    }
    if (__any(__float_as_uint(mnB) <= thrb)) {
#pragma unroll
      for (int r = 0; r < 4; r++) {
        unsigned bits = __float_as_uint(dB[r]);
        bool pred = (bits <= thrb);
        u64 mask = __ballot(pred);
        int pc = __popcll(mask);
        if (cntb + pc > 64) compact64(bufb, cntb, lob, thrb, lane);
        if (pred) bufb[cntb + mbcnt64(mask)] =
            (((u64)bits) << 32) | (unsigned)(base + c0 + r);
        cntb = __builtin_amdgcn_readfirstlane(cntb + pc);
      }
    }
  }
  compact64(bufa, cnta, loa, thra, lane);
  compact64(bufb, cntb, lob, thrb, lane);

  // strip self (d2=0 guarantees membership in the 21); output order irrelevant
  {
    u64 ball = __ballot(((int)(loa & 0xffffffffu) == rowA) && (lane <= KK));
    int p0 = __ffsll((long long)ball) - 1;
    if (p0 < 0) p0 = KK + 1;
    int src = lane + ((lane >= p0) ? 1 : 0);
    u64 outk = shfl64(loa, src);
    if (lane < KK) knn[rowA*KK + lane] = (int)(outk & 0xffffffffu);
  }
  {
    u64 ball = __ballot(((int)(lob & 0xffffffffu) == rowB) && (lane <= KK));
    int p0 = __ffsll((long long)ball) - 1;
    if (p0 < 0) p0 = KK + 1;
    int src = lane + ((lane >= p0) ? 1 : 0);
    u64 outk = shfl64(lob, src);
    if (lane < KK) knn[rowB*KK + lane] = (int)(outk & 0xffffffffu);
  }
}

// forward edge e=(i -> d=knn[i][j]); mutual iff i in knn(d). Non-mutual edges need a CSR slot.
__global__ void count_kernel(const int* __restrict__ knn, int* __restrict__ flags,
                             int* __restrict__ cnt)
{
  int e = blockIdx.x * 256 + threadIdx.x;
  if (e >= N_NODES*KK) return;
  int i = e / KK;
  int d = knn[e];
  int mut = 0;
#pragma unroll
  for (int t = 0; t < KK; t++) mut |= (knn[d*KK + t] == i);
  flags[e] = mut;
  if (!mut) atomicAdd(&cnt[d], 1);
}

__global__ __launch_bounds__(1024) void scan_kernel(const int* __restrict__ cnt,
                                                    int* __restrict__ off)
{
  __shared__ int ssum[1024];
  int tid = threadIdx.x;
  int i0 = tid * 32;
  int loc[32];
  int s = 0;
#pragma unroll
  for (int j = 0; j < 32; j++) { loc[j] = s; s += cnt[i0 + j]; }
  ssum[tid] = s;
  __syncthreads();
  for (int d = 1; d < 1024; d <<= 1) {
    int t = (tid >= d) ? ssum[tid - d] : 0;
    __syncthreads();
    ssum[tid] += t;
    __syncthreads();
  }
  int bse = ssum[tid] - s;             // exclusive base
#pragma unroll
  for (int j = 0; j < 32; j++) off[i0 + j] = bse + loc[j];
  if (tid == 1023) off[N_NODES] = bse + s;
}

__global__ void fill_kernel(const int* __restrict__ knn, const int* __restrict__ flags,
                            const int* __restrict__ off, int* __restrict__ cursor,
                            int* __restrict__ extra)
{
  int e = blockIdx.x * 256 + threadIdx.x;
  if (e >= N_NODES*KK) return;
  if (flags[e]) return;
  int i = e / KK;
  int d = knn[e];
  int p = atomicAdd(&cursor[d], 1);
  extra[off[d] + p] = i;
}

// Y = X @ W (+ bias [*deg]) [+relu]; X:[n,128] W:[128,128] row-major.
// Full W staged in LDS (64 KB, 2 blocks/CU); X streamed via float4 (16 same-addr
// lanes merge); ONE barrier total; inner chunk = 4 global float4 + 8 LDS b128
// (bank-conflict-free) per 128 FMA.
template<int RELU, int DEG>
__global__ __launch_bounds__(256) void gemm128(const float* __restrict__ X,
    const float* __restrict__ W, const float* __restrict__ bias,
    const int* __restrict__ offs, float* __restrict__ Y)
{
  __shared__ float ws[128*128];
  const int tid = threadIdx.x;
  const int r0  = blockIdx.x * 64;

  {
    const float4* W4 = (const float4*)W;
    float4* ws4 = (float4*)ws;
#pragma unroll
    for (int li = 0; li < 16; li++) ws4[tid + li*256] = W4[tid + li*256];
  }
  __syncthreads();

  const int tr = tid >> 4, tc = tid & 15;
  const int rr0 = tr*4, cc0 = tc*8;
  float acc[4][8];
#pragma unroll
  for (int a = 0; a < 4; a++)
#pragma unroll
    for (int c = 0; c < 8; c++) acc[a][c] = 0.f;

  for (int kc = 0; kc < 32; kc++) {
    float4 xr[4];
#pragma unroll
    for (int rr = 0; rr < 4; rr++)
      xr[rr] = *(const float4*)&X[(size_t)(r0 + rr0 + rr)*128 + kc*4];
#pragma unroll
    for (int kk = 0; kk < 4; kk++) {
      float4 wA = *(const float4*)&ws[(kc*4 + kk)*128 + cc0];
      float4 wB = *(const float4*)&ws[(kc*4 + kk)*128 + cc0 + 4];
      float wv[8] = {wA.x, wA.y, wA.z, wA.w, wB.x, wB.y, wB.z, wB.w};
      float xa[4] = {kk==0?xr[0].x:kk==1?xr[0].y:kk==2?xr[0].z:xr[0].w,
                     kk==0?xr[1].x:kk==1?xr[1].y:kk==2?xr[1].z:xr[1].w,
                     kk==0?xr[2].x:kk==1?xr[2].y:kk==2?xr[2].z:xr[2].w,
                     kk==0?xr[3].x:kk==1?xr[3].y:kk==2?xr[3].z:xr[3].w};
#pragma unroll
      for (int rr = 0; rr < 4; rr++)
#pragma unroll
        for (int cc = 0; cc < 8; cc++) acc[rr][cc] += xa[rr] * wv[cc];
    }
  }
#pragma unroll
  for (int rr = 0; rr < 4; rr++) {
    int r = r0 + rr0 + rr;
    float dg = 1.f;
    if (DEG) dg = (float)(KK + offs[r+1] - offs[r]);
    float o[8];
#pragma unroll
    for (int cc = 0; cc < 8; cc++) {
      float vv = acc[rr][cc] + bias[cc0+cc] * dg;
      if (RELU) vv = fmaxf(vv, 0.f);
      o[cc] = vv;
    }
    *(float4*)&Y[(size_t)r*128 + cc0]     = make_float4(o[0], o[1], o[2], o[3]);
    *(float4*)&Y[(size_t)r*128 + cc0 + 4] = make_float4(o[4], o[5], o[6], o[7]);
  }
}

// agg[d] = sum over in-neighbors s of relu(H[s] + (pos[d]-pos[s]) @ Wr).
// TWO nodes per wave (lanes 0-31 node A, 32-63 node B), 4 cols/lane (float4).
// ALL 20 neighbor indices preloaded via 5x int4 (one latency), then the fully
// unrolled neighbor loop issues 20 independent H-row/pos load groups -- removes
// the per-iteration idx->row dependent-latency chain.
// XCD swizzle: graph g -> XCD pair {2g,2g+1}; bijection (g,nb) <-> dblk bits.
__global__ __launch_bounds__(256) void agg_kernel(const float* __restrict__ H,
    const float* __restrict__ pos, const int* __restrict__ knn,
    const int* __restrict__ off, const int* __restrict__ extra,
    const float* __restrict__ Wr, float* __restrict__ agg)
{
  const int lane = threadIdx.x & 63;
  const int w    = threadIdx.x >> 6;
  const int half = lane >> 5;
  const int hl   = lane & 31;
  const int dblk = blockIdx.x;            // 4096 blocks
  const int g    = (dblk >> 1) & 3;
  const int nb   = ((dblk >> 3) << 1) | (dblk & 1);   // 0..1023
  const int d    = g*NPER + nb*8 + w*2 + half;
  const int c0   = hl * 4;

  // preload all 20 neighbor indices (80B contiguous, 16B-aligned: d*80)
  const int4* kn4 = (const int4*)&knn[d*KK];
  int4 i0 = kn4[0], i1 = kn4[1], i2 = kn4[2], i3 = kn4[3], i4 = kn4[4];
  const int e0 = off[d], e1 = off[d+1];
  int idx[KK] = {i0.x,i0.y,i0.z,i0.w, i1.x,i1.y,i1.z,i1.w,
                 i2.x,i2.y,i2.z,i2.w, i3.x,i3.y,i3.z,i3.w,
                 i4.x,i4.y,i4.z,i4.w};

  const float4 w0 = *(const float4*)&Wr[0*DH + c0];
  const float4 w1 = *(const float4*)&Wr[1*DH + c0];
  const float4 w2 = *(const float4*)&Wr[2*DH + c0];
  const float px = pos[d*3+0], py = pos[d*3+1], pz = pos[d*3+2];

  float a0 = 0.f, a1 = 0.f, a2 = 0.f, a3 = 0.f;
#pragma unroll
  for (int t = 0; t < KK; t++) {
    int s = idx[t];
    float rx = px - pos[s*3+0];
    float ry = py - pos[s*3+1];
    float rz = pz - pos[s*3+2];
    float4 h = *(const float4*)&H[(size_t)s*DH + c0];
    a0 += fmaxf(h.x + rx*w0.x + ry*w1.x + rz*w2.x, 0.f);
    a1 += fmaxf(h.y + rx*w0.y + ry*w1.y + rz*w2.y, 0.f);
    a2 += fmaxf(h.z + rx*w0.z + ry*w1.z + rz*w2.z, 0.f);
    a3 += fmaxf(h.w + rx*w0.w + ry*w1.w + rz*w2.w, 0.f);
  }
  for (int t = e0; t < e1; t++) {
    int s = extra[t];
    float rx = px - pos[s*3+0];
    float ry = py - pos[s*3+1];
    float rz = pz - pos[s*3+2];
    float4 h = *(const float4*)&H[(size_t)s*DH + c0];
    a0 += fmaxf(h.x + rx*w0.x + ry*w1.x + rz*w2.x, 0.f);
    a1 += fmaxf(h.y + rx*w0.y + ry*w1.y + rz*w2.y, 0.f);
    a2 += fmaxf(h.z + rx*w0.z + ry*w1.z + rz*w2.z, 0.f);
    a3 += fmaxf(h.w + rx*w0.w + ry*w1.w + rz*w2.w, 0.f);
  }
  *(float4*)&agg[(size_t)d*DH + c0] = make_float4(a0, a1, a2, a3);
}

// logits = X @ Wf + bf; per-graph softmax over 8192 nodes.
__global__ __launch_bounds__(1024) void final_kernel(const float* __restrict__ X,
    const float* __restrict__ Wf, const float* __restrict__ bf, float* __restrict__ out)
{
  __shared__ float red[16];
  __shared__ float bcast;
  const int g = blockIdx.x, tid = threadIdx.x;
  const int lane = tid & 63, wid = tid >> 6;
  float lg[8];
#pragma unroll
  for (int k = 0; k < 8; k++) {
    int n = g*NPER + k*1024 + tid;
    const float4* xr = (const float4*)&X[(size_t)n*128];
    float acc = 0.f;
#pragma unroll 8
    for (int q = 0; q < 32; q++) {
      float4 xv = xr[q];
      float4 wv = *(const float4*)&Wf[q*4];
      acc += xv.x*wv.x + xv.y*wv.y + xv.z*wv.z + xv.w*wv.w;
    }
    lg[k] = acc + bf[0];
  }
  float m = lg[0];
#pragma unroll
  for (int k = 1; k < 8; k++) m = fmaxf(m, lg[k]);
  for (int o = 1; o < 64; o <<= 1) m = fmaxf(m, __shfl_xor(m, o, 64));
  if (lane == 0) red[wid] = m;
  __syncthreads();
  if (tid == 0) {
    float mm = red[0];
    for (int i = 1; i < 16; i++) mm = fmaxf(mm, red[i]);
    bcast = mm;
  }
  __syncthreads();
  const float M = bcast;
  float e[8];
  float s = 0.f;
#pragma unroll
  for (int k = 0; k < 8; k++) { e[k] = expf(lg[k] - M); s += e[k]; }
  for (int o = 1; o < 64; o <<= 1) s += __shfl_xor(s, o, 64);
  __syncthreads();
  if (lane == 0) red[wid] = s;
  __syncthreads();
  if (tid == 0) {
    float ss = 0.f;
    for (int i = 0; i < 16; i++) ss += red[i];
    bcast = ss;
  }
  __syncthreads();
  const float S = bcast;
#pragma unroll
  for (int k = 0; k < 8; k++) {
    int n = g*NPER + k*1024 + tid;
    out[n] = e[k] / S;
  }
}

extern "C" void kernel_launch(void* const* d_in, const int* in_sizes, int n_in,
                              void* d_out, int out_size, void* d_ws, size_t ws_size,
                              hipStream_t stream)
{
  const float* x   = (const float*)d_in[0];
  const float* pos = (const float*)d_in[1];
  // d_in[2] = batch (unused: sorted, equal-size graphs)
  const float* W1s = (const float*)d_in[3];
  const float* b1s = (const float*)d_in[4];
  const float* W2s = (const float*)d_in[5];
  const float* b2s = (const float*)d_in[6];
  const float* Wf  = (const float*)d_in[7];
  const float* bf  = (const float*)d_in[8];
  float* out = (float*)d_out;

  char* wsb = (char*)d_ws;
  size_t o = 0;
  auto alloc = [&](size_t bytes) { void* p = wsb + o; o += (bytes + 255) & ~255ull; return p; };
  int*   knn    = (int*)  alloc((size_t)N_NODES*KK*4);
  int*   flags  = (int*)  alloc((size_t)N_NODES*KK*4);
  int*   cnt    = (int*)  alloc((size_t)(N_NODES+1)*4);
  int*   off    = (int*)  alloc((size_t)(N_NODES+1)*4);
  int*   cursor = (int*)  alloc((size_t)N_NODES*4);
  int*   extra  = (int*)  alloc((size_t)N_NODES*KK*4);
  float* H      = (float*)alloc((size_t)N_NODES*DH*4);
  float* agg    = (float*)alloc((size_t)N_NODES*DH*4);
  float* xbuf   = (float*)alloc((size_t)N_NODES*DH*4);
  (void)ws_size; (void)in_sizes; (void)n_in; (void)out_size;

  hipMemsetAsync(cnt,    0, (size_t)(N_NODES+1)*4, stream);
  hipMemsetAsync(cursor, 0, (size_t)N_NODES*4,     stream);

  knn_kernel <<<N_NODES/8, 256, 0, stream>>>(pos, knn);
  count_kernel<<<(N_NODES*KK + 255)/256, 256, 0, stream>>>(knn, flags, cnt);
  scan_kernel<<<1, 1024, 0, stream>>>(cnt, off);
  fill_kernel<<<(N_NODES*KK + 255)/256, 256, 0, stream>>>(knn, flags, off, cursor, extra);

  const float* xin = x;
  for (int l = 0; l < 3; l++) {
    const float* W1 = W1s + (size_t)l*131*128;   // rows 0..127: x-part
    const float* Wr = W1 + 128*128;              // rows 128..130: rel-part
    const float* b1 = b1s + l*128;
    const float* W2 = W2s + (size_t)l*128*128;
    const float* b2 = b2s + l*128;
    gemm128<0,0><<<N_NODES/64, 256, 0, stream>>>(xin, W1, b1, nullptr, H);
    agg_kernel  <<<N_NODES/8,  256, 0, stream>>>(H, pos, knn, off, extra, Wr, agg);
    gemm128<1,1><<<N_NODES/64, 256, 0, stream>>>(agg, W2, b2, off, xbuf);
    xin = xbuf;
  }
  final_kernel<<<NB, 1024, 0, stream>>>(xbuf, Wf, bf, out);
}

// Round 16
// 515.461 us; speedup vs baseline: 2.8677x; 1.0038x over previous
//
#include <hip/hip_runtime.h>
#include <stdint.h>

#define N_NODES 32768
#define NPER    8192
#define NB      4
#define KK      20
#define DH      128

typedef unsigned long long u64;
typedef unsigned short ushort;

__device__ __forceinline__ ushort f2bf(float f) {      // RNE float->bf16
  unsigned x = __float_as_uint(f);
  return (ushort)((x + 0x7fff + ((x >> 16) & 1)) >> 16);
}
__device__ __forceinline__ float bflo(unsigned u) { return __uint_as_float(u << 16); }
__device__ __forceinline__ float bfhi(unsigned u) { return __uint_as_float(u & 0xffff0000u); }

__device__ __forceinline__ u64 shflx64(u64 x, int m) {
  unsigned lo = __shfl_xor((unsigned)(x & 0xffffffffu), m, 64);
  unsigned hi = __shfl_xor((unsigned)(x >> 32), m, 64);
  return (((u64)hi) << 32) | lo;
}
__device__ __forceinline__ u64 shfl64(u64 x, int src) {
  unsigned lo = __shfl((unsigned)(x & 0xffffffffu), src, 64);
  unsigned hi = __shfl((unsigned)(x >> 32), src, 64);
  return (((u64)hi) << 32) | lo;
}
__device__ __forceinline__ int mbcnt64(u64 mask) {
  return __builtin_amdgcn_mbcnt_hi((unsigned)(mask >> 32),
         __builtin_amdgcn_mbcnt_lo((unsigned)mask, 0u));
}
// 64-lane bitonic sort, ascending across lanes (u64 keys)
__device__ __forceinline__ u64 bsort64(u64 key, int lane) {
#pragma unroll
  for (int k = 2; k <= 64; k <<= 1) {
#pragma unroll
    for (int j = k >> 1; j >= 1; j >>= 1) {
      u64 other = shflx64(key, j);
      bool up = ((lane & k) == 0);
      bool keepmin = (((lane & j) == 0) == up);
      bool take = keepmin ? (other < key) : (other > key);
      key = take ? other : key;
    }
  }
  return key;
}
// 64-lane bitonic sort, ascending, u32 keys (half the shuffle cost)
__device__ __forceinline__ unsigned bsortu32(unsigned key, int lane) {
#pragma unroll
  for (int k = 2; k <= 64; k <<= 1) {
#pragma unroll
    for (int j = k >> 1; j >= 1; j >>= 1) {
      unsigned other = (unsigned)__shfl_xor((int)key, j, 64);
      bool up = ((lane & k) == 0);
      bool keepmin = (((lane & j) == 0) == up);
      bool take = keepmin ? (other < key) : (other > key);
      key = take ? other : key;
    }
  }
  return key;
}
// bitonic merge-clean (input bitonic, output ascending)
__device__ __forceinline__ u64 bclean64(u64 key, int lane) {
#pragma unroll
  for (int j = 32; j >= 1; j >>= 1) {
    u64 other = shflx64(key, j);
    bool keepmin = ((lane & j) == 0);
    bool take = keepmin ? (other < key) : (other > key);
    key = take ? other : key;
  }
  return key;
}

// Fold <=64 NEW buffered keys into register-kept sorted list lo (21 valid + pad):
// one bsort64 of the new keys, half-cleaner merge vs lo, bclean. Tighten thr.
__device__ __forceinline__ void compact64(u64* bufr, int& cnt, u64& lo,
                                          unsigned& thr, int lane) {
  asm volatile("s_waitcnt lgkmcnt(0)" ::: "memory");
  u64 k = (lane < cnt) ? bufr[lane] : ~0ull;
  k = bsort64(k, lane);                     // new keys ascending
  u64 kr = shfl64(k, 63 - lane);            // descending copy
  u64 m = (kr < lo) ? kr : lo;              // half-cleaner: 64 smallest of 128, bitonic
  lo = bclean64(m, lane);                   // sorted ascending
  thr = (unsigned)(shfl64(lo, KK) >> 32);   // d2-bits of 21st smallest (incl self)
  cnt = 0;
  asm volatile("s_waitcnt lgkmcnt(0)" ::: "memory");
}

// One wave per TWO consecutive rows; each lane handles FOUR consecutive candidates
// per iteration (48B contiguous = 3x float4, coalesced). Threshold PRIMED from
// iteration-0 lane-mins. Sorted top-21 in registers; LDS holds only new appends.
// Self (d2=0) flows through, stripped at output. Exact top-20 by (d2, idx).
__global__ __launch_bounds__(256) void knn_kernel(const float* __restrict__ pos,
                                                  int* __restrict__ knn)
{
  __shared__ u64 buf[8][64];

  const int lane = threadIdx.x & 63;
  const int w    = threadIdx.x >> 6;
  const int rowA = blockIdx.x * 8 + w * 2;
  const int rowB = rowA + 1;
  const int base = (rowA >> 13) << 13;   // graph start

  const float ax = pos[rowA*3+0], ay = pos[rowA*3+1], az = pos[rowA*3+2];
  const float bx = pos[rowB*3+0], by = pos[rowB*3+1], bz = pos[rowB*3+2];

  unsigned thra, thrb;
  int cnta = 0, cntb = 0;
  u64 loa = ~0ull, lob = ~0ull;
  u64* bufa = buf[w*2+0];
  u64* bufb = buf[w*2+1];

  const float4* __restrict__ p4 = (const float4*)(pos + (size_t)base*3);

  // ---- prime thresholds from iteration-0 candidates (lane-min upper bound) ----
  {
    float4 q0 = p4[lane*3+0];
    float4 q1 = p4[lane*3+1];
    float4 q2 = p4[lane*3+2];
    const float X[4] = {q0.x, q0.w, q1.z, q2.y};
    const float Y[4] = {q0.y, q1.x, q1.w, q2.z};
    const float Z[4] = {q0.z, q1.y, q2.x, q2.w};
    float mA = 3.4e38f, mB = 3.4e38f;
#pragma unroll
    for (int r = 0; r < 4; r++) {
      float dx = ax - X[r], dy = ay - Y[r], dz = az - Z[r];
      mA = fminf(mA, fmaf(dx, dx, fmaf(dy, dy, dz*dz)));
      float ex = bx - X[r], ey = by - Y[r], ez = bz - Z[r];
      mB = fminf(mB, fmaf(ex, ex, fmaf(ey, ey, ez*ez)));
    }
    unsigned sA = bsortu32(__float_as_uint(mA), lane);
    unsigned sB = bsortu32(__float_as_uint(mB), lane);
    thra = (unsigned)__shfl((int)sA, KK, 64);   // 21st smallest lane-min
    thrb = (unsigned)__shfl((int)sB, KK, 64);
  }

  for (int it = 0; it < 32; it++) {
    const int c0 = it*256 + lane*4;            // 4 consecutive candidates
    const int f4 = it*192 + lane*3;            // float4 index of candidate block
    float4 q0 = p4[f4+0];
    float4 q1 = p4[f4+1];
    float4 q2 = p4[f4+2];
    const float X[4] = {q0.x, q0.w, q1.z, q2.y};
    const float Y[4] = {q0.y, q1.x, q1.w, q2.z};
    const float Z[4] = {q0.z, q1.y, q2.x, q2.w};

    float dA[4], dB[4];
#pragma unroll
    for (int r = 0; r < 4; r++) {
      float dx = ax - X[r], dy = ay - Y[r], dz = az - Z[r];
      dA[r] = fmaf(dx, dx, fmaf(dy, dy, dz*dz));
      float ex = bx - X[r], ey = by - Y[r], ez = bz - Z[r];
      dB[r] = fmaf(ex, ex, fmaf(ey, ey, ez*ez));
    }
    float mnA = fminf(fminf(dA[0], dA[1]), fminf(dA[2], dA[3]));
    float mnB = fminf(fminf(dB[0], dB[1]), fminf(dB[2], dB[3]));

    if (__any(__float_as_uint(mnA) <= thra)) {
#pragma unroll
      for (int r = 0; r < 4; r++) {
        unsigned bits = __float_as_uint(dA[r]);
        bool pred = (bits <= thra);
        u64 mask = __ballot(pred);
        int pc = __popcll(mask);
        if (cnta + pc > 64) compact64(bufa, cnta, loa, thra, lane);
        if (pred) bufa[cnta + mbcnt64(mask)] =
            (((u64)bits) << 32) | (unsigned)(base + c0 + r);
        cnta = __builtin_amdgcn_readfirstlane(cnta + pc);
      }
    }
    if (__any(__float_as_uint(mnB) <= thrb)) {
#pragma unroll
      for (int r = 0; r < 4; r++) {
        unsigned bits = __float_as_uint(dB[r]);
        bool pred = (bits <= thrb);
        u64 mask = __ballot(pred);
        int pc = __popcll(mask);
        if (cntb + pc > 64) compact64(bufb, cntb, lob, thrb, lane);
        if (pred) bufb[cntb + mbcnt64(mask)] =
            (((u64)bits) << 32) | (unsigned)(base + c0 + r);
        cntb = __builtin_amdgcn_readfirstlane(cntb + pc);
      }
    }
  }
  compact64(bufa, cnta, loa, thra, lane);
  compact64(bufb, cntb, lob, thrb, lane);

  // strip self (d2=0 guarantees membership in the 21); output order irrelevant
  {
    u64 ball = __ballot(((int)(loa & 0xffffffffu) == rowA) && (lane <= KK));
    int p0 = __ffsll((long long)ball) - 1;
    if (p0 < 0) p0 = KK + 1;
    int src = lane + ((lane >= p0) ? 1 : 0);
    u64 outk = shfl64(loa, src);
    if (lane < KK) knn[rowA*KK + lane] = (int)(outk & 0xffffffffu);
  }
  {
    u64 ball = __ballot(((int)(lob & 0xffffffffu) == rowB) && (lane <= KK));
    int p0 = __ffsll((long long)ball) - 1;
    if (p0 < 0) p0 = KK + 1;
    int src = lane + ((lane >= p0) ? 1 : 0);
    u64 outk = shfl64(lob, src);
    if (lane < KK) knn[rowB*KK + lane] = (int)(outk & 0xffffffffu);
  }
}

// forward edge e=(i -> d=knn[i][j]); mutual iff i in knn(d). Non-mutual edges need a CSR slot.
__global__ void count_kernel(const int* __restrict__ knn, int* __restrict__ flags,
                             int* __restrict__ cnt)
{
  int e = blockIdx.x * 256 + threadIdx.x;
  if (e >= N_NODES*KK) return;
  int i = e / KK;
  int d = knn[e];
  int mut = 0;
#pragma unroll
  for (int t = 0; t < KK; t++) mut |= (knn[d*KK + t] == i);
  flags[e] = mut;
  if (!mut) atomicAdd(&cnt[d], 1);
}

__global__ __launch_bounds__(1024) void scan_kernel(const int* __restrict__ cnt,
                                                    int* __restrict__ off)
{
  __shared__ int ssum[1024];
  int tid = threadIdx.x;
  int i0 = tid * 32;
  int loc[32];
  int s = 0;
#pragma unroll
  for (int j = 0; j < 32; j++) { loc[j] = s; s += cnt[i0 + j]; }
  ssum[tid] = s;
  __syncthreads();
  for (int d = 1; d < 1024; d <<= 1) {
    int t = (tid >= d) ? ssum[tid - d] : 0;
    __syncthreads();
    ssum[tid] += t;
    __syncthreads();
  }
  int bse = ssum[tid] - s;             // exclusive base
#pragma unroll
  for (int j = 0; j < 32; j++) off[i0 + j] = bse + loc[j];
  if (tid == 1023) off[N_NODES] = bse + s;
}

__global__ void fill_kernel(const int* __restrict__ knn, const int* __restrict__ flags,
                            const int* __restrict__ off, int* __restrict__ cursor,
                            int* __restrict__ extra)
{
  int e = blockIdx.x * 256 + threadIdx.x;
  if (e >= N_NODES*KK) return;
  if (flags[e]) return;
  int i = e / KK;
  int d = knn[e];
  int p = atomicAdd(&cursor[d], 1);
  extra[off[d] + p] = i;
}

// Y = X @ W (+ bias [*deg]) [+relu]; X:[n,128] f32, W:[128,128] row-major.
// OBF16: store Y as bf16 (RNE) instead of f32.
// Full W staged in LDS (64 KB, 2 blocks/CU); ONE barrier total.
template<int RELU, int DEG, int OBF16>
__global__ __launch_bounds__(256) void gemm128(const float* __restrict__ X,
    const float* __restrict__ W, const float* __restrict__ bias,
    const int* __restrict__ offs, void* __restrict__ Yv)
{
  __shared__ float ws[128*128];
  const int tid = threadIdx.x;
  const int r0  = blockIdx.x * 64;

  {
    const float4* W4 = (const float4*)W;
    float4* ws4 = (float4*)ws;
#pragma unroll
    for (int li = 0; li < 16; li++) ws4[tid + li*256] = W4[tid + li*256];
  }
  __syncthreads();

  const int tr = tid >> 4, tc = tid & 15;
  const int rr0 = tr*4, cc0 = tc*8;
  float acc[4][8];
#pragma unroll
  for (int a = 0; a < 4; a++)
#pragma unroll
    for (int c = 0; c < 8; c++) acc[a][c] = 0.f;

  for (int kc = 0; kc < 32; kc++) {
    float4 xr[4];
#pragma unroll
    for (int rr = 0; rr < 4; rr++)
      xr[rr] = *(const float4*)&X[(size_t)(r0 + rr0 + rr)*128 + kc*4];
#pragma unroll
    for (int kk = 0; kk < 4; kk++) {
      float4 wA = *(const float4*)&ws[(kc*4 + kk)*128 + cc0];
      float4 wB = *(const float4*)&ws[(kc*4 + kk)*128 + cc0 + 4];
      float wv[8] = {wA.x, wA.y, wA.z, wA.w, wB.x, wB.y, wB.z, wB.w};
      float xa[4] = {kk==0?xr[0].x:kk==1?xr[0].y:kk==2?xr[0].z:xr[0].w,
                     kk==0?xr[1].x:kk==1?xr[1].y:kk==2?xr[1].z:xr[1].w,
                     kk==0?xr[2].x:kk==1?xr[2].y:kk==2?xr[2].z:xr[2].w,
                     kk==0?xr[3].x:kk==1?xr[3].y:kk==2?xr[3].z:xr[3].w};
#pragma unroll
      for (int rr = 0; rr < 4; rr++)
#pragma unroll
        for (int cc = 0; cc < 8; cc++) acc[rr][cc] += xa[rr] * wv[cc];
    }
  }
#pragma unroll
  for (int rr = 0; rr < 4; rr++) {
    int r = r0 + rr0 + rr;
    float dg = 1.f;
    if (DEG) dg = (float)(KK + offs[r+1] - offs[r]);
    float o[8];
#pragma unroll
    for (int cc = 0; cc < 8; cc++) {
      float vv = acc[rr][cc] + bias[cc0+cc] * dg;
      if (RELU) vv = fmaxf(vv, 0.f);
      o[cc] = vv;
    }
    if (OBF16) {
      ushort* Y = (ushort*)Yv;
      unsigned p[4];
#pragma unroll
      for (int q = 0; q < 4; q++)
        p[q] = (unsigned)f2bf(o[2*q]) | ((unsigned)f2bf(o[2*q+1]) << 16);
      *(uint4*)&Y[(size_t)r*128 + cc0] = make_uint4(p[0], p[1], p[2], p[3]);
    } else {
      float* Y = (float*)Yv;
      *(float4*)&Y[(size_t)r*128 + cc0]     = make_float4(o[0], o[1], o[2], o[3]);
      *(float4*)&Y[(size_t)r*128 + cc0 + 4] = make_float4(o[4], o[5], o[6], o[7]);
    }
  }
}

// agg[d] = sum over in-neighbors s of relu(H[s] + (pos[d]-pos[s]) @ Wr).
// H is bf16 [N,128] (256B rows): FOUR nodes per wave (16 lanes each, 8 cols/lane
// via one 16B uint4 = 8 bf16). One dwordx4 instr fetches FOUR rows -> VMEM
// instructions AND bytes per node both halve vs the f32 2-node version.
// XCD swizzle: graph g -> XCD pair {2g,2g+1}; (g,nb) <-> dblk bits bijective.
__global__ __launch_bounds__(256) void agg_kernel(const ushort* __restrict__ H,
    const float* __restrict__ pos, const int* __restrict__ knn,
    const int* __restrict__ off, const int* __restrict__ extra,
    const float* __restrict__ Wr, float* __restrict__ agg)
{
  const int lane = threadIdx.x & 63;
  const int w    = threadIdx.x >> 6;
  const int grp  = lane >> 4;             // node within wave
  const int hl   = lane & 15;             // lane within node group
  const int dblk = blockIdx.x;            // 2048 blocks
  const int g    = (dblk >> 1) & 3;
  const int nb   = ((dblk >> 3) << 1) | (dblk & 1);   // 0..511
  const int d    = g*NPER + nb*16 + w*4 + grp;
  const int c0   = hl * 8;

  // preload all 20 neighbor indices (80B contiguous)
  const int4* kn4 = (const int4*)&knn[d*KK];
  int4 i0 = kn4[0], i1 = kn4[1], i2 = kn4[2], i3 = kn4[3], i4 = kn4[4];
  const int e0 = off[d], e1 = off[d+1];
  const int idx[KK] = {i0.x,i0.y,i0.z,i0.w, i1.x,i1.y,i1.z,i1.w,
                       i2.x,i2.y,i2.z,i2.w, i3.x,i3.y,i3.z,i3.w,
                       i4.x,i4.y,i4.z,i4.w};

  // 8 columns of Wr per lane
  float w0[8], w1[8], w2[8];
#pragma unroll
  for (int j = 0; j < 8; j++) {
    w0[j] = Wr[0*DH + c0 + j];
    w1[j] = Wr[1*DH + c0 + j];
    w2[j] = Wr[2*DH + c0 + j];
  }
  const float px = pos[d*3+0], py = pos[d*3+1], pz = pos[d*3+2];

  float a[8];
#pragma unroll
  for (int j = 0; j < 8; j++) a[j] = 0.f;

#pragma unroll
  for (int t = 0; t < KK; t++) {
    int s = idx[t];
    float rx = px - pos[s*3+0];
    float ry = py - pos[s*3+1];
    float rz = pz - pos[s*3+2];
    uint4 hv = *(const uint4*)&H[(size_t)s*DH + c0];
    float h[8] = {bflo(hv.x), bfhi(hv.x), bflo(hv.y), bfhi(hv.y),
                  bflo(hv.z), bfhi(hv.z), bflo(hv.w), bfhi(hv.w)};
#pragma unroll
    for (int j = 0; j < 8; j++) {
      float m = h[j] + rx*w0[j] + ry*w1[j] + rz*w2[j];
      a[j] += fmaxf(m, 0.f);
    }
  }
  for (int t = e0; t < e1; t++) {
    int s = extra[t];
    float rx = px - pos[s*3+0];
    float ry = py - pos[s*3+1];
    float rz = pz - pos[s*3+2];
    uint4 hv = *(const uint4*)&H[(size_t)s*DH + c0];
    float h[8] = {bflo(hv.x), bfhi(hv.x), bflo(hv.y), bfhi(hv.y),
                  bflo(hv.z), bfhi(hv.z), bflo(hv.w), bfhi(hv.w)};
#pragma unroll
    for (int j = 0; j < 8; j++) {
      float m = h[j] + rx*w0[j] + ry*w1[j] + rz*w2[j];
      a[j] += fmaxf(m, 0.f);
    }
  }
  *(float4*)&agg[(size_t)d*DH + c0]     = make_float4(a[0], a[1], a[2], a[3]);
  *(float4*)&agg[(size_t)d*DH + c0 + 4] = make_float4(a[4], a[5], a[6], a[7]);
}

// logits = X @ Wf + bf; per-graph softmax over 8192 nodes.
__global__ __launch_bounds__(1024) void final_kernel(const float* __restrict__ X,
    const float* __restrict__ Wf, const float* __restrict__ bf, float* __restrict__ out)
{
  __shared__ float red[16];
  __shared__ float bcast;
  const int g = blockIdx.x, tid = threadIdx.x;
  const int lane = tid & 63, wid = tid >> 6;
  float lg[8];
#pragma unroll
  for (int k = 0; k < 8; k++) {
    int n = g*NPER + k*1024 + tid;
    const float4* xr = (const float4*)&X[(size_t)n*128];
    float acc = 0.f;
#pragma unroll 8
    for (int q = 0; q < 32; q++) {
      float4 xv = xr[q];
      float4 wv = *(const float4*)&Wf[q*4];
      acc += xv.x*wv.x + xv.y*wv.y + xv.z*wv.z + xv.w*wv.w;
    }
    lg[k] = acc + bf[0];
  }
  float m = lg[0];
#pragma unroll
  for (int k = 1; k < 8; k++) m = fmaxf(m, lg[k]);
  for (int o = 1; o < 64; o <<= 1) m = fmaxf(m, __shfl_xor(m, o, 64));
  if (lane == 0) red[wid] = m;
  __syncthreads();
  if (tid == 0) {
    float mm = red[0];
    for (int i = 1; i < 16; i++) mm = fmaxf(mm, red[i]);
    bcast = mm;
  }
  __syncthreads();
  const float M = bcast;
  float e[8];
  float s = 0.f;
#pragma unroll
  for (int k = 0; k < 8; k++) { e[k] = expf(lg[k] - M); s += e[k]; }
  for (int o = 1; o < 64; o <<= 1) s += __shfl_xor(s, o, 64);
  __syncthreads();
  if (lane == 0) red[wid] = s;
  __syncthreads();
  if (tid == 0) {
    float ss = 0.f;
    for (int i = 0; i < 16; i++) ss += red[i];
    bcast = ss;
  }
  __syncthreads();
  const float S = bcast;
#pragma unroll
  for (int k = 0; k < 8; k++) {
    int n = g*NPER + k*1024 + tid;
    out[n] = e[k] / S;
  }
}

extern "C" void kernel_launch(void* const* d_in, const int* in_sizes, int n_in,
                              void* d_out, int out_size, void* d_ws, size_t ws_size,
                              hipStream_t stream)
{
  const float* x   = (const float*)d_in[0];
  const float* pos = (const float*)d_in[1];
  // d_in[2] = batch (unused: sorted, equal-size graphs)
  const float* W1s = (const float*)d_in[3];
  const float* b1s = (const float*)d_in[4];
  const float* W2s = (const float*)d_in[5];
  const float* b2s = (const float*)d_in[6];
  const float* Wf  = (const float*)d_in[7];
  const float* bf  = (const float*)d_in[8];
  float* out = (float*)d_out;

  char* wsb = (char*)d_ws;
  size_t o = 0;
  auto alloc = [&](size_t bytes) { void* p = wsb + o; o += (bytes + 255) & ~255ull; return p; };
  int*    knn    = (int*)   alloc((size_t)N_NODES*KK*4);
  int*    flags  = (int*)   alloc((size_t)N_NODES*KK*4);
  int*    cnt    = (int*)   alloc((size_t)(N_NODES+1)*4);
  int*    off    = (int*)   alloc((size_t)(N_NODES+1)*4);
  int*    cursor = (int*)   alloc((size_t)N_NODES*4);
  int*    extra  = (int*)   alloc((size_t)N_NODES*KK*4);
  ushort* H      = (ushort*)alloc((size_t)N_NODES*DH*2);   // bf16
  float*  agg    = (float*) alloc((size_t)N_NODES*DH*4);
  float*  xbuf   = (float*) alloc((size_t)N_NODES*DH*4);
  (void)ws_size; (void)in_sizes; (void)n_in; (void)out_size;

  hipMemsetAsync(cnt,    0, (size_t)(N_NODES+1)*4, stream);
  hipMemsetAsync(cursor, 0, (size_t)N_NODES*4,     stream);

  knn_kernel <<<N_NODES/8, 256, 0, stream>>>(pos, knn);
  count_kernel<<<(N_NODES*KK + 255)/256, 256, 0, stream>>>(knn, flags, cnt);
  scan_kernel<<<1, 1024, 0, stream>>>(cnt, off);
  fill_kernel<<<(N_NODES*KK + 255)/256, 256, 0, stream>>>(knn, flags, off, cursor, extra);

  const float* xin = x;
  for (int l = 0; l < 3; l++) {
    const float* W1 = W1s + (size_t)l*131*128;   // rows 0..127: x-part
    const float* Wr = W1 + 128*128;              // rows 128..130: rel-part
    const float* b1 = b1s + l*128;
    const float* W2 = W2s + (size_t)l*128*128;
    const float* b2 = b2s + l*128;
    gemm128<0,0,1><<<N_NODES/64, 256, 0, stream>>>(xin, W1, b1, nullptr, H);
    agg_kernel  <<<N_NODES/16, 256, 0, stream>>>(H, pos, knn, off, extra, Wr, agg);
    gemm128<1,1,0><<<N_NODES/64, 256, 0, stream>>>(agg, W2, b2, off, xbuf);
    xin = xbuf;
  }
  final_kernel<<<NB, 1024, 0, stream>>>(xbuf, Wf, bf, out);
}